// Round 2
// baseline (1177.682 us; speedup 1.0000x reference)
//
#include <hip/hip_runtime.h>
#include <hip/hip_bf16.h>

#define NN 50000
#define EE 800000

__device__ __forceinline__ float lrelu(float x) { return x > 0.f ? x : 0.2f * x; }

// ---------------- CSR build ----------------
__global__ void hist_k(const int* __restrict__ dst, int* __restrict__ deg) {
    int i = blockIdx.x * 256 + threadIdx.x;
    if (i < EE) atomicAdd(&deg[dst[i]], 1);
}

__global__ __launch_bounds__(1024) void scan_k(const int* __restrict__ deg,
                                               int* __restrict__ row_ptr,
                                               int* __restrict__ cursor) {
    __shared__ int wsum[16];
    int tid = threadIdx.x, lane = tid & 63, w = tid >> 6;
    int carry = 0;
    for (int base = 0; base < NN; base += 1024) {
        int i = base + tid;
        int v = (i < NN) ? deg[i] : 0;
        int x = v;
#pragma unroll
        for (int off = 1; off < 64; off <<= 1) {
            int y = __shfl_up(x, off);
            if (lane >= off) x += y;
        }
        if (lane == 63) wsum[w] = x;
        __syncthreads();
        if (tid < 16) {
            int s = wsum[tid];
#pragma unroll
            for (int off = 1; off < 16; off <<= 1) {
                int y = __shfl_up(s, off);
                if (tid >= off) s += y;
            }
            wsum[tid] = s;
        }
        __syncthreads();
        int woff = w ? wsum[w - 1] : 0;
        int excl = carry + woff + x - v;
        if (i < NN) { row_ptr[i] = excl; cursor[i] = excl; }
        carry += wsum[15];
        __syncthreads();
    }
    if (tid == 0) row_ptr[NN] = carry;
}

__global__ void scatter_k(const int* __restrict__ src, const int* __restrict__ dst,
                          int* __restrict__ cursor, int* __restrict__ csr_src) {
    int i = blockIdx.x * 256 + threadIdx.x;
    if (i < EE) {
        int slot = atomicAdd(&cursor[dst[i]], 1);
        csr_src[slot] = src[i];
    }
}

// ---------------- attention logits el/er ----------------
// Layer 1: feat computed on the fly from positions (rank-2 input).
__global__ __launch_bounds__(256) void eler1_k(const float* __restrict__ pos,
                                               const float* __restrict__ W1,
                                               const float* __restrict__ al,
                                               const float* __restrict__ ar,
                                               float* __restrict__ el,
                                               float* __restrict__ er) {
    int wid = blockIdx.x * 4 + (threadIdx.x >> 6);
    int lane = threadIdx.x & 63;
    if (wid >= NN) return;
    int f = lane * 4;
    float4 w0 = *(const float4*)&W1[f];
    float4 w1 = *(const float4*)&W1[256 + f];
    float4 a4 = *(const float4*)&al[f];
    float4 r4 = *(const float4*)&ar[f];
    float2 p = *(const float2*)&pos[wid * 2];
    float fx = p.x * w0.x + p.y * w1.x;
    float fy = p.x * w0.y + p.y * w1.y;
    float fz = p.x * w0.z + p.y * w1.z;
    float fw = p.x * w0.w + p.y * w1.w;
    float pl = fx * a4.x + fy * a4.y + fz * a4.z + fw * a4.w;
    float pr = fx * r4.x + fy * r4.y + fz * r4.z + fw * r4.w;
#pragma unroll
    for (int off = 1; off < 16; off <<= 1) {
        pl += __shfl_xor(pl, off);
        pr += __shfl_xor(pr, off);
    }
    if ((lane & 15) == 0) {
        int h = lane >> 4;
        el[wid * 4 + h] = pl;
        er[wid * 4 + h] = pr;
    }
}

__global__ __launch_bounds__(256) void eler_k(const float* __restrict__ feat,
                                              const float* __restrict__ al,
                                              const float* __restrict__ ar,
                                              float* __restrict__ el,
                                              float* __restrict__ er) {
    int wid = blockIdx.x * 4 + (threadIdx.x >> 6);
    int lane = threadIdx.x & 63;
    if (wid >= NN) return;
    int f = lane * 4;
    float4 f4 = *(const float4*)&feat[(size_t)wid * 256 + f];
    float4 a4 = *(const float4*)&al[f];
    float4 r4 = *(const float4*)&ar[f];
    float pl = f4.x * a4.x + f4.y * a4.y + f4.z * a4.z + f4.w * a4.w;
    float pr = f4.x * r4.x + f4.y * r4.y + f4.z * r4.z + f4.w * r4.w;
#pragma unroll
    for (int off = 1; off < 16; off <<= 1) {
        pl += __shfl_xor(pl, off);
        pr += __shfl_xor(pr, off);
    }
    if ((lane & 15) == 0) {
        int h = lane >> 4;
        el[wid * 4 + h] = pl;
        er[wid * 4 + h] = pr;
    }
}

// ---------------- aggregation: one wave per dst node ----------------
// Layer 1: feat[src] = pos[src] @ W1 folded into two scalar accumulators.
__global__ __launch_bounds__(256) void agg1_k(const float* __restrict__ pos,
                                              const float* __restrict__ W1,
                                              const float* __restrict__ resW1,
                                              const float* __restrict__ el,
                                              const float* __restrict__ er,
                                              const int* __restrict__ row_ptr,
                                              const int* __restrict__ csr_src,
                                              float* __restrict__ hout) {
    int wid = blockIdx.x * 4 + (threadIdx.x >> 6);
    int lane = threadIdx.x & 63;
    if (wid >= NN) return;
    int f = lane * 4;
    int start = row_ptr[wid], end = row_ptr[wid + 1];
    float4 er4 = *(const float4*)&er[wid * 4];

    float m0 = -1e30f, m1 = -1e30f, m2 = -1e30f, m3 = -1e30f;
    for (int s = start + lane; s < end; s += 64) {
        int sn = csr_src[s];
        float4 ev = *(const float4*)&el[sn * 4];
        m0 = fmaxf(m0, lrelu(ev.x + er4.x));
        m1 = fmaxf(m1, lrelu(ev.y + er4.y));
        m2 = fmaxf(m2, lrelu(ev.z + er4.z));
        m3 = fmaxf(m3, lrelu(ev.w + er4.w));
    }
#pragma unroll
    for (int off = 32; off; off >>= 1) {
        m0 = fmaxf(m0, __shfl_xor(m0, off));
        m1 = fmaxf(m1, __shfl_xor(m1, off));
        m2 = fmaxf(m2, __shfl_xor(m2, off));
        m3 = fmaxf(m3, __shfl_xor(m3, off));
    }
    float s0 = 0, s1 = 0, s2 = 0, s3 = 0;
    for (int s = start + lane; s < end; s += 64) {
        int sn = csr_src[s];
        float4 ev = *(const float4*)&el[sn * 4];
        s0 += __expf(lrelu(ev.x + er4.x) - m0);
        s1 += __expf(lrelu(ev.y + er4.y) - m1);
        s2 += __expf(lrelu(ev.z + er4.z) - m2);
        s3 += __expf(lrelu(ev.w + er4.w) - m3);
    }
#pragma unroll
    for (int off = 32; off; off >>= 1) {
        s0 += __shfl_xor(s0, off);
        s1 += __shfl_xor(s1, off);
        s2 += __shfl_xor(s2, off);
        s3 += __shfl_xor(s3, off);
    }
    float i0 = 1.f / fmaxf(s0, 1e-9f), i1 = 1.f / fmaxf(s1, 1e-9f);
    float i2 = 1.f / fmaxf(s2, 1e-9f), i3 = 1.f / fmaxf(s3, 1e-9f);

    int h = lane >> 4;
    float mh = (lane & 32) ? ((lane & 16) ? m3 : m2) : ((lane & 16) ? m1 : m0);
    float ih = (lane & 32) ? ((lane & 16) ? i3 : i2) : ((lane & 16) ? i1 : i0);
    float eh = (lane & 32) ? ((lane & 16) ? er4.w : er4.z) : ((lane & 16) ? er4.y : er4.x);

    float ap0 = 0.f, ap1 = 0.f;  // weighted position sums (feat is linear in pos)
    for (int s = start; s < end; ++s) {
        int sn = csr_src[s];
        float a = __expf(lrelu(el[sn * 4 + h] + eh) - mh) * ih;
        float2 p = *(const float2*)&pos[sn * 2];
        ap0 += a * p.x;
        ap1 += a * p.y;
    }
    float4 w0 = *(const float4*)&W1[f];
    float4 w1 = *(const float4*)&W1[256 + f];
    float4 rw0 = *(const float4*)&resW1[f];
    float4 rw1 = *(const float4*)&resW1[256 + f];
    float2 pd = *(const float2*)&pos[wid * 2];
    float4 o;
    o.x = fmaxf(ap0 * w0.x + ap1 * w1.x + pd.x * rw0.x + pd.y * rw1.x, 0.f);
    o.y = fmaxf(ap0 * w0.y + ap1 * w1.y + pd.x * rw0.y + pd.y * rw1.y, 0.f);
    o.z = fmaxf(ap0 * w0.z + ap1 * w1.z + pd.x * rw0.z + pd.y * rw1.z, 0.f);
    o.w = fmaxf(ap0 * w0.w + ap1 * w1.w + pd.x * rw0.w + pd.y * rw1.w, 0.f);
    *(float4*)&hout[(size_t)wid * 256 + f] = o;
}

// Layer 2: gather feat rows, residual in-place (each wave owns its row), relu.
__global__ __launch_bounds__(256) void agg_k(const float* __restrict__ feat,
                                             const float* __restrict__ el,
                                             const float* __restrict__ er,
                                             const int* __restrict__ row_ptr,
                                             const int* __restrict__ csr_src,
                                             float* __restrict__ hio) {
    int wid = blockIdx.x * 4 + (threadIdx.x >> 6);
    int lane = threadIdx.x & 63;
    if (wid >= NN) return;
    int f = lane * 4;
    int start = row_ptr[wid], end = row_ptr[wid + 1];
    float4 er4 = *(const float4*)&er[wid * 4];

    float m0 = -1e30f, m1 = -1e30f, m2 = -1e30f, m3 = -1e30f;
    for (int s = start + lane; s < end; s += 64) {
        int sn = csr_src[s];
        float4 ev = *(const float4*)&el[sn * 4];
        m0 = fmaxf(m0, lrelu(ev.x + er4.x));
        m1 = fmaxf(m1, lrelu(ev.y + er4.y));
        m2 = fmaxf(m2, lrelu(ev.z + er4.z));
        m3 = fmaxf(m3, lrelu(ev.w + er4.w));
    }
#pragma unroll
    for (int off = 32; off; off >>= 1) {
        m0 = fmaxf(m0, __shfl_xor(m0, off));
        m1 = fmaxf(m1, __shfl_xor(m1, off));
        m2 = fmaxf(m2, __shfl_xor(m2, off));
        m3 = fmaxf(m3, __shfl_xor(m3, off));
    }
    float s0 = 0, s1 = 0, s2 = 0, s3 = 0;
    for (int s = start + lane; s < end; s += 64) {
        int sn = csr_src[s];
        float4 ev = *(const float4*)&el[sn * 4];
        s0 += __expf(lrelu(ev.x + er4.x) - m0);
        s1 += __expf(lrelu(ev.y + er4.y) - m1);
        s2 += __expf(lrelu(ev.z + er4.z) - m2);
        s3 += __expf(lrelu(ev.w + er4.w) - m3);
    }
#pragma unroll
    for (int off = 32; off; off >>= 1) {
        s0 += __shfl_xor(s0, off);
        s1 += __shfl_xor(s1, off);
        s2 += __shfl_xor(s2, off);
        s3 += __shfl_xor(s3, off);
    }
    float i0 = 1.f / fmaxf(s0, 1e-9f), i1 = 1.f / fmaxf(s1, 1e-9f);
    float i2 = 1.f / fmaxf(s2, 1e-9f), i3 = 1.f / fmaxf(s3, 1e-9f);

    int h = lane >> 4;
    float mh = (lane & 32) ? ((lane & 16) ? m3 : m2) : ((lane & 16) ? m1 : m0);
    float ih = (lane & 32) ? ((lane & 16) ? i3 : i2) : ((lane & 16) ? i1 : i0);
    float eh = (lane & 32) ? ((lane & 16) ? er4.w : er4.z) : ((lane & 16) ? er4.y : er4.x);

    float4 acc = {0.f, 0.f, 0.f, 0.f};
    for (int s = start; s < end; ++s) {
        int sn = csr_src[s];
        float a = __expf(lrelu(el[sn * 4 + h] + eh) - mh) * ih;
        float4 v = *(const float4*)&feat[(size_t)sn * 256 + f];
        acc.x += a * v.x;
        acc.y += a * v.y;
        acc.z += a * v.z;
        acc.w += a * v.w;
    }
    float4 r = *(const float4*)&hio[(size_t)wid * 256 + f];
    float4 o;
    o.x = fmaxf(acc.x + r.x, 0.f);
    o.y = fmaxf(acc.y + r.y, 0.f);
    o.z = fmaxf(acc.z + r.z, 0.f);
    o.w = fmaxf(acc.w + r.w, 0.f);
    *(float4*)&hio[(size_t)wid * 256 + f] = o;
}

// Layer 3: no relu, mean over heads -> hsmall [N,64]
__global__ __launch_bounds__(256) void agg3_k(const float* __restrict__ feat,
                                              const float* __restrict__ el,
                                              const float* __restrict__ er,
                                              const int* __restrict__ row_ptr,
                                              const int* __restrict__ csr_src,
                                              const float* __restrict__ hres,
                                              float* __restrict__ hsmall) {
    int wid = blockIdx.x * 4 + (threadIdx.x >> 6);
    int lane = threadIdx.x & 63;
    if (wid >= NN) return;
    int f = lane * 4;
    int start = row_ptr[wid], end = row_ptr[wid + 1];
    float4 er4 = *(const float4*)&er[wid * 4];

    float m0 = -1e30f, m1 = -1e30f, m2 = -1e30f, m3 = -1e30f;
    for (int s = start + lane; s < end; s += 64) {
        int sn = csr_src[s];
        float4 ev = *(const float4*)&el[sn * 4];
        m0 = fmaxf(m0, lrelu(ev.x + er4.x));
        m1 = fmaxf(m1, lrelu(ev.y + er4.y));
        m2 = fmaxf(m2, lrelu(ev.z + er4.z));
        m3 = fmaxf(m3, lrelu(ev.w + er4.w));
    }
#pragma unroll
    for (int off = 32; off; off >>= 1) {
        m0 = fmaxf(m0, __shfl_xor(m0, off));
        m1 = fmaxf(m1, __shfl_xor(m1, off));
        m2 = fmaxf(m2, __shfl_xor(m2, off));
        m3 = fmaxf(m3, __shfl_xor(m3, off));
    }
    float s0 = 0, s1 = 0, s2 = 0, s3 = 0;
    for (int s = start + lane; s < end; s += 64) {
        int sn = csr_src[s];
        float4 ev = *(const float4*)&el[sn * 4];
        s0 += __expf(lrelu(ev.x + er4.x) - m0);
        s1 += __expf(lrelu(ev.y + er4.y) - m1);
        s2 += __expf(lrelu(ev.z + er4.z) - m2);
        s3 += __expf(lrelu(ev.w + er4.w) - m3);
    }
#pragma unroll
    for (int off = 32; off; off >>= 1) {
        s0 += __shfl_xor(s0, off);
        s1 += __shfl_xor(s1, off);
        s2 += __shfl_xor(s2, off);
        s3 += __shfl_xor(s3, off);
    }
    float i0 = 1.f / fmaxf(s0, 1e-9f), i1 = 1.f / fmaxf(s1, 1e-9f);
    float i2 = 1.f / fmaxf(s2, 1e-9f), i3 = 1.f / fmaxf(s3, 1e-9f);

    int h = lane >> 4;
    float mh = (lane & 32) ? ((lane & 16) ? m3 : m2) : ((lane & 16) ? m1 : m0);
    float ih = (lane & 32) ? ((lane & 16) ? i3 : i2) : ((lane & 16) ? i1 : i0);
    float eh = (lane & 32) ? ((lane & 16) ? er4.w : er4.z) : ((lane & 16) ? er4.y : er4.x);

    float4 acc = {0.f, 0.f, 0.f, 0.f};
    for (int s = start; s < end; ++s) {
        int sn = csr_src[s];
        float a = __expf(lrelu(el[sn * 4 + h] + eh) - mh) * ih;
        float4 v = *(const float4*)&feat[(size_t)sn * 256 + f];
        acc.x += a * v.x;
        acc.y += a * v.y;
        acc.z += a * v.z;
        acc.w += a * v.w;
    }
    float4 r = *(const float4*)&hres[(size_t)wid * 256 + f];
    float4 o;
    o.x = acc.x + r.x;
    o.y = acc.y + r.y;
    o.z = acc.z + r.z;
    o.w = acc.w + r.w;
    // mean over heads: lanes {l, l^16, l^32, l^48} hold same d
    o.x += __shfl_xor(o.x, 16); o.y += __shfl_xor(o.y, 16);
    o.z += __shfl_xor(o.z, 16); o.w += __shfl_xor(o.w, 16);
    o.x += __shfl_xor(o.x, 32); o.y += __shfl_xor(o.y, 32);
    o.z += __shfl_xor(o.z, 32); o.w += __shfl_xor(o.w, 32);
    if (lane < 16) {
        float4 m4;
        m4.x = o.x * 0.25f; m4.y = o.y * 0.25f; m4.z = o.z * 0.25f; m4.w = o.w * 0.25f;
        *(float4*)&hsmall[(size_t)wid * 64 + lane * 4] = m4;
    }
}

// ---------------- dense GEMM [N,256] @ [256,256] f32 ----------------
__global__ __launch_bounds__(256) void gemm256_k(const float* __restrict__ A,
                                                 const float* __restrict__ B,
                                                 float* __restrict__ C) {
    __shared__ float As[32][66];  // transposed A tile [k][m]
    __shared__ float Bs[32][64];
    int tid = threadIdx.x;
    int tx = tid & 15, ty = tid >> 4;
    int tileM = blockIdx.x * 64;
    int tileN = blockIdx.y * 64;
    float acc[4][4] = {};
    for (int k0 = 0; k0 < 256; k0 += 32) {
        {
            int row = tid >> 2, c = (tid & 3) * 8;
            int gr = tileM + row;
            float4 a0 = {0, 0, 0, 0}, a1 = {0, 0, 0, 0};
            if (gr < NN) {
                a0 = *(const float4*)&A[(size_t)gr * 256 + k0 + c];
                a1 = *(const float4*)&A[(size_t)gr * 256 + k0 + c + 4];
            }
            As[c + 0][row] = a0.x; As[c + 1][row] = a0.y;
            As[c + 2][row] = a0.z; As[c + 3][row] = a0.w;
            As[c + 4][row] = a1.x; As[c + 5][row] = a1.y;
            As[c + 6][row] = a1.z; As[c + 7][row] = a1.w;
            int br = tid >> 3, bc = (tid & 7) * 8;
            float4 b0 = *(const float4*)&B[(size_t)(k0 + br) * 256 + tileN + bc];
            float4 b1 = *(const float4*)&B[(size_t)(k0 + br) * 256 + tileN + bc + 4];
            *(float4*)&Bs[br][bc] = b0;
            *(float4*)&Bs[br][bc + 4] = b1;
        }
        __syncthreads();
#pragma unroll
        for (int kk = 0; kk < 32; ++kk) {
            float2 a01 = *(const float2*)&As[kk][ty * 4];
            float2 a23 = *(const float2*)&As[kk][ty * 4 + 2];
            float4 b = *(const float4*)&Bs[kk][tx * 4];
            acc[0][0] += a01.x * b.x; acc[0][1] += a01.x * b.y;
            acc[0][2] += a01.x * b.z; acc[0][3] += a01.x * b.w;
            acc[1][0] += a01.y * b.x; acc[1][1] += a01.y * b.y;
            acc[1][2] += a01.y * b.z; acc[1][3] += a01.y * b.w;
            acc[2][0] += a23.x * b.x; acc[2][1] += a23.x * b.y;
            acc[2][2] += a23.x * b.z; acc[2][3] += a23.x * b.w;
            acc[3][0] += a23.y * b.x; acc[3][1] += a23.y * b.y;
            acc[3][2] += a23.y * b.z; acc[3][3] += a23.y * b.w;
        }
        __syncthreads();
    }
#pragma unroll
    for (int i = 0; i < 4; ++i) {
        int row = tileM + ty * 4 + i;
        if (row < NN) {
            float4 o;
            o.x = acc[i][0]; o.y = acc[i][1]; o.z = acc[i][2]; o.w = acc[i][3];
            *(float4*)&C[(size_t)row * 256 + tileN + tx * 4] = o;
        }
    }
}

// ---------------- edge scoring MLP ----------------
__global__ __launch_bounds__(256) void edge_score_k(const float* __restrict__ hs,
                                                    const int* __restrict__ src,
                                                    const int* __restrict__ dst,
                                                    const float* __restrict__ mW1,
                                                    const float* __restrict__ mb1,
                                                    const float* __restrict__ mW2,
                                                    const float* __restrict__ mb2,
                                                    float* __restrict__ out) {
    __shared__ float Ws[64 * 64];
    __shared__ float xs[4][64];
    for (int i = threadIdx.x * 4; i < 4096; i += 1024)
        *(float4*)&Ws[i] = *(const float4*)&mW1[i];
    int w = threadIdx.x >> 6, lane = threadIdx.x & 63;
    int e = blockIdx.x * 4 + w;   // EE % 4 == 0, all lanes valid
    int s = src[e], d = dst[e];
    __syncthreads();
    xs[w][lane] = fabsf(hs[(size_t)s * 64 + lane] - hs[(size_t)d * 64 + lane]);
    __syncthreads();
    float y = mb1[lane];
#pragma unroll
    for (int k = 0; k < 64; ++k) y += xs[w][k] * Ws[k * 64 + lane];
    float t = fmaxf(y, 0.f) * mW2[lane];
#pragma unroll
    for (int off = 32; off; off >>= 1) t += __shfl_xor(t, off);
    if (lane == 0) out[e] = 1.f / (1.f + __expf(-(t + mb2[0])));
}

extern "C" void kernel_launch(void* const* d_in, const int* in_sizes, int n_in,
                              void* d_out, int out_size, void* d_ws, size_t ws_size,
                              hipStream_t stream) {
    (void)in_sizes; (void)n_in; (void)out_size; (void)ws_size;
    const float* pos   = (const float*)d_in[0];
    const int*   src   = (const int*)d_in[1];
    const int*   dst   = (const int*)d_in[2];
    const float* W1    = (const float*)d_in[3];
    const float* al1   = (const float*)d_in[4];
    const float* ar1   = (const float*)d_in[5];
    const float* resW1 = (const float*)d_in[6];
    const float* W2    = (const float*)d_in[7];
    const float* al2   = (const float*)d_in[8];
    const float* ar2   = (const float*)d_in[9];
    const float* W3    = (const float*)d_in[10];
    const float* al3   = (const float*)d_in[11];
    const float* ar3   = (const float*)d_in[12];
    const float* mW1   = (const float*)d_in[13];
    const float* mb1   = (const float*)d_in[14];
    const float* mW2   = (const float*)d_in[15];
    const float* mb2   = (const float*)d_in[16];
    float* out = (float*)d_out;

    char* ws = (char*)d_ws;
    size_t off = 0;
    auto alloc = [&](size_t bytes) {
        void* p = ws + off;
        off += (bytes + 255) & ~(size_t)255;
        return p;
    };
    float* Hbuf   = (float*)alloc((size_t)NN * 256 * 4);  // h (in-place residual+out)
    float* FEAT   = (float*)alloc((size_t)NN * 256 * 4);  // feat of current layer
    float* hsmall = (float*)alloc((size_t)NN * 64 * 4);
    float* el     = (float*)alloc((size_t)NN * 4 * 4);
    float* er     = (float*)alloc((size_t)NN * 4 * 4);
    int* deg      = (int*)alloc((size_t)NN * 4);
    int* row_ptr  = (int*)alloc((size_t)(NN + 1) * 4);
    int* cursor   = (int*)alloc((size_t)NN * 4);
    int* csr      = (int*)alloc((size_t)EE * 4);

    hipMemsetAsync(deg, 0, (size_t)NN * 4, stream);
    hist_k<<<(EE + 255) / 256, 256, 0, stream>>>(dst, deg);
    scan_k<<<1, 1024, 0, stream>>>(deg, row_ptr, cursor);
    scatter_k<<<(EE + 255) / 256, 256, 0, stream>>>(src, dst, cursor, csr);

    // layer 1
    eler1_k<<<NN / 4 + 1, 256, 0, stream>>>(pos, W1, al1, ar1, el, er);
    agg1_k<<<NN / 4 + 1, 256, 0, stream>>>(pos, W1, resW1, el, er, row_ptr, csr, Hbuf);

    dim3 ggrid((NN + 63) / 64, 4);
    // layer 2
    gemm256_k<<<ggrid, 256, 0, stream>>>(Hbuf, W2, FEAT);
    eler_k<<<NN / 4 + 1, 256, 0, stream>>>(FEAT, al2, ar2, el, er);
    agg_k<<<NN / 4 + 1, 256, 0, stream>>>(FEAT, el, er, row_ptr, csr, Hbuf);

    // layer 3
    gemm256_k<<<ggrid, 256, 0, stream>>>(Hbuf, W3, FEAT);
    eler_k<<<NN / 4 + 1, 256, 0, stream>>>(FEAT, al3, ar3, el, er);
    agg3_k<<<NN / 4 + 1, 256, 0, stream>>>(FEAT, el, er, row_ptr, csr, Hbuf, hsmall);

    // edge MLP
    edge_score_k<<<EE / 4, 256, 0, stream>>>(hsmall, src, dst, mW1, mb1, mW2, mb2, out);
}

// Round 3
// 1103.949 us; speedup vs baseline: 1.0668x; 1.0668x over previous
//
#include <hip/hip_runtime.h>
#include <hip/hip_bf16.h>

#define NN 50000
#define EE 800000

__device__ __forceinline__ float lrelu(float x) { return x > 0.f ? x : 0.2f * x; }

// ---------------- CSR build ----------------
__global__ void hist_k(const int* __restrict__ dst, int* __restrict__ deg) {
    int i = blockIdx.x * 256 + threadIdx.x;
    if (i < EE) atomicAdd(&deg[dst[i]], 1);
}

__global__ __launch_bounds__(1024) void scan_k(const int* __restrict__ deg,
                                               int* __restrict__ row_ptr,
                                               int* __restrict__ cursor) {
    __shared__ int wsum[16];
    int tid = threadIdx.x, lane = tid & 63, w = tid >> 6;
    int carry = 0;
    for (int base = 0; base < NN; base += 1024) {
        int i = base + tid;
        int v = (i < NN) ? deg[i] : 0;
        int x = v;
#pragma unroll
        for (int off = 1; off < 64; off <<= 1) {
            int y = __shfl_up(x, off);
            if (lane >= off) x += y;
        }
        if (lane == 63) wsum[w] = x;
        __syncthreads();
        if (tid < 16) {
            int s = wsum[tid];
#pragma unroll
            for (int off = 1; off < 16; off <<= 1) {
                int y = __shfl_up(s, off);
                if (tid >= off) s += y;
            }
            wsum[tid] = s;
        }
        __syncthreads();
        int woff = w ? wsum[w - 1] : 0;
        int excl = carry + woff + x - v;
        if (i < NN) { row_ptr[i] = excl; cursor[i] = excl; }
        carry += wsum[15];
        __syncthreads();
    }
    if (tid == 0) row_ptr[NN] = carry;
}

__global__ void scatter_k(const int* __restrict__ src, const int* __restrict__ dst,
                          int* __restrict__ cursor, int* __restrict__ csr_src) {
    int i = blockIdx.x * 256 + threadIdx.x;
    if (i < EE) {
        int slot = atomicAdd(&cursor[dst[i]], 1);
        csr_src[slot] = src[i];
    }
}

// ---------------- attention logits el/er ----------------
__global__ __launch_bounds__(256) void eler1_k(const float* __restrict__ pos,
                                               const float* __restrict__ W1,
                                               const float* __restrict__ al,
                                               const float* __restrict__ ar,
                                               float* __restrict__ el,
                                               float* __restrict__ er) {
    int wid = blockIdx.x * 4 + (threadIdx.x >> 6);
    int lane = threadIdx.x & 63;
    if (wid >= NN) return;
    int f = lane * 4;
    float4 w0 = *(const float4*)&W1[f];
    float4 w1 = *(const float4*)&W1[256 + f];
    float4 a4 = *(const float4*)&al[f];
    float4 r4 = *(const float4*)&ar[f];
    float2 p = *(const float2*)&pos[wid * 2];
    float fx = p.x * w0.x + p.y * w1.x;
    float fy = p.x * w0.y + p.y * w1.y;
    float fz = p.x * w0.z + p.y * w1.z;
    float fw = p.x * w0.w + p.y * w1.w;
    float pl = fx * a4.x + fy * a4.y + fz * a4.z + fw * a4.w;
    float pr = fx * r4.x + fy * r4.y + fz * r4.z + fw * r4.w;
#pragma unroll
    for (int off = 1; off < 16; off <<= 1) {
        pl += __shfl_xor(pl, off);
        pr += __shfl_xor(pr, off);
    }
    if ((lane & 15) == 0) {
        int h = lane >> 4;
        el[wid * 4 + h] = pl;
        er[wid * 4 + h] = pr;
    }
}

__global__ __launch_bounds__(256) void eler_k(const float* __restrict__ feat,
                                              const float* __restrict__ al,
                                              const float* __restrict__ ar,
                                              float* __restrict__ el,
                                              float* __restrict__ er) {
    int wid = blockIdx.x * 4 + (threadIdx.x >> 6);
    int lane = threadIdx.x & 63;
    if (wid >= NN) return;
    int f = lane * 4;
    float4 f4 = *(const float4*)&feat[(size_t)wid * 256 + f];
    float4 a4 = *(const float4*)&al[f];
    float4 r4 = *(const float4*)&ar[f];
    float pl = f4.x * a4.x + f4.y * a4.y + f4.z * a4.z + f4.w * a4.w;
    float pr = f4.x * r4.x + f4.y * r4.y + f4.z * r4.z + f4.w * r4.w;
#pragma unroll
    for (int off = 1; off < 16; off <<= 1) {
        pl += __shfl_xor(pl, off);
        pr += __shfl_xor(pr, off);
    }
    if ((lane & 15) == 0) {
        int h = lane >> 4;
        el[wid * 4 + h] = pl;
        er[wid * 4 + h] = pr;
    }
}

// ---------------- aggregation: one wave per dst node ----------------
__global__ __launch_bounds__(256) void agg1_k(const float* __restrict__ pos,
                                              const float* __restrict__ W1,
                                              const float* __restrict__ resW1,
                                              const float* __restrict__ el,
                                              const float* __restrict__ er,
                                              const int* __restrict__ row_ptr,
                                              const int* __restrict__ csr_src,
                                              float* __restrict__ hout) {
    int wid = blockIdx.x * 4 + (threadIdx.x >> 6);
    int lane = threadIdx.x & 63;
    if (wid >= NN) return;
    int f = lane * 4;
    int start = row_ptr[wid], end = row_ptr[wid + 1];
    float4 er4 = *(const float4*)&er[wid * 4];

    float m0 = -1e30f, m1 = -1e30f, m2 = -1e30f, m3 = -1e30f;
    for (int s = start + lane; s < end; s += 64) {
        int sn = csr_src[s];
        float4 ev = *(const float4*)&el[sn * 4];
        m0 = fmaxf(m0, lrelu(ev.x + er4.x));
        m1 = fmaxf(m1, lrelu(ev.y + er4.y));
        m2 = fmaxf(m2, lrelu(ev.z + er4.z));
        m3 = fmaxf(m3, lrelu(ev.w + er4.w));
    }
#pragma unroll
    for (int off = 32; off; off >>= 1) {
        m0 = fmaxf(m0, __shfl_xor(m0, off));
        m1 = fmaxf(m1, __shfl_xor(m1, off));
        m2 = fmaxf(m2, __shfl_xor(m2, off));
        m3 = fmaxf(m3, __shfl_xor(m3, off));
    }
    float s0 = 0, s1 = 0, s2 = 0, s3 = 0;
    for (int s = start + lane; s < end; s += 64) {
        int sn = csr_src[s];
        float4 ev = *(const float4*)&el[sn * 4];
        s0 += __expf(lrelu(ev.x + er4.x) - m0);
        s1 += __expf(lrelu(ev.y + er4.y) - m1);
        s2 += __expf(lrelu(ev.z + er4.z) - m2);
        s3 += __expf(lrelu(ev.w + er4.w) - m3);
    }
#pragma unroll
    for (int off = 32; off; off >>= 1) {
        s0 += __shfl_xor(s0, off);
        s1 += __shfl_xor(s1, off);
        s2 += __shfl_xor(s2, off);
        s3 += __shfl_xor(s3, off);
    }
    float i0 = 1.f / fmaxf(s0, 1e-9f), i1 = 1.f / fmaxf(s1, 1e-9f);
    float i2 = 1.f / fmaxf(s2, 1e-9f), i3 = 1.f / fmaxf(s3, 1e-9f);

    int h = lane >> 4;
    float mh = (lane & 32) ? ((lane & 16) ? m3 : m2) : ((lane & 16) ? m1 : m0);
    float ih = (lane & 32) ? ((lane & 16) ? i3 : i2) : ((lane & 16) ? i1 : i0);
    float eh = (lane & 32) ? ((lane & 16) ? er4.w : er4.z) : ((lane & 16) ? er4.y : er4.x);

    float ap0 = 0.f, ap1 = 0.f;
    for (int s = start; s < end; ++s) {
        int sn = csr_src[s];
        float a = __expf(lrelu(el[sn * 4 + h] + eh) - mh) * ih;
        float2 p = *(const float2*)&pos[sn * 2];
        ap0 += a * p.x;
        ap1 += a * p.y;
    }
    float4 w0 = *(const float4*)&W1[f];
    float4 w1 = *(const float4*)&W1[256 + f];
    float4 rw0 = *(const float4*)&resW1[f];
    float4 rw1 = *(const float4*)&resW1[256 + f];
    float2 pd = *(const float2*)&pos[wid * 2];
    float4 o;
    o.x = fmaxf(ap0 * w0.x + ap1 * w1.x + pd.x * rw0.x + pd.y * rw1.x, 0.f);
    o.y = fmaxf(ap0 * w0.y + ap1 * w1.y + pd.x * rw0.y + pd.y * rw1.y, 0.f);
    o.z = fmaxf(ap0 * w0.z + ap1 * w1.z + pd.x * rw0.z + pd.y * rw1.z, 0.f);
    o.w = fmaxf(ap0 * w0.w + ap1 * w1.w + pd.x * rw0.w + pd.y * rw1.w, 0.f);
    *(float4*)&hout[(size_t)wid * 256 + f] = o;
}

__global__ __launch_bounds__(256) void agg_k(const float* __restrict__ feat,
                                             const float* __restrict__ el,
                                             const float* __restrict__ er,
                                             const int* __restrict__ row_ptr,
                                             const int* __restrict__ csr_src,
                                             float* __restrict__ hio) {
    int wid = blockIdx.x * 4 + (threadIdx.x >> 6);
    int lane = threadIdx.x & 63;
    if (wid >= NN) return;
    int f = lane * 4;
    int start = row_ptr[wid], end = row_ptr[wid + 1];
    float4 er4 = *(const float4*)&er[wid * 4];

    float m0 = -1e30f, m1 = -1e30f, m2 = -1e30f, m3 = -1e30f;
    for (int s = start + lane; s < end; s += 64) {
        int sn = csr_src[s];
        float4 ev = *(const float4*)&el[sn * 4];
        m0 = fmaxf(m0, lrelu(ev.x + er4.x));
        m1 = fmaxf(m1, lrelu(ev.y + er4.y));
        m2 = fmaxf(m2, lrelu(ev.z + er4.z));
        m3 = fmaxf(m3, lrelu(ev.w + er4.w));
    }
#pragma unroll
    for (int off = 32; off; off >>= 1) {
        m0 = fmaxf(m0, __shfl_xor(m0, off));
        m1 = fmaxf(m1, __shfl_xor(m1, off));
        m2 = fmaxf(m2, __shfl_xor(m2, off));
        m3 = fmaxf(m3, __shfl_xor(m3, off));
    }
    float s0 = 0, s1 = 0, s2 = 0, s3 = 0;
    for (int s = start + lane; s < end; s += 64) {
        int sn = csr_src[s];
        float4 ev = *(const float4*)&el[sn * 4];
        s0 += __expf(lrelu(ev.x + er4.x) - m0);
        s1 += __expf(lrelu(ev.y + er4.y) - m1);
        s2 += __expf(lrelu(ev.z + er4.z) - m2);
        s3 += __expf(lrelu(ev.w + er4.w) - m3);
    }
#pragma unroll
    for (int off = 32; off; off >>= 1) {
        s0 += __shfl_xor(s0, off);
        s1 += __shfl_xor(s1, off);
        s2 += __shfl_xor(s2, off);
        s3 += __shfl_xor(s3, off);
    }
    float i0 = 1.f / fmaxf(s0, 1e-9f), i1 = 1.f / fmaxf(s1, 1e-9f);
    float i2 = 1.f / fmaxf(s2, 1e-9f), i3 = 1.f / fmaxf(s3, 1e-9f);

    int h = lane >> 4;
    float mh = (lane & 32) ? ((lane & 16) ? m3 : m2) : ((lane & 16) ? m1 : m0);
    float ih = (lane & 32) ? ((lane & 16) ? i3 : i2) : ((lane & 16) ? i1 : i0);
    float eh = (lane & 32) ? ((lane & 16) ? er4.w : er4.z) : ((lane & 16) ? er4.y : er4.x);

    float4 acc = {0.f, 0.f, 0.f, 0.f};
    for (int s = start; s < end; ++s) {
        int sn = csr_src[s];
        float a = __expf(lrelu(el[sn * 4 + h] + eh) - mh) * ih;
        float4 v = *(const float4*)&feat[(size_t)sn * 256 + f];
        acc.x += a * v.x;
        acc.y += a * v.y;
        acc.z += a * v.z;
        acc.w += a * v.w;
    }
    float4 r = *(const float4*)&hio[(size_t)wid * 256 + f];
    float4 o;
    o.x = fmaxf(acc.x + r.x, 0.f);
    o.y = fmaxf(acc.y + r.y, 0.f);
    o.z = fmaxf(acc.z + r.z, 0.f);
    o.w = fmaxf(acc.w + r.w, 0.f);
    *(float4*)&hio[(size_t)wid * 256 + f] = o;
}

__global__ __launch_bounds__(256) void agg3_k(const float* __restrict__ feat,
                                              const float* __restrict__ el,
                                              const float* __restrict__ er,
                                              const int* __restrict__ row_ptr,
                                              const int* __restrict__ csr_src,
                                              const float* __restrict__ hres,
                                              float* __restrict__ hsmall) {
    int wid = blockIdx.x * 4 + (threadIdx.x >> 6);
    int lane = threadIdx.x & 63;
    if (wid >= NN) return;
    int f = lane * 4;
    int start = row_ptr[wid], end = row_ptr[wid + 1];
    float4 er4 = *(const float4*)&er[wid * 4];

    float m0 = -1e30f, m1 = -1e30f, m2 = -1e30f, m3 = -1e30f;
    for (int s = start + lane; s < end; s += 64) {
        int sn = csr_src[s];
        float4 ev = *(const float4*)&el[sn * 4];
        m0 = fmaxf(m0, lrelu(ev.x + er4.x));
        m1 = fmaxf(m1, lrelu(ev.y + er4.y));
        m2 = fmaxf(m2, lrelu(ev.z + er4.z));
        m3 = fmaxf(m3, lrelu(ev.w + er4.w));
    }
#pragma unroll
    for (int off = 32; off; off >>= 1) {
        m0 = fmaxf(m0, __shfl_xor(m0, off));
        m1 = fmaxf(m1, __shfl_xor(m1, off));
        m2 = fmaxf(m2, __shfl_xor(m2, off));
        m3 = fmaxf(m3, __shfl_xor(m3, off));
    }
    float s0 = 0, s1 = 0, s2 = 0, s3 = 0;
    for (int s = start + lane; s < end; s += 64) {
        int sn = csr_src[s];
        float4 ev = *(const float4*)&el[sn * 4];
        s0 += __expf(lrelu(ev.x + er4.x) - m0);
        s1 += __expf(lrelu(ev.y + er4.y) - m1);
        s2 += __expf(lrelu(ev.z + er4.z) - m2);
        s3 += __expf(lrelu(ev.w + er4.w) - m3);
    }
#pragma unroll
    for (int off = 32; off; off >>= 1) {
        s0 += __shfl_xor(s0, off);
        s1 += __shfl_xor(s1, off);
        s2 += __shfl_xor(s2, off);
        s3 += __shfl_xor(s3, off);
    }
    float i0 = 1.f / fmaxf(s0, 1e-9f), i1 = 1.f / fmaxf(s1, 1e-9f);
    float i2 = 1.f / fmaxf(s2, 1e-9f), i3 = 1.f / fmaxf(s3, 1e-9f);

    int h = lane >> 4;
    float mh = (lane & 32) ? ((lane & 16) ? m3 : m2) : ((lane & 16) ? m1 : m0);
    float ih = (lane & 32) ? ((lane & 16) ? i3 : i2) : ((lane & 16) ? i1 : i0);
    float eh = (lane & 32) ? ((lane & 16) ? er4.w : er4.z) : ((lane & 16) ? er4.y : er4.x);

    float4 acc = {0.f, 0.f, 0.f, 0.f};
    for (int s = start; s < end; ++s) {
        int sn = csr_src[s];
        float a = __expf(lrelu(el[sn * 4 + h] + eh) - mh) * ih;
        float4 v = *(const float4*)&feat[(size_t)sn * 256 + f];
        acc.x += a * v.x;
        acc.y += a * v.y;
        acc.z += a * v.z;
        acc.w += a * v.w;
    }
    float4 r = *(const float4*)&hres[(size_t)wid * 256 + f];
    float4 o;
    o.x = acc.x + r.x;
    o.y = acc.y + r.y;
    o.z = acc.z + r.z;
    o.w = acc.w + r.w;
    o.x += __shfl_xor(o.x, 16); o.y += __shfl_xor(o.y, 16);
    o.z += __shfl_xor(o.z, 16); o.w += __shfl_xor(o.w, 16);
    o.x += __shfl_xor(o.x, 32); o.y += __shfl_xor(o.y, 32);
    o.z += __shfl_xor(o.z, 32); o.w += __shfl_xor(o.w, 32);
    if (lane < 16) {
        float4 m4;
        m4.x = o.x * 0.25f; m4.y = o.y * 0.25f; m4.z = o.z * 0.25f; m4.w = o.w * 0.25f;
        *(float4*)&hsmall[(size_t)wid * 64 + lane * 4] = m4;
    }
}

// ---------------- dense GEMM [N,256] @ [256,256] f32, 128x128 tile ----------------
__global__ __launch_bounds__(256) void gemm128_k(const float* __restrict__ A,
                                                 const float* __restrict__ B,
                                                 float* __restrict__ C) {
    __shared__ __align__(16) float As[32][132];  // [k][m], pad 132 keeps 16B align
    __shared__ __align__(16) float Bs[32][128];
    int tid = threadIdx.x;
    int tileM = blockIdx.x * 128;
    int tileN = blockIdx.y * 128;
    int arow = tid >> 1;            // 0..127
    int acol = (tid & 1) * 16;      // 0 / 16
    int brow = tid >> 3;            // 0..31
    int bcol = (tid & 7) * 16;      // 0..112
    int tx = tid & 15, ty = tid >> 4;
    float acc[8][8] = {};
    for (int k0 = 0; k0 < 256; k0 += 32) {
        int gr = tileM + arow;
#pragma unroll
        for (int q = 0; q < 4; ++q) {
            float4 a = {0.f, 0.f, 0.f, 0.f};
            if (gr < NN) a = *(const float4*)&A[(size_t)gr * 256 + k0 + acol + q * 4];
            As[acol + q * 4 + 0][arow] = a.x;
            As[acol + q * 4 + 1][arow] = a.y;
            As[acol + q * 4 + 2][arow] = a.z;
            As[acol + q * 4 + 3][arow] = a.w;
        }
#pragma unroll
        for (int q = 0; q < 4; ++q) {
            *(float4*)&Bs[brow][bcol + q * 4] =
                *(const float4*)&B[(size_t)(k0 + brow) * 256 + tileN + bcol + q * 4];
        }
        __syncthreads();
#pragma unroll
        for (int kk = 0; kk < 32; ++kk) {
            float ar[8], br[8];
            *(float4*)&ar[0] = *(const float4*)&As[kk][ty * 8];
            *(float4*)&ar[4] = *(const float4*)&As[kk][ty * 8 + 4];
            *(float4*)&br[0] = *(const float4*)&Bs[kk][tx * 8];
            *(float4*)&br[4] = *(const float4*)&Bs[kk][tx * 8 + 4];
#pragma unroll
            for (int i = 0; i < 8; ++i)
#pragma unroll
                for (int j = 0; j < 8; ++j)
                    acc[i][j] += ar[i] * br[j];
        }
        __syncthreads();
    }
#pragma unroll
    for (int i = 0; i < 8; ++i) {
        int row = tileM + ty * 8 + i;
        if (row < NN) {
            float4 o0, o1;
            o0.x = acc[i][0]; o0.y = acc[i][1]; o0.z = acc[i][2]; o0.w = acc[i][3];
            o1.x = acc[i][4]; o1.y = acc[i][5]; o1.z = acc[i][6]; o1.w = acc[i][7];
            *(float4*)&C[(size_t)row * 256 + tileN + tx * 8] = o0;
            *(float4*)&C[(size_t)row * 256 + tileN + tx * 8 + 4] = o1;
        }
    }
}

// ---------------- edge scoring MLP v2: thread-per-edge, 2 edges/thread ----------------
__global__ __launch_bounds__(256) void edge_score2_k(const float* __restrict__ hs,
                                                     const int* __restrict__ src,
                                                     const int* __restrict__ dst,
                                                     const float* __restrict__ mW1,
                                                     const float* __restrict__ mb1,
                                                     const float* __restrict__ mW2,
                                                     const float* __restrict__ mb2,
                                                     float* __restrict__ out) {
    __shared__ __align__(16) float Ws[64 * 64];
    __shared__ __align__(16) float b1s[64];
    __shared__ __align__(16) float w2s[64];
    int tid = threadIdx.x;
    for (int i = tid * 4; i < 4096; i += 1024)
        *(float4*)&Ws[i] = *(const float4*)&mW1[i];
    if (tid < 64) { b1s[tid] = mb1[tid]; w2s[tid] = mW2[tid]; }

    int e0 = blockIdx.x * 512 + tid;       // always < EE (last block: <= 799999)
    int e1 = e0 + 256;
    bool v1 = e1 < EE;
    int s0 = src[e0], d0 = dst[e0];
    int s1 = v1 ? src[e1] : s0, d1 = v1 ? dst[e1] : d0;
    __syncthreads();

    float xA[64], xB[64];
#pragma unroll
    for (int i = 0; i < 16; ++i) {
        float4 a = *(const float4*)&hs[(size_t)s0 * 64 + i * 4];
        float4 b = *(const float4*)&hs[(size_t)d0 * 64 + i * 4];
        xA[4 * i + 0] = fabsf(a.x - b.x);
        xA[4 * i + 1] = fabsf(a.y - b.y);
        xA[4 * i + 2] = fabsf(a.z - b.z);
        xA[4 * i + 3] = fabsf(a.w - b.w);
        float4 c = *(const float4*)&hs[(size_t)s1 * 64 + i * 4];
        float4 d = *(const float4*)&hs[(size_t)d1 * 64 + i * 4];
        xB[4 * i + 0] = fabsf(c.x - d.x);
        xB[4 * i + 1] = fabsf(c.y - d.y);
        xB[4 * i + 2] = fabsf(c.z - d.z);
        xB[4 * i + 3] = fabsf(c.w - d.w);
    }

    float t0 = 0.f, t1 = 0.f;
    for (int j0 = 0; j0 < 16; ++j0) {
        float4 bb = *(const float4*)&b1s[j0 * 4];
        float4 y0 = bb, y1 = bb;
#pragma unroll
        for (int k = 0; k < 64; ++k) {
            float4 w = *(const float4*)&Ws[k * 64 + j0 * 4];
            y0.x += xA[k] * w.x; y0.y += xA[k] * w.y;
            y0.z += xA[k] * w.z; y0.w += xA[k] * w.w;
            y1.x += xB[k] * w.x; y1.y += xB[k] * w.y;
            y1.z += xB[k] * w.z; y1.w += xB[k] * w.w;
        }
        float4 w2 = *(const float4*)&w2s[j0 * 4];
        t0 += fmaxf(y0.x, 0.f) * w2.x + fmaxf(y0.y, 0.f) * w2.y +
              fmaxf(y0.z, 0.f) * w2.z + fmaxf(y0.w, 0.f) * w2.w;
        t1 += fmaxf(y1.x, 0.f) * w2.x + fmaxf(y1.y, 0.f) * w2.y +
              fmaxf(y1.z, 0.f) * w2.z + fmaxf(y1.w, 0.f) * w2.w;
    }
    float bias = mb2[0];
    out[e0] = 1.f / (1.f + __expf(-(t0 + bias)));
    if (v1) out[e1] = 1.f / (1.f + __expf(-(t1 + bias)));
}

extern "C" void kernel_launch(void* const* d_in, const int* in_sizes, int n_in,
                              void* d_out, int out_size, void* d_ws, size_t ws_size,
                              hipStream_t stream) {
    (void)in_sizes; (void)n_in; (void)out_size; (void)ws_size;
    const float* pos   = (const float*)d_in[0];
    const int*   src   = (const int*)d_in[1];
    const int*   dst   = (const int*)d_in[2];
    const float* W1    = (const float*)d_in[3];
    const float* al1   = (const float*)d_in[4];
    const float* ar1   = (const float*)d_in[5];
    const float* resW1 = (const float*)d_in[6];
    const float* W2    = (const float*)d_in[7];
    const float* al2   = (const float*)d_in[8];
    const float* ar2   = (const float*)d_in[9];
    const float* W3    = (const float*)d_in[10];
    const float* al3   = (const float*)d_in[11];
    const float* ar3   = (const float*)d_in[12];
    const float* mW1   = (const float*)d_in[13];
    const float* mb1   = (const float*)d_in[14];
    const float* mW2   = (const float*)d_in[15];
    const float* mb2   = (const float*)d_in[16];
    float* out = (float*)d_out;

    char* ws = (char*)d_ws;
    size_t off = 0;
    auto alloc = [&](size_t bytes) {
        void* p = ws + off;
        off += (bytes + 255) & ~(size_t)255;
        return p;
    };
    float* Hbuf   = (float*)alloc((size_t)NN * 256 * 4);
    float* FEAT   = (float*)alloc((size_t)NN * 256 * 4);
    float* hsmall = (float*)alloc((size_t)NN * 64 * 4);
    float* el     = (float*)alloc((size_t)NN * 4 * 4);
    float* er     = (float*)alloc((size_t)NN * 4 * 4);
    int* deg      = (int*)alloc((size_t)NN * 4);
    int* row_ptr  = (int*)alloc((size_t)(NN + 1) * 4);
    int* cursor   = (int*)alloc((size_t)NN * 4);
    int* csr      = (int*)alloc((size_t)EE * 4);

    hipMemsetAsync(deg, 0, (size_t)NN * 4, stream);
    hist_k<<<(EE + 255) / 256, 256, 0, stream>>>(dst, deg);
    scan_k<<<1, 1024, 0, stream>>>(deg, row_ptr, cursor);
    scatter_k<<<(EE + 255) / 256, 256, 0, stream>>>(src, dst, cursor, csr);

    // layer 1
    eler1_k<<<NN / 4 + 1, 256, 0, stream>>>(pos, W1, al1, ar1, el, er);
    agg1_k<<<NN / 4 + 1, 256, 0, stream>>>(pos, W1, resW1, el, er, row_ptr, csr, Hbuf);

    dim3 ggrid((NN + 127) / 128, 2);
    // layer 2
    gemm128_k<<<ggrid, 256, 0, stream>>>(Hbuf, W2, FEAT);
    eler_k<<<NN / 4 + 1, 256, 0, stream>>>(FEAT, al2, ar2, el, er);
    agg_k<<<NN / 4 + 1, 256, 0, stream>>>(FEAT, el, er, row_ptr, csr, Hbuf);

    // layer 3
    gemm128_k<<<ggrid, 256, 0, stream>>>(Hbuf, W3, FEAT);
    eler_k<<<NN / 4 + 1, 256, 0, stream>>>(FEAT, al3, ar3, el, er);
    agg3_k<<<NN / 4 + 1, 256, 0, stream>>>(FEAT, el, er, row_ptr, csr, Hbuf, hsmall);

    // edge MLP
    edge_score2_k<<<(EE + 511) / 512, 256, 0, stream>>>(hsmall, src, dst, mW1, mb1, mW2, mb2, out);
}

// Round 4
// 971.717 us; speedup vs baseline: 1.2120x; 1.1361x over previous
//
#include <hip/hip_runtime.h>
#include <hip/hip_bf16.h>

#define NN 50000
#define EE 800000

__device__ __forceinline__ float lrelu(float x) { return x > 0.f ? x : 0.2f * x; }

// ---------------- CSR build ----------------
__global__ void hist_k(const int* __restrict__ dst, int* __restrict__ deg) {
    int i = blockIdx.x * 256 + threadIdx.x;
    if (i < EE) atomicAdd(&deg[dst[i]], 1);
}

__global__ __launch_bounds__(1024) void scan_k(const int* __restrict__ deg,
                                               int* __restrict__ row_ptr,
                                               int* __restrict__ cursor) {
    __shared__ int wsum[16];
    int tid = threadIdx.x, lane = tid & 63, w = tid >> 6;
    int carry = 0;
    for (int base = 0; base < NN; base += 1024) {
        int i = base + tid;
        int v = (i < NN) ? deg[i] : 0;
        int x = v;
#pragma unroll
        for (int off = 1; off < 64; off <<= 1) {
            int y = __shfl_up(x, off);
            if (lane >= off) x += y;
        }
        if (lane == 63) wsum[w] = x;
        __syncthreads();
        if (tid < 16) {
            int s = wsum[tid];
#pragma unroll
            for (int off = 1; off < 16; off <<= 1) {
                int y = __shfl_up(s, off);
                if (tid >= off) s += y;
            }
            wsum[tid] = s;
        }
        __syncthreads();
        int woff = w ? wsum[w - 1] : 0;
        int excl = carry + woff + x - v;
        if (i < NN) { row_ptr[i] = excl; cursor[i] = excl; }
        carry += wsum[15];
        __syncthreads();
    }
    if (tid == 0) row_ptr[NN] = carry;
}

__global__ void scatter_k(const int* __restrict__ src, const int* __restrict__ dst,
                          int* __restrict__ cursor, int* __restrict__ csr_src) {
    int i = blockIdx.x * 256 + threadIdx.x;
    if (i < EE) {
        int slot = atomicAdd(&cursor[dst[i]], 1);
        csr_src[slot] = src[i];
    }
}

// ---------------- attention logits el/er ----------------
__global__ __launch_bounds__(256) void eler1_k(const float* __restrict__ pos,
                                               const float* __restrict__ W1,
                                               const float* __restrict__ al,
                                               const float* __restrict__ ar,
                                               float* __restrict__ el,
                                               float* __restrict__ er) {
    int wid = blockIdx.x * 4 + (threadIdx.x >> 6);
    int lane = threadIdx.x & 63;
    if (wid >= NN) return;
    int f = lane * 4;
    float4 w0 = *(const float4*)&W1[f];
    float4 w1 = *(const float4*)&W1[256 + f];
    float4 a4 = *(const float4*)&al[f];
    float4 r4 = *(const float4*)&ar[f];
    float2 p = *(const float2*)&pos[wid * 2];
    float fx = p.x * w0.x + p.y * w1.x;
    float fy = p.x * w0.y + p.y * w1.y;
    float fz = p.x * w0.z + p.y * w1.z;
    float fw = p.x * w0.w + p.y * w1.w;
    float pl = fx * a4.x + fy * a4.y + fz * a4.z + fw * a4.w;
    float pr = fx * r4.x + fy * r4.y + fz * r4.z + fw * r4.w;
#pragma unroll
    for (int off = 1; off < 16; off <<= 1) {
        pl += __shfl_xor(pl, off);
        pr += __shfl_xor(pr, off);
    }
    if ((lane & 15) == 0) {
        int h = lane >> 4;
        el[wid * 4 + h] = pl;
        er[wid * 4 + h] = pr;
    }
}

__global__ __launch_bounds__(256) void eler_k(const float* __restrict__ feat,
                                              const float* __restrict__ al,
                                              const float* __restrict__ ar,
                                              float* __restrict__ el,
                                              float* __restrict__ er) {
    int wid = blockIdx.x * 4 + (threadIdx.x >> 6);
    int lane = threadIdx.x & 63;
    if (wid >= NN) return;
    int f = lane * 4;
    float4 f4 = *(const float4*)&feat[(size_t)wid * 256 + f];
    float4 a4 = *(const float4*)&al[f];
    float4 r4 = *(const float4*)&ar[f];
    float pl = f4.x * a4.x + f4.y * a4.y + f4.z * a4.z + f4.w * a4.w;
    float pr = f4.x * r4.x + f4.y * r4.y + f4.z * r4.z + f4.w * r4.w;
#pragma unroll
    for (int off = 1; off < 16; off <<= 1) {
        pl += __shfl_xor(pl, off);
        pr += __shfl_xor(pr, off);
    }
    if ((lane & 15) == 0) {
        int h = lane >> 4;
        el[wid * 4 + h] = pl;
        er[wid * 4 + h] = pr;
    }
}

// ---------------- aggregation: one wave per dst node ----------------
__global__ __launch_bounds__(256) void agg1_k(const float* __restrict__ pos,
                                              const float* __restrict__ W1,
                                              const float* __restrict__ resW1,
                                              const float* __restrict__ el,
                                              const float* __restrict__ er,
                                              const int* __restrict__ row_ptr,
                                              const int* __restrict__ csr_src,
                                              float* __restrict__ hout) {
    int wid = blockIdx.x * 4 + (threadIdx.x >> 6);
    int lane = threadIdx.x & 63;
    if (wid >= NN) return;
    int f = lane * 4;
    int start = row_ptr[wid], end = row_ptr[wid + 1];
    float4 er4 = *(const float4*)&er[wid * 4];

    float m0 = -1e30f, m1 = -1e30f, m2 = -1e30f, m3 = -1e30f;
    for (int s = start + lane; s < end; s += 64) {
        int sn = csr_src[s];
        float4 ev = *(const float4*)&el[sn * 4];
        m0 = fmaxf(m0, lrelu(ev.x + er4.x));
        m1 = fmaxf(m1, lrelu(ev.y + er4.y));
        m2 = fmaxf(m2, lrelu(ev.z + er4.z));
        m3 = fmaxf(m3, lrelu(ev.w + er4.w));
    }
#pragma unroll
    for (int off = 32; off; off >>= 1) {
        m0 = fmaxf(m0, __shfl_xor(m0, off));
        m1 = fmaxf(m1, __shfl_xor(m1, off));
        m2 = fmaxf(m2, __shfl_xor(m2, off));
        m3 = fmaxf(m3, __shfl_xor(m3, off));
    }
    float s0 = 0, s1 = 0, s2 = 0, s3 = 0;
    for (int s = start + lane; s < end; s += 64) {
        int sn = csr_src[s];
        float4 ev = *(const float4*)&el[sn * 4];
        s0 += __expf(lrelu(ev.x + er4.x) - m0);
        s1 += __expf(lrelu(ev.y + er4.y) - m1);
        s2 += __expf(lrelu(ev.z + er4.z) - m2);
        s3 += __expf(lrelu(ev.w + er4.w) - m3);
    }
#pragma unroll
    for (int off = 32; off; off >>= 1) {
        s0 += __shfl_xor(s0, off);
        s1 += __shfl_xor(s1, off);
        s2 += __shfl_xor(s2, off);
        s3 += __shfl_xor(s3, off);
    }
    float i0 = 1.f / fmaxf(s0, 1e-9f), i1 = 1.f / fmaxf(s1, 1e-9f);
    float i2 = 1.f / fmaxf(s2, 1e-9f), i3 = 1.f / fmaxf(s3, 1e-9f);

    int h = lane >> 4;
    float mh = (lane & 32) ? ((lane & 16) ? m3 : m2) : ((lane & 16) ? m1 : m0);
    float ih = (lane & 32) ? ((lane & 16) ? i3 : i2) : ((lane & 16) ? i1 : i0);
    float eh = (lane & 32) ? ((lane & 16) ? er4.w : er4.z) : ((lane & 16) ? er4.y : er4.x);

    float ap0 = 0.f, ap1 = 0.f;
    for (int s = start; s < end; ++s) {
        int sn = csr_src[s];
        float a = __expf(lrelu(el[sn * 4 + h] + eh) - mh) * ih;
        float2 p = *(const float2*)&pos[sn * 2];
        ap0 += a * p.x;
        ap1 += a * p.y;
    }
    float4 w0 = *(const float4*)&W1[f];
    float4 w1 = *(const float4*)&W1[256 + f];
    float4 rw0 = *(const float4*)&resW1[f];
    float4 rw1 = *(const float4*)&resW1[256 + f];
    float2 pd = *(const float2*)&pos[wid * 2];
    float4 o;
    o.x = fmaxf(ap0 * w0.x + ap1 * w1.x + pd.x * rw0.x + pd.y * rw1.x, 0.f);
    o.y = fmaxf(ap0 * w0.y + ap1 * w1.y + pd.x * rw0.y + pd.y * rw1.y, 0.f);
    o.z = fmaxf(ap0 * w0.z + ap1 * w1.z + pd.x * rw0.z + pd.y * rw1.z, 0.f);
    o.w = fmaxf(ap0 * w0.w + ap1 * w1.w + pd.x * rw0.w + pd.y * rw1.w, 0.f);
    *(float4*)&hout[(size_t)wid * 256 + f] = o;
}

__global__ __launch_bounds__(256) void agg_k(const float* __restrict__ feat,
                                             const float* __restrict__ el,
                                             const float* __restrict__ er,
                                             const int* __restrict__ row_ptr,
                                             const int* __restrict__ csr_src,
                                             float* __restrict__ hio) {
    int wid = blockIdx.x * 4 + (threadIdx.x >> 6);
    int lane = threadIdx.x & 63;
    if (wid >= NN) return;
    int f = lane * 4;
    int start = row_ptr[wid], end = row_ptr[wid + 1];
    float4 er4 = *(const float4*)&er[wid * 4];

    float m0 = -1e30f, m1 = -1e30f, m2 = -1e30f, m3 = -1e30f;
    for (int s = start + lane; s < end; s += 64) {
        int sn = csr_src[s];
        float4 ev = *(const float4*)&el[sn * 4];
        m0 = fmaxf(m0, lrelu(ev.x + er4.x));
        m1 = fmaxf(m1, lrelu(ev.y + er4.y));
        m2 = fmaxf(m2, lrelu(ev.z + er4.z));
        m3 = fmaxf(m3, lrelu(ev.w + er4.w));
    }
#pragma unroll
    for (int off = 32; off; off >>= 1) {
        m0 = fmaxf(m0, __shfl_xor(m0, off));
        m1 = fmaxf(m1, __shfl_xor(m1, off));
        m2 = fmaxf(m2, __shfl_xor(m2, off));
        m3 = fmaxf(m3, __shfl_xor(m3, off));
    }
    float s0 = 0, s1 = 0, s2 = 0, s3 = 0;
    for (int s = start + lane; s < end; s += 64) {
        int sn = csr_src[s];
        float4 ev = *(const float4*)&el[sn * 4];
        s0 += __expf(lrelu(ev.x + er4.x) - m0);
        s1 += __expf(lrelu(ev.y + er4.y) - m1);
        s2 += __expf(lrelu(ev.z + er4.z) - m2);
        s3 += __expf(lrelu(ev.w + er4.w) - m3);
    }
#pragma unroll
    for (int off = 32; off; off >>= 1) {
        s0 += __shfl_xor(s0, off);
        s1 += __shfl_xor(s1, off);
        s2 += __shfl_xor(s2, off);
        s3 += __shfl_xor(s3, off);
    }
    float i0 = 1.f / fmaxf(s0, 1e-9f), i1 = 1.f / fmaxf(s1, 1e-9f);
    float i2 = 1.f / fmaxf(s2, 1e-9f), i3 = 1.f / fmaxf(s3, 1e-9f);

    int h = lane >> 4;
    float mh = (lane & 32) ? ((lane & 16) ? m3 : m2) : ((lane & 16) ? m1 : m0);
    float ih = (lane & 32) ? ((lane & 16) ? i3 : i2) : ((lane & 16) ? i1 : i0);
    float eh = (lane & 32) ? ((lane & 16) ? er4.w : er4.z) : ((lane & 16) ? er4.y : er4.x);

    float4 acc = {0.f, 0.f, 0.f, 0.f};
    for (int s = start; s < end; ++s) {
        int sn = csr_src[s];
        float a = __expf(lrelu(el[sn * 4 + h] + eh) - mh) * ih;
        float4 v = *(const float4*)&feat[(size_t)sn * 256 + f];
        acc.x += a * v.x;
        acc.y += a * v.y;
        acc.z += a * v.z;
        acc.w += a * v.w;
    }
    float4 r = *(const float4*)&hio[(size_t)wid * 256 + f];
    float4 o;
    o.x = fmaxf(acc.x + r.x, 0.f);
    o.y = fmaxf(acc.y + r.y, 0.f);
    o.z = fmaxf(acc.z + r.z, 0.f);
    o.w = fmaxf(acc.w + r.w, 0.f);
    *(float4*)&hio[(size_t)wid * 256 + f] = o;
}

__global__ __launch_bounds__(256) void agg3_k(const float* __restrict__ feat,
                                              const float* __restrict__ el,
                                              const float* __restrict__ er,
                                              const int* __restrict__ row_ptr,
                                              const int* __restrict__ csr_src,
                                              const float* __restrict__ hres,
                                              float* __restrict__ hsmall) {
    int wid = blockIdx.x * 4 + (threadIdx.x >> 6);
    int lane = threadIdx.x & 63;
    if (wid >= NN) return;
    int f = lane * 4;
    int start = row_ptr[wid], end = row_ptr[wid + 1];
    float4 er4 = *(const float4*)&er[wid * 4];

    float m0 = -1e30f, m1 = -1e30f, m2 = -1e30f, m3 = -1e30f;
    for (int s = start + lane; s < end; s += 64) {
        int sn = csr_src[s];
        float4 ev = *(const float4*)&el[sn * 4];
        m0 = fmaxf(m0, lrelu(ev.x + er4.x));
        m1 = fmaxf(m1, lrelu(ev.y + er4.y));
        m2 = fmaxf(m2, lrelu(ev.z + er4.z));
        m3 = fmaxf(m3, lrelu(ev.w + er4.w));
    }
#pragma unroll
    for (int off = 32; off; off >>= 1) {
        m0 = fmaxf(m0, __shfl_xor(m0, off));
        m1 = fmaxf(m1, __shfl_xor(m1, off));
        m2 = fmaxf(m2, __shfl_xor(m2, off));
        m3 = fmaxf(m3, __shfl_xor(m3, off));
    }
    float s0 = 0, s1 = 0, s2 = 0, s3 = 0;
    for (int s = start + lane; s < end; s += 64) {
        int sn = csr_src[s];
        float4 ev = *(const float4*)&el[sn * 4];
        s0 += __expf(lrelu(ev.x + er4.x) - m0);
        s1 += __expf(lrelu(ev.y + er4.y) - m1);
        s2 += __expf(lrelu(ev.z + er4.z) - m2);
        s3 += __expf(lrelu(ev.w + er4.w) - m3);
    }
#pragma unroll
    for (int off = 32; off; off >>= 1) {
        s0 += __shfl_xor(s0, off);
        s1 += __shfl_xor(s1, off);
        s2 += __shfl_xor(s2, off);
        s3 += __shfl_xor(s3, off);
    }
    float i0 = 1.f / fmaxf(s0, 1e-9f), i1 = 1.f / fmaxf(s1, 1e-9f);
    float i2 = 1.f / fmaxf(s2, 1e-9f), i3 = 1.f / fmaxf(s3, 1e-9f);

    int h = lane >> 4;
    float mh = (lane & 32) ? ((lane & 16) ? m3 : m2) : ((lane & 16) ? m1 : m0);
    float ih = (lane & 32) ? ((lane & 16) ? i3 : i2) : ((lane & 16) ? i1 : i0);
    float eh = (lane & 32) ? ((lane & 16) ? er4.w : er4.z) : ((lane & 16) ? er4.y : er4.x);

    float4 acc = {0.f, 0.f, 0.f, 0.f};
    for (int s = start; s < end; ++s) {
        int sn = csr_src[s];
        float a = __expf(lrelu(el[sn * 4 + h] + eh) - mh) * ih;
        float4 v = *(const float4*)&feat[(size_t)sn * 256 + f];
        acc.x += a * v.x;
        acc.y += a * v.y;
        acc.z += a * v.z;
        acc.w += a * v.w;
    }
    float4 r = *(const float4*)&hres[(size_t)wid * 256 + f];
    float4 o;
    o.x = acc.x + r.x;
    o.y = acc.y + r.y;
    o.z = acc.z + r.z;
    o.w = acc.w + r.w;
    o.x += __shfl_xor(o.x, 16); o.y += __shfl_xor(o.y, 16);
    o.z += __shfl_xor(o.z, 16); o.w += __shfl_xor(o.w, 16);
    o.x += __shfl_xor(o.x, 32); o.y += __shfl_xor(o.y, 32);
    o.z += __shfl_xor(o.z, 32); o.w += __shfl_xor(o.w, 32);
    if (lane < 16) {
        float4 m4;
        m4.x = o.x * 0.25f; m4.y = o.y * 0.25f; m4.z = o.z * 0.25f; m4.w = o.w * 0.25f;
        *(float4*)&hsmall[(size_t)wid * 64 + lane * 4] = m4;
    }
}

// ---------------- dense GEMM [N,256] @ [256,256] f32, 128x128 tile ----------------
__global__ __launch_bounds__(256) void gemm128_k(const float* __restrict__ A,
                                                 const float* __restrict__ B,
                                                 float* __restrict__ C) {
    __shared__ __align__(16) float As[32][132];
    __shared__ __align__(16) float Bs[32][128];
    int tid = threadIdx.x;
    int tileM = blockIdx.x * 128;
    int tileN = blockIdx.y * 128;
    int arow = tid >> 1;
    int acol = (tid & 1) * 16;
    int brow = tid >> 3;
    int bcol = (tid & 7) * 16;
    int tx = tid & 15, ty = tid >> 4;
    float acc[8][8] = {};
    for (int k0 = 0; k0 < 256; k0 += 32) {
        int gr = tileM + arow;
#pragma unroll
        for (int q = 0; q < 4; ++q) {
            float4 a = {0.f, 0.f, 0.f, 0.f};
            if (gr < NN) a = *(const float4*)&A[(size_t)gr * 256 + k0 + acol + q * 4];
            As[acol + q * 4 + 0][arow] = a.x;
            As[acol + q * 4 + 1][arow] = a.y;
            As[acol + q * 4 + 2][arow] = a.z;
            As[acol + q * 4 + 3][arow] = a.w;
        }
#pragma unroll
        for (int q = 0; q < 4; ++q) {
            *(float4*)&Bs[brow][bcol + q * 4] =
                *(const float4*)&B[(size_t)(k0 + brow) * 256 + tileN + bcol + q * 4];
        }
        __syncthreads();
#pragma unroll
        for (int kk = 0; kk < 32; ++kk) {
            float ar[8], br[8];
            *(float4*)&ar[0] = *(const float4*)&As[kk][ty * 8];
            *(float4*)&ar[4] = *(const float4*)&As[kk][ty * 8 + 4];
            *(float4*)&br[0] = *(const float4*)&Bs[kk][tx * 8];
            *(float4*)&br[4] = *(const float4*)&Bs[kk][tx * 8 + 4];
#pragma unroll
            for (int i = 0; i < 8; ++i)
#pragma unroll
                for (int j = 0; j < 8; ++j)
                    acc[i][j] += ar[i] * br[j];
        }
        __syncthreads();
    }
#pragma unroll
    for (int i = 0; i < 8; ++i) {
        int row = tileM + ty * 8 + i;
        if (row < NN) {
            float4 o0, o1;
            o0.x = acc[i][0]; o0.y = acc[i][1]; o0.z = acc[i][2]; o0.w = acc[i][3];
            o1.x = acc[i][4]; o1.y = acc[i][5]; o1.z = acc[i][6]; o1.w = acc[i][7];
            *(float4*)&C[(size_t)row * 256 + tileN + tx * 8] = o0;
            *(float4*)&C[(size_t)row * 256 + tileN + tx * 8 + 4] = o1;
        }
    }
}

// ---------------- edge scoring MLP v3: LDS-tiled micro-GEMM, 64 edges/block ----------------
// Thread (eq=tid>>4, jq=tid&15) owns a 4-edge x 4-j f32 tile. No register arrays
// indexed at runtime -> no scratch. xT transposed in LDS so compute reads are b128.
__global__ __launch_bounds__(256) void edge_score3_k(const float* __restrict__ hs,
                                                     const int* __restrict__ src,
                                                     const int* __restrict__ dst,
                                                     const float* __restrict__ mW1,
                                                     const float* __restrict__ mb1,
                                                     const float* __restrict__ mW2,
                                                     const float* __restrict__ mb2,
                                                     float* __restrict__ out) {
    __shared__ __align__(16) float Ws[64 * 64];    // 16 KB
    __shared__ __align__(16) float xT[64][66];     // [k][edge], padded
    __shared__ __align__(16) float b1s[64];
    __shared__ __align__(16) float w2s[64];
    int tid = threadIdx.x;
    for (int i = tid * 4; i < 4096; i += 1024)
        *(float4*)&Ws[i] = *(const float4*)&mW1[i];
    if (tid < 64) { b1s[tid] = mb1[tid]; w2s[tid] = mW2[tid]; }

    // stage x = |h_src - h_dst| transposed: thread covers edge (tid>>2), k-quarter (tid&3)
    int e_loc = tid >> 2, q = tid & 3;
    int e = blockIdx.x * 64 + e_loc;               // EE % 64 == 0
    int s = src[e], d = dst[e];
    const float* rs = &hs[(size_t)s * 64 + q * 16];
    const float* rd = &hs[(size_t)d * 64 + q * 16];
#pragma unroll
    for (int i = 0; i < 4; ++i) {
        float4 a = *(const float4*)&rs[i * 4];
        float4 b = *(const float4*)&rd[i * 4];
        int k = q * 16 + i * 4;
        xT[k + 0][e_loc] = fabsf(a.x - b.x);
        xT[k + 1][e_loc] = fabsf(a.y - b.y);
        xT[k + 2][e_loc] = fabsf(a.z - b.z);
        xT[k + 3][e_loc] = fabsf(a.w - b.w);
    }
    __syncthreads();

    int eq = tid >> 4, jq = tid & 15;
    float4 bb = *(const float4*)&b1s[jq * 4];
    float4 acc0 = bb, acc1 = bb, acc2 = bb, acc3 = bb;
#pragma unroll
    for (int k = 0; k < 64; ++k) {
        float4 xv = *(const float4*)&xT[k][eq * 4];    // broadcast across 16 lanes
        float4 wv = *(const float4*)&Ws[k * 64 + jq * 4];
        acc0.x += xv.x * wv.x; acc0.y += xv.x * wv.y; acc0.z += xv.x * wv.z; acc0.w += xv.x * wv.w;
        acc1.x += xv.y * wv.x; acc1.y += xv.y * wv.y; acc1.z += xv.y * wv.z; acc1.w += xv.y * wv.w;
        acc2.x += xv.z * wv.x; acc2.y += xv.z * wv.y; acc2.z += xv.z * wv.z; acc2.w += xv.z * wv.w;
        acc3.x += xv.w * wv.x; acc3.y += xv.w * wv.y; acc3.z += xv.w * wv.z; acc3.w += xv.w * wv.w;
    }
    float4 w2 = *(const float4*)&w2s[jq * 4];
    float t0 = fmaxf(acc0.x, 0.f) * w2.x + fmaxf(acc0.y, 0.f) * w2.y +
               fmaxf(acc0.z, 0.f) * w2.z + fmaxf(acc0.w, 0.f) * w2.w;
    float t1 = fmaxf(acc1.x, 0.f) * w2.x + fmaxf(acc1.y, 0.f) * w2.y +
               fmaxf(acc1.z, 0.f) * w2.z + fmaxf(acc1.w, 0.f) * w2.w;
    float t2 = fmaxf(acc2.x, 0.f) * w2.x + fmaxf(acc2.y, 0.f) * w2.y +
               fmaxf(acc2.z, 0.f) * w2.z + fmaxf(acc2.w, 0.f) * w2.w;
    float t3 = fmaxf(acc3.x, 0.f) * w2.x + fmaxf(acc3.y, 0.f) * w2.y +
               fmaxf(acc3.z, 0.f) * w2.z + fmaxf(acc3.w, 0.f) * w2.w;
#pragma unroll
    for (int off = 1; off < 16; off <<= 1) {     // reduce over jq (wave-local)
        t0 += __shfl_xor(t0, off);
        t1 += __shfl_xor(t1, off);
        t2 += __shfl_xor(t2, off);
        t3 += __shfl_xor(t3, off);
    }
    if (jq == 0) {
        float bias = mb2[0];
        int base = blockIdx.x * 64 + eq * 4;
        out[base + 0] = 1.f / (1.f + __expf(-(t0 + bias)));
        out[base + 1] = 1.f / (1.f + __expf(-(t1 + bias)));
        out[base + 2] = 1.f / (1.f + __expf(-(t2 + bias)));
        out[base + 3] = 1.f / (1.f + __expf(-(t3 + bias)));
    }
}

extern "C" void kernel_launch(void* const* d_in, const int* in_sizes, int n_in,
                              void* d_out, int out_size, void* d_ws, size_t ws_size,
                              hipStream_t stream) {
    (void)in_sizes; (void)n_in; (void)out_size; (void)ws_size;
    const float* pos   = (const float*)d_in[0];
    const int*   src   = (const int*)d_in[1];
    const int*   dst   = (const int*)d_in[2];
    const float* W1    = (const float*)d_in[3];
    const float* al1   = (const float*)d_in[4];
    const float* ar1   = (const float*)d_in[5];
    const float* resW1 = (const float*)d_in[6];
    const float* W2    = (const float*)d_in[7];
    const float* al2   = (const float*)d_in[8];
    const float* ar2   = (const float*)d_in[9];
    const float* W3    = (const float*)d_in[10];
    const float* al3   = (const float*)d_in[11];
    const float* ar3   = (const float*)d_in[12];
    const float* mW1   = (const float*)d_in[13];
    const float* mb1   = (const float*)d_in[14];
    const float* mW2   = (const float*)d_in[15];
    const float* mb2   = (const float*)d_in[16];
    float* out = (float*)d_out;

    char* ws = (char*)d_ws;
    size_t off = 0;
    auto alloc = [&](size_t bytes) {
        void* p = ws + off;
        off += (bytes + 255) & ~(size_t)255;
        return p;
    };
    float* Hbuf   = (float*)alloc((size_t)NN * 256 * 4);
    float* FEAT   = (float*)alloc((size_t)NN * 256 * 4);
    float* hsmall = (float*)alloc((size_t)NN * 64 * 4);
    float* el     = (float*)alloc((size_t)NN * 4 * 4);
    float* er     = (float*)alloc((size_t)NN * 4 * 4);
    int* deg      = (int*)alloc((size_t)NN * 4);
    int* row_ptr  = (int*)alloc((size_t)(NN + 1) * 4);
    int* cursor   = (int*)alloc((size_t)NN * 4);
    int* csr      = (int*)alloc((size_t)EE * 4);

    hipMemsetAsync(deg, 0, (size_t)NN * 4, stream);
    hist_k<<<(EE + 255) / 256, 256, 0, stream>>>(dst, deg);
    scan_k<<<1, 1024, 0, stream>>>(deg, row_ptr, cursor);
    scatter_k<<<(EE + 255) / 256, 256, 0, stream>>>(src, dst, cursor, csr);

    // layer 1
    eler1_k<<<NN / 4 + 1, 256, 0, stream>>>(pos, W1, al1, ar1, el, er);
    agg1_k<<<NN / 4 + 1, 256, 0, stream>>>(pos, W1, resW1, el, er, row_ptr, csr, Hbuf);

    dim3 ggrid((NN + 127) / 128, 2);
    // layer 2
    gemm128_k<<<ggrid, 256, 0, stream>>>(Hbuf, W2, FEAT);
    eler_k<<<NN / 4 + 1, 256, 0, stream>>>(FEAT, al2, ar2, el, er);
    agg_k<<<NN / 4 + 1, 256, 0, stream>>>(FEAT, el, er, row_ptr, csr, Hbuf);

    // layer 3
    gemm128_k<<<ggrid, 256, 0, stream>>>(Hbuf, W3, FEAT);
    eler_k<<<NN / 4 + 1, 256, 0, stream>>>(FEAT, al3, ar3, el, er);
    agg3_k<<<NN / 4 + 1, 256, 0, stream>>>(FEAT, el, er, row_ptr, csr, Hbuf, hsmall);

    // edge MLP
    edge_score3_k<<<EE / 64, 256, 0, stream>>>(hsmall, src, dst, mW1, mb1, mW2, mb2, out);
}

// Round 5
// 734.469 us; speedup vs baseline: 1.6034x; 1.3230x over previous
//
#include <hip/hip_runtime.h>
#include <hip/hip_bf16.h>

#define NN 50000
#define EE 800000

typedef short short8 __attribute__((ext_vector_type(8)));
typedef float f32x4 __attribute__((ext_vector_type(4)));

__device__ __forceinline__ float lrelu(float x) { return x > 0.f ? x : 0.2f * x; }

__device__ __forceinline__ unsigned short f2bf(float x) {
    __hip_bfloat16 b = __float2bfloat16(x);
    return *(unsigned short*)&b;
}

// ---------------- CSR build ----------------
__global__ void hist_k(const int* __restrict__ dst, int* __restrict__ deg) {
    int i = blockIdx.x * 256 + threadIdx.x;
    if (i < EE) atomicAdd(&deg[dst[i]], 1);
}

__global__ __launch_bounds__(1024) void scan_k(const int* __restrict__ deg,
                                               int* __restrict__ row_ptr,
                                               int* __restrict__ cursor) {
    __shared__ int wsum[16];
    int tid = threadIdx.x, lane = tid & 63, w = tid >> 6;
    int carry = 0;
    for (int base = 0; base < NN; base += 1024) {
        int i = base + tid;
        int v = (i < NN) ? deg[i] : 0;
        int x = v;
#pragma unroll
        for (int off = 1; off < 64; off <<= 1) {
            int y = __shfl_up(x, off);
            if (lane >= off) x += y;
        }
        if (lane == 63) wsum[w] = x;
        __syncthreads();
        if (tid < 16) {
            int s = wsum[tid];
#pragma unroll
            for (int off = 1; off < 16; off <<= 1) {
                int y = __shfl_up(s, off);
                if (tid >= off) s += y;
            }
            wsum[tid] = s;
        }
        __syncthreads();
        int woff = w ? wsum[w - 1] : 0;
        int excl = carry + woff + x - v;
        if (i < NN) { row_ptr[i] = excl; cursor[i] = excl; }
        carry += wsum[15];
        __syncthreads();
    }
    if (tid == 0) row_ptr[NN] = carry;
}

__global__ void scatter_k(const int* __restrict__ src, const int* __restrict__ dst,
                          int* __restrict__ cursor, int* __restrict__ csr_src) {
    int i = blockIdx.x * 256 + threadIdx.x;
    if (i < EE) {
        int slot = atomicAdd(&cursor[dst[i]], 1);
        csr_src[slot] = src[i];
    }
}

// ---------------- W2/W3 -> bf16, transposed BT[n][k] ----------------
__global__ __launch_bounds__(256) void bconv_k(const float* __restrict__ W2,
                                               const float* __restrict__ W3,
                                               unsigned short* __restrict__ BT2,
                                               unsigned short* __restrict__ BT3) {
    int tid = blockIdx.x * 256 + threadIdx.x;   // 65536
    int k = tid & 255, n = tid >> 8;
    BT2[n * 256 + k] = f2bf(W2[k * 256 + n]);
    BT3[n * 256 + k] = f2bf(W3[k * 256 + n]);
}

// ---------------- attention logits el/er ----------------
__global__ __launch_bounds__(256) void eler1_k(const float* __restrict__ pos,
                                               const float* __restrict__ W1,
                                               const float* __restrict__ al,
                                               const float* __restrict__ ar,
                                               float* __restrict__ el,
                                               float* __restrict__ er) {
    int wid = blockIdx.x * 4 + (threadIdx.x >> 6);
    int lane = threadIdx.x & 63;
    if (wid >= NN) return;
    int f = lane * 4;
    float4 w0 = *(const float4*)&W1[f];
    float4 w1 = *(const float4*)&W1[256 + f];
    float4 a4 = *(const float4*)&al[f];
    float4 r4 = *(const float4*)&ar[f];
    float2 p = *(const float2*)&pos[wid * 2];
    float fx = p.x * w0.x + p.y * w1.x;
    float fy = p.x * w0.y + p.y * w1.y;
    float fz = p.x * w0.z + p.y * w1.z;
    float fw = p.x * w0.w + p.y * w1.w;
    float pl = fx * a4.x + fy * a4.y + fz * a4.z + fw * a4.w;
    float pr = fx * r4.x + fy * r4.y + fz * r4.z + fw * r4.w;
#pragma unroll
    for (int off = 1; off < 16; off <<= 1) {
        pl += __shfl_xor(pl, off);
        pr += __shfl_xor(pr, off);
    }
    if ((lane & 15) == 0) {
        int h = lane >> 4;
        el[wid * 4 + h] = pl;
        er[wid * 4 + h] = pr;
    }
}

__global__ __launch_bounds__(256) void eler_k(const float* __restrict__ feat,
                                              const float* __restrict__ al,
                                              const float* __restrict__ ar,
                                              float* __restrict__ el,
                                              float* __restrict__ er) {
    int wid = blockIdx.x * 4 + (threadIdx.x >> 6);
    int lane = threadIdx.x & 63;
    if (wid >= NN) return;
    int f = lane * 4;
    float4 f4 = *(const float4*)&feat[(size_t)wid * 256 + f];
    float4 a4 = *(const float4*)&al[f];
    float4 r4 = *(const float4*)&ar[f];
    float pl = f4.x * a4.x + f4.y * a4.y + f4.z * a4.z + f4.w * a4.w;
    float pr = f4.x * r4.x + f4.y * r4.y + f4.z * r4.z + f4.w * r4.w;
#pragma unroll
    for (int off = 1; off < 16; off <<= 1) {
        pl += __shfl_xor(pl, off);
        pr += __shfl_xor(pr, off);
    }
    if ((lane & 15) == 0) {
        int h = lane >> 4;
        el[wid * 4 + h] = pl;
        er[wid * 4 + h] = pr;
    }
}

// ---------------- aggregation: one wave per dst node ----------------
__global__ __launch_bounds__(256) void agg1_k(const float* __restrict__ pos,
                                              const float* __restrict__ W1,
                                              const float* __restrict__ resW1,
                                              const float* __restrict__ el,
                                              const float* __restrict__ er,
                                              const int* __restrict__ row_ptr,
                                              const int* __restrict__ csr_src,
                                              float* __restrict__ hout,
                                              unsigned short* __restrict__ hb16) {
    int wid = blockIdx.x * 4 + (threadIdx.x >> 6);
    int lane = threadIdx.x & 63;
    if (wid >= NN) return;
    int f = lane * 4;
    int start = row_ptr[wid], end = row_ptr[wid + 1];
    float4 er4 = *(const float4*)&er[wid * 4];

    float m0 = -1e30f, m1 = -1e30f, m2 = -1e30f, m3 = -1e30f;
    for (int s = start + lane; s < end; s += 64) {
        int sn = csr_src[s];
        float4 ev = *(const float4*)&el[sn * 4];
        m0 = fmaxf(m0, lrelu(ev.x + er4.x));
        m1 = fmaxf(m1, lrelu(ev.y + er4.y));
        m2 = fmaxf(m2, lrelu(ev.z + er4.z));
        m3 = fmaxf(m3, lrelu(ev.w + er4.w));
    }
#pragma unroll
    for (int off = 32; off; off >>= 1) {
        m0 = fmaxf(m0, __shfl_xor(m0, off));
        m1 = fmaxf(m1, __shfl_xor(m1, off));
        m2 = fmaxf(m2, __shfl_xor(m2, off));
        m3 = fmaxf(m3, __shfl_xor(m3, off));
    }
    float s0 = 0, s1 = 0, s2 = 0, s3 = 0;
    for (int s = start + lane; s < end; s += 64) {
        int sn = csr_src[s];
        float4 ev = *(const float4*)&el[sn * 4];
        s0 += __expf(lrelu(ev.x + er4.x) - m0);
        s1 += __expf(lrelu(ev.y + er4.y) - m1);
        s2 += __expf(lrelu(ev.z + er4.z) - m2);
        s3 += __expf(lrelu(ev.w + er4.w) - m3);
    }
#pragma unroll
    for (int off = 32; off; off >>= 1) {
        s0 += __shfl_xor(s0, off);
        s1 += __shfl_xor(s1, off);
        s2 += __shfl_xor(s2, off);
        s3 += __shfl_xor(s3, off);
    }
    float i0 = 1.f / fmaxf(s0, 1e-9f), i1 = 1.f / fmaxf(s1, 1e-9f);
    float i2 = 1.f / fmaxf(s2, 1e-9f), i3 = 1.f / fmaxf(s3, 1e-9f);

    int h = lane >> 4;
    float mh = (lane & 32) ? ((lane & 16) ? m3 : m2) : ((lane & 16) ? m1 : m0);
    float ih = (lane & 32) ? ((lane & 16) ? i3 : i2) : ((lane & 16) ? i1 : i0);
    float eh = (lane & 32) ? ((lane & 16) ? er4.w : er4.z) : ((lane & 16) ? er4.y : er4.x);

    float ap0 = 0.f, ap1 = 0.f;
    for (int s = start; s < end; ++s) {
        int sn = csr_src[s];
        float a = __expf(lrelu(el[sn * 4 + h] + eh) - mh) * ih;
        float2 p = *(const float2*)&pos[sn * 2];
        ap0 += a * p.x;
        ap1 += a * p.y;
    }
    float4 w0 = *(const float4*)&W1[f];
    float4 w1 = *(const float4*)&W1[256 + f];
    float4 rw0 = *(const float4*)&resW1[f];
    float4 rw1 = *(const float4*)&resW1[256 + f];
    float2 pd = *(const float2*)&pos[wid * 2];
    float4 o;
    o.x = fmaxf(ap0 * w0.x + ap1 * w1.x + pd.x * rw0.x + pd.y * rw1.x, 0.f);
    o.y = fmaxf(ap0 * w0.y + ap1 * w1.y + pd.x * rw0.y + pd.y * rw1.y, 0.f);
    o.z = fmaxf(ap0 * w0.z + ap1 * w1.z + pd.x * rw0.z + pd.y * rw1.z, 0.f);
    o.w = fmaxf(ap0 * w0.w + ap1 * w1.w + pd.x * rw0.w + pd.y * rw1.w, 0.f);
    *(float4*)&hout[(size_t)wid * 256 + f] = o;
    ushort4 ob;
    ob.x = f2bf(o.x); ob.y = f2bf(o.y); ob.z = f2bf(o.z); ob.w = f2bf(o.w);
    *(ushort4*)&hb16[(size_t)wid * 256 + f] = ob;
}

__global__ __launch_bounds__(256) void agg_k(const float* __restrict__ feat,
                                             const float* __restrict__ el,
                                             const float* __restrict__ er,
                                             const int* __restrict__ row_ptr,
                                             const int* __restrict__ csr_src,
                                             float* __restrict__ hio,
                                             unsigned short* __restrict__ hb16) {
    int wid = blockIdx.x * 4 + (threadIdx.x >> 6);
    int lane = threadIdx.x & 63;
    if (wid >= NN) return;
    int f = lane * 4;
    int start = row_ptr[wid], end = row_ptr[wid + 1];
    float4 er4 = *(const float4*)&er[wid * 4];

    float m0 = -1e30f, m1 = -1e30f, m2 = -1e30f, m3 = -1e30f;
    for (int s = start + lane; s < end; s += 64) {
        int sn = csr_src[s];
        float4 ev = *(const float4*)&el[sn * 4];
        m0 = fmaxf(m0, lrelu(ev.x + er4.x));
        m1 = fmaxf(m1, lrelu(ev.y + er4.y));
        m2 = fmaxf(m2, lrelu(ev.z + er4.z));
        m3 = fmaxf(m3, lrelu(ev.w + er4.w));
    }
#pragma unroll
    for (int off = 32; off; off >>= 1) {
        m0 = fmaxf(m0, __shfl_xor(m0, off));
        m1 = fmaxf(m1, __shfl_xor(m1, off));
        m2 = fmaxf(m2, __shfl_xor(m2, off));
        m3 = fmaxf(m3, __shfl_xor(m3, off));
    }
    float s0 = 0, s1 = 0, s2 = 0, s3 = 0;
    for (int s = start + lane; s < end; s += 64) {
        int sn = csr_src[s];
        float4 ev = *(const float4*)&el[sn * 4];
        s0 += __expf(lrelu(ev.x + er4.x) - m0);
        s1 += __expf(lrelu(ev.y + er4.y) - m1);
        s2 += __expf(lrelu(ev.z + er4.z) - m2);
        s3 += __expf(lrelu(ev.w + er4.w) - m3);
    }
#pragma unroll
    for (int off = 32; off; off >>= 1) {
        s0 += __shfl_xor(s0, off);
        s1 += __shfl_xor(s1, off);
        s2 += __shfl_xor(s2, off);
        s3 += __shfl_xor(s3, off);
    }
    float i0 = 1.f / fmaxf(s0, 1e-9f), i1 = 1.f / fmaxf(s1, 1e-9f);
    float i2 = 1.f / fmaxf(s2, 1e-9f), i3 = 1.f / fmaxf(s3, 1e-9f);

    int h = lane >> 4;
    float mh = (lane & 32) ? ((lane & 16) ? m3 : m2) : ((lane & 16) ? m1 : m0);
    float ih = (lane & 32) ? ((lane & 16) ? i3 : i2) : ((lane & 16) ? i1 : i0);
    float eh = (lane & 32) ? ((lane & 16) ? er4.w : er4.z) : ((lane & 16) ? er4.y : er4.x);

    float4 acc = {0.f, 0.f, 0.f, 0.f};
    for (int s = start; s < end; ++s) {
        int sn = csr_src[s];
        float a = __expf(lrelu(el[sn * 4 + h] + eh) - mh) * ih;
        float4 v = *(const float4*)&feat[(size_t)sn * 256 + f];
        acc.x += a * v.x;
        acc.y += a * v.y;
        acc.z += a * v.z;
        acc.w += a * v.w;
    }
    float4 r = *(const float4*)&hio[(size_t)wid * 256 + f];
    float4 o;
    o.x = fmaxf(acc.x + r.x, 0.f);
    o.y = fmaxf(acc.y + r.y, 0.f);
    o.z = fmaxf(acc.z + r.z, 0.f);
    o.w = fmaxf(acc.w + r.w, 0.f);
    *(float4*)&hio[(size_t)wid * 256 + f] = o;
    ushort4 ob;
    ob.x = f2bf(o.x); ob.y = f2bf(o.y); ob.z = f2bf(o.z); ob.w = f2bf(o.w);
    *(ushort4*)&hb16[(size_t)wid * 256 + f] = ob;
}

__global__ __launch_bounds__(256) void agg3_k(const float* __restrict__ feat,
                                              const float* __restrict__ el,
                                              const float* __restrict__ er,
                                              const int* __restrict__ row_ptr,
                                              const int* __restrict__ csr_src,
                                              const float* __restrict__ hres,
                                              float* __restrict__ hsmall) {
    int wid = blockIdx.x * 4 + (threadIdx.x >> 6);
    int lane = threadIdx.x & 63;
    if (wid >= NN) return;
    int f = lane * 4;
    int start = row_ptr[wid], end = row_ptr[wid + 1];
    float4 er4 = *(const float4*)&er[wid * 4];

    float m0 = -1e30f, m1 = -1e30f, m2 = -1e30f, m3 = -1e30f;
    for (int s = start + lane; s < end; s += 64) {
        int sn = csr_src[s];
        float4 ev = *(const float4*)&el[sn * 4];
        m0 = fmaxf(m0, lrelu(ev.x + er4.x));
        m1 = fmaxf(m1, lrelu(ev.y + er4.y));
        m2 = fmaxf(m2, lrelu(ev.z + er4.z));
        m3 = fmaxf(m3, lrelu(ev.w + er4.w));
    }
#pragma unroll
    for (int off = 32; off; off >>= 1) {
        m0 = fmaxf(m0, __shfl_xor(m0, off));
        m1 = fmaxf(m1, __shfl_xor(m1, off));
        m2 = fmaxf(m2, __shfl_xor(m2, off));
        m3 = fmaxf(m3, __shfl_xor(m3, off));
    }
    float s0 = 0, s1 = 0, s2 = 0, s3 = 0;
    for (int s = start + lane; s < end; s += 64) {
        int sn = csr_src[s];
        float4 ev = *(const float4*)&el[sn * 4];
        s0 += __expf(lrelu(ev.x + er4.x) - m0);
        s1 += __expf(lrelu(ev.y + er4.y) - m1);
        s2 += __expf(lrelu(ev.z + er4.z) - m2);
        s3 += __expf(lrelu(ev.w + er4.w) - m3);
    }
#pragma unroll
    for (int off = 32; off; off >>= 1) {
        s0 += __shfl_xor(s0, off);
        s1 += __shfl_xor(s1, off);
        s2 += __shfl_xor(s2, off);
        s3 += __shfl_xor(s3, off);
    }
    float i0 = 1.f / fmaxf(s0, 1e-9f), i1 = 1.f / fmaxf(s1, 1e-9f);
    float i2 = 1.f / fmaxf(s2, 1e-9f), i3 = 1.f / fmaxf(s3, 1e-9f);

    int h = lane >> 4;
    float mh = (lane & 32) ? ((lane & 16) ? m3 : m2) : ((lane & 16) ? m1 : m0);
    float ih = (lane & 32) ? ((lane & 16) ? i3 : i2) : ((lane & 16) ? i1 : i0);
    float eh = (lane & 32) ? ((lane & 16) ? er4.w : er4.z) : ((lane & 16) ? er4.y : er4.x);

    float4 acc = {0.f, 0.f, 0.f, 0.f};
    for (int s = start; s < end; ++s) {
        int sn = csr_src[s];
        float a = __expf(lrelu(el[sn * 4 + h] + eh) - mh) * ih;
        float4 v = *(const float4*)&feat[(size_t)sn * 256 + f];
        acc.x += a * v.x;
        acc.y += a * v.y;
        acc.z += a * v.z;
        acc.w += a * v.w;
    }
    float4 r = *(const float4*)&hres[(size_t)wid * 256 + f];
    float4 o;
    o.x = acc.x + r.x;
    o.y = acc.y + r.y;
    o.z = acc.z + r.z;
    o.w = acc.w + r.w;
    o.x += __shfl_xor(o.x, 16); o.y += __shfl_xor(o.y, 16);
    o.z += __shfl_xor(o.z, 16); o.w += __shfl_xor(o.w, 16);
    o.x += __shfl_xor(o.x, 32); o.y += __shfl_xor(o.y, 32);
    o.z += __shfl_xor(o.z, 32); o.w += __shfl_xor(o.w, 32);
    if (lane < 16) {
        float4 m4;
        m4.x = o.x * 0.25f; m4.y = o.y * 0.25f; m4.z = o.z * 0.25f; m4.w = o.w * 0.25f;
        *(float4*)&hsmall[(size_t)wid * 64 + lane * 4] = m4;
    }
}

// ---------------- MFMA GEMM: [N,256]bf16 @ BT[n][k]bf16 -> [N,256]f32 ----------------
// 128x128 tile, 4 waves (2x2), each wave 64x64 = 4x4 fragments of 16x16x32.
// LDS rows padded to 40 shorts (80B): fragment b128 reads spread over 8 bank-quads.
__global__ __launch_bounds__(256) void gemm_mfma_k(const unsigned short* __restrict__ Ab,
                                                   const unsigned short* __restrict__ BT,
                                                   float* __restrict__ C) {
    __shared__ __align__(16) short As[128 * 40];
    __shared__ __align__(16) short Bs[128 * 40];
    int tid = threadIdx.x;
    int lane = tid & 63, wave = tid >> 6;
    int wr = wave >> 1, wc = wave & 1;
    int tileM = blockIdx.x * 128;
    int tileN = blockIdx.y * 128;

    int srow = tid >> 1, sko = (tid & 1) * 16;       // staging: 32B per thread
    int fm = lane & 15, kg = lane >> 4;              // fragment row/col, k-group

    f32x4 acc[4][4];
#pragma unroll
    for (int i = 0; i < 4; ++i)
#pragma unroll
        for (int j = 0; j < 4; ++j) acc[i][j] = (f32x4){0.f, 0.f, 0.f, 0.f};

    for (int k0 = 0; k0 < 256; k0 += 32) {
        int gr = tileM + srow;
        short8 a0 = (short8)0, a1 = (short8)0;
        if (gr < NN) {
            a0 = *(const short8*)&Ab[(size_t)gr * 256 + k0 + sko];
            a1 = *(const short8*)&Ab[(size_t)gr * 256 + k0 + sko + 8];
        }
        *(short8*)&As[srow * 40 + sko] = a0;
        *(short8*)&As[srow * 40 + sko + 8] = a1;
        short8 b0 = *(const short8*)&BT[(size_t)(tileN + srow) * 256 + k0 + sko];
        short8 b1 = *(const short8*)&BT[(size_t)(tileN + srow) * 256 + k0 + sko + 8];
        *(short8*)&Bs[srow * 40 + sko] = b0;
        *(short8*)&Bs[srow * 40 + sko + 8] = b1;
        __syncthreads();

        short8 afr[4], bfr[4];
#pragma unroll
        for (int mi = 0; mi < 4; ++mi)
            afr[mi] = *(const short8*)&As[(wr * 64 + mi * 16 + fm) * 40 + kg * 8];
#pragma unroll
        for (int ni = 0; ni < 4; ++ni)
            bfr[ni] = *(const short8*)&Bs[(wc * 64 + ni * 16 + fm) * 40 + kg * 8];
#pragma unroll
        for (int mi = 0; mi < 4; ++mi)
#pragma unroll
            for (int ni = 0; ni < 4; ++ni)
                acc[mi][ni] = __builtin_amdgcn_mfma_f32_16x16x32_bf16(
                    afr[mi], bfr[ni], acc[mi][ni], 0, 0, 0);
        __syncthreads();
    }

#pragma unroll
    for (int mi = 0; mi < 4; ++mi) {
#pragma unroll
        for (int ni = 0; ni < 4; ++ni) {
            int col = tileN + wc * 64 + ni * 16 + fm;
#pragma unroll
            for (int r = 0; r < 4; ++r) {
                int row = tileM + wr * 64 + mi * 16 + kg * 4 + r;
                if (row < NN) C[(size_t)row * 256 + col] = acc[mi][ni][r];
            }
        }
    }
}

// ---------------- edge scoring MLP v3: LDS-tiled micro-GEMM, 64 edges/block ----------------
__global__ __launch_bounds__(256) void edge_score3_k(const float* __restrict__ hs,
                                                     const int* __restrict__ src,
                                                     const int* __restrict__ dst,
                                                     const float* __restrict__ mW1,
                                                     const float* __restrict__ mb1,
                                                     const float* __restrict__ mW2,
                                                     const float* __restrict__ mb2,
                                                     float* __restrict__ out) {
    __shared__ __align__(16) float Ws[64 * 64];
    __shared__ __align__(16) float xT[64][66];
    __shared__ __align__(16) float b1s[64];
    __shared__ __align__(16) float w2s[64];
    int tid = threadIdx.x;
    for (int i = tid * 4; i < 4096; i += 1024)
        *(float4*)&Ws[i] = *(const float4*)&mW1[i];
    if (tid < 64) { b1s[tid] = mb1[tid]; w2s[tid] = mW2[tid]; }

    int e_loc = tid >> 2, q = tid & 3;
    int e = blockIdx.x * 64 + e_loc;
    int s = src[e], d = dst[e];
    const float* rs = &hs[(size_t)s * 64 + q * 16];
    const float* rd = &hs[(size_t)d * 64 + q * 16];
#pragma unroll
    for (int i = 0; i < 4; ++i) {
        float4 a = *(const float4*)&rs[i * 4];
        float4 b = *(const float4*)&rd[i * 4];
        int k = q * 16 + i * 4;
        xT[k + 0][e_loc] = fabsf(a.x - b.x);
        xT[k + 1][e_loc] = fabsf(a.y - b.y);
        xT[k + 2][e_loc] = fabsf(a.z - b.z);
        xT[k + 3][e_loc] = fabsf(a.w - b.w);
    }
    __syncthreads();

    int eq = tid >> 4, jq = tid & 15;
    float4 bb = *(const float4*)&b1s[jq * 4];
    float4 acc0 = bb, acc1 = bb, acc2 = bb, acc3 = bb;
#pragma unroll
    for (int k = 0; k < 64; ++k) {
        float4 xv = *(const float4*)&xT[k][eq * 4];
        float4 wv = *(const float4*)&Ws[k * 64 + jq * 4];
        acc0.x += xv.x * wv.x; acc0.y += xv.x * wv.y; acc0.z += xv.x * wv.z; acc0.w += xv.x * wv.w;
        acc1.x += xv.y * wv.x; acc1.y += xv.y * wv.y; acc1.z += xv.y * wv.z; acc1.w += xv.y * wv.w;
        acc2.x += xv.z * wv.x; acc2.y += xv.z * wv.y; acc2.z += xv.z * wv.z; acc2.w += xv.z * wv.w;
        acc3.x += xv.w * wv.x; acc3.y += xv.w * wv.y; acc3.z += xv.w * wv.z; acc3.w += xv.w * wv.w;
    }
    float4 w2 = *(const float4*)&w2s[jq * 4];
    float t0 = fmaxf(acc0.x, 0.f) * w2.x + fmaxf(acc0.y, 0.f) * w2.y +
               fmaxf(acc0.z, 0.f) * w2.z + fmaxf(acc0.w, 0.f) * w2.w;
    float t1 = fmaxf(acc1.x, 0.f) * w2.x + fmaxf(acc1.y, 0.f) * w2.y +
               fmaxf(acc1.z, 0.f) * w2.z + fmaxf(acc1.w, 0.f) * w2.w;
    float t2 = fmaxf(acc2.x, 0.f) * w2.x + fmaxf(acc2.y, 0.f) * w2.y +
               fmaxf(acc2.z, 0.f) * w2.z + fmaxf(acc2.w, 0.f) * w2.w;
    float t3 = fmaxf(acc3.x, 0.f) * w2.x + fmaxf(acc3.y, 0.f) * w2.y +
               fmaxf(acc3.z, 0.f) * w2.z + fmaxf(acc3.w, 0.f) * w2.w;
#pragma unroll
    for (int off = 1; off < 16; off <<= 1) {
        t0 += __shfl_xor(t0, off);
        t1 += __shfl_xor(t1, off);
        t2 += __shfl_xor(t2, off);
        t3 += __shfl_xor(t3, off);
    }
    if (jq == 0) {
        float bias = mb2[0];
        int base = blockIdx.x * 64 + eq * 4;
        out[base + 0] = 1.f / (1.f + __expf(-(t0 + bias)));
        out[base + 1] = 1.f / (1.f + __expf(-(t1 + bias)));
        out[base + 2] = 1.f / (1.f + __expf(-(t2 + bias)));
        out[base + 3] = 1.f / (1.f + __expf(-(t3 + bias)));
    }
}

extern "C" void kernel_launch(void* const* d_in, const int* in_sizes, int n_in,
                              void* d_out, int out_size, void* d_ws, size_t ws_size,
                              hipStream_t stream) {
    (void)in_sizes; (void)n_in; (void)out_size; (void)ws_size;
    const float* pos   = (const float*)d_in[0];
    const int*   src   = (const int*)d_in[1];
    const int*   dst   = (const int*)d_in[2];
    const float* W1    = (const float*)d_in[3];
    const float* al1   = (const float*)d_in[4];
    const float* ar1   = (const float*)d_in[5];
    const float* resW1 = (const float*)d_in[6];
    const float* W2    = (const float*)d_in[7];
    const float* al2   = (const float*)d_in[8];
    const float* ar2   = (const float*)d_in[9];
    const float* W3    = (const float*)d_in[10];
    const float* al3   = (const float*)d_in[11];
    const float* ar3   = (const float*)d_in[12];
    const float* mW1   = (const float*)d_in[13];
    const float* mb1   = (const float*)d_in[14];
    const float* mW2   = (const float*)d_in[15];
    const float* mb2   = (const float*)d_in[16];
    float* out = (float*)d_out;

    char* ws = (char*)d_ws;
    size_t off = 0;
    auto alloc = [&](size_t bytes) {
        void* p = ws + off;
        off += (bytes + 255) & ~(size_t)255;
        return p;
    };
    float* Hbuf            = (float*)alloc((size_t)NN * 256 * 4);
    float* FEAT            = (float*)alloc((size_t)NN * 256 * 4);
    unsigned short* Hb16   = (unsigned short*)alloc((size_t)NN * 256 * 2);
    unsigned short* BT2    = (unsigned short*)alloc((size_t)256 * 256 * 2);
    unsigned short* BT3    = (unsigned short*)alloc((size_t)256 * 256 * 2);
    float* hsmall = (float*)alloc((size_t)NN * 64 * 4);
    float* el     = (float*)alloc((size_t)NN * 4 * 4);
    float* er     = (float*)alloc((size_t)NN * 4 * 4);
    int* deg      = (int*)alloc((size_t)NN * 4);
    int* row_ptr  = (int*)alloc((size_t)(NN + 1) * 4);
    int* cursor   = (int*)alloc((size_t)NN * 4);
    int* csr      = (int*)alloc((size_t)EE * 4);

    hipMemsetAsync(deg, 0, (size_t)NN * 4, stream);
    hist_k<<<(EE + 255) / 256, 256, 0, stream>>>(dst, deg);
    scan_k<<<1, 1024, 0, stream>>>(deg, row_ptr, cursor);
    scatter_k<<<(EE + 255) / 256, 256, 0, stream>>>(src, dst, cursor, csr);
    bconv_k<<<256, 256, 0, stream>>>(W2, W3, BT2, BT3);

    // layer 1
    eler1_k<<<NN / 4 + 1, 256, 0, stream>>>(pos, W1, al1, ar1, el, er);
    agg1_k<<<NN / 4 + 1, 256, 0, stream>>>(pos, W1, resW1, el, er, row_ptr, csr, Hbuf, Hb16);

    dim3 ggrid((NN + 127) / 128, 2);
    // layer 2
    gemm_mfma_k<<<ggrid, 256, 0, stream>>>(Hb16, BT2, FEAT);
    eler_k<<<NN / 4 + 1, 256, 0, stream>>>(FEAT, al2, ar2, el, er);
    agg_k<<<NN / 4 + 1, 256, 0, stream>>>(FEAT, el, er, row_ptr, csr, Hbuf, Hb16);

    // layer 3
    gemm_mfma_k<<<ggrid, 256, 0, stream>>>(Hb16, BT3, FEAT);
    eler_k<<<NN / 4 + 1, 256, 0, stream>>>(FEAT, al3, ar3, el, er);
    agg3_k<<<NN / 4 + 1, 256, 0, stream>>>(FEAT, el, er, row_ptr, csr, Hbuf, hsmall);

    // edge MLP
    edge_score3_k<<<EE / 64, 256, 0, stream>>>(hsmall, src, dst, mW1, mb1, mW2, mb2, out);
}

// Round 6
// 685.679 us; speedup vs baseline: 1.7175x; 1.0712x over previous
//
#include <hip/hip_runtime.h>
#include <hip/hip_bf16.h>

#define NN 50000
#define EE 800000

typedef short short8 __attribute__((ext_vector_type(8)));
typedef float f32x4 __attribute__((ext_vector_type(4)));

__device__ __forceinline__ float lrelu(float x) { return x > 0.f ? x : 0.2f * x; }

__device__ __forceinline__ unsigned short f2bf(float x) {
    __hip_bfloat16 b = __float2bfloat16(x);
    return *(unsigned short*)&b;
}
__device__ __forceinline__ float bf2f(unsigned short u) {
    return __uint_as_float(((unsigned int)u) << 16);
}

// ---------------- CSR build ----------------
__global__ void hist_k(const int* __restrict__ dst, int* __restrict__ deg) {
    int i = blockIdx.x * 256 + threadIdx.x;
    if (i < EE) atomicAdd(&deg[dst[i]], 1);
}

__global__ __launch_bounds__(1024) void scan_k(const int* __restrict__ deg,
                                               int* __restrict__ row_ptr,
                                               int* __restrict__ cursor) {
    __shared__ int wsum[16];
    int tid = threadIdx.x, lane = tid & 63, w = tid >> 6;
    int carry = 0;
    for (int base = 0; base < NN; base += 1024) {
        int i = base + tid;
        int v = (i < NN) ? deg[i] : 0;
        int x = v;
#pragma unroll
        for (int off = 1; off < 64; off <<= 1) {
            int y = __shfl_up(x, off);
            if (lane >= off) x += y;
        }
        if (lane == 63) wsum[w] = x;
        __syncthreads();
        if (tid < 16) {
            int s = wsum[tid];
#pragma unroll
            for (int off = 1; off < 16; off <<= 1) {
                int y = __shfl_up(s, off);
                if (tid >= off) s += y;
            }
            wsum[tid] = s;
        }
        __syncthreads();
        int woff = w ? wsum[w - 1] : 0;
        int excl = carry + woff + x - v;
        if (i < NN) { row_ptr[i] = excl; cursor[i] = excl; }
        carry += wsum[15];
        __syncthreads();
    }
    if (tid == 0) row_ptr[NN] = carry;
}

__global__ void scatter_k(const int* __restrict__ src, const int* __restrict__ dst,
                          int* __restrict__ cursor, int* __restrict__ csr_src) {
    int i = blockIdx.x * 256 + threadIdx.x;
    if (i < EE) {
        int slot = atomicAdd(&cursor[dst[i]], 1);
        csr_src[slot] = src[i];
    }
}

// ---------------- W2/W3 -> bf16, transposed BT[n][k] ----------------
__global__ __launch_bounds__(256) void bconv_k(const float* __restrict__ W2,
                                               const float* __restrict__ W3,
                                               unsigned short* __restrict__ BT2,
                                               unsigned short* __restrict__ BT3) {
    int tid = blockIdx.x * 256 + threadIdx.x;   // 65536
    int k = tid & 255, n = tid >> 8;
    BT2[n * 256 + k] = f2bf(W2[k * 256 + n]);
    BT3[n * 256 + k] = f2bf(W3[k * 256 + n]);
}

// ---------------- attention logits el/er ----------------
__global__ __launch_bounds__(256) void eler1_k(const float* __restrict__ pos,
                                               const float* __restrict__ W1,
                                               const float* __restrict__ al,
                                               const float* __restrict__ ar,
                                               float* __restrict__ el,
                                               float* __restrict__ er) {
    int wid = blockIdx.x * 4 + (threadIdx.x >> 6);
    int lane = threadIdx.x & 63;
    if (wid >= NN) return;
    int f = lane * 4;
    float4 w0 = *(const float4*)&W1[f];
    float4 w1 = *(const float4*)&W1[256 + f];
    float4 a4 = *(const float4*)&al[f];
    float4 r4 = *(const float4*)&ar[f];
    float2 p = *(const float2*)&pos[wid * 2];
    float fx = p.x * w0.x + p.y * w1.x;
    float fy = p.x * w0.y + p.y * w1.y;
    float fz = p.x * w0.z + p.y * w1.z;
    float fw = p.x * w0.w + p.y * w1.w;
    float pl = fx * a4.x + fy * a4.y + fz * a4.z + fw * a4.w;
    float pr = fx * r4.x + fy * r4.y + fz * r4.z + fw * r4.w;
#pragma unroll
    for (int off = 1; off < 16; off <<= 1) {
        pl += __shfl_xor(pl, off);
        pr += __shfl_xor(pr, off);
    }
    if ((lane & 15) == 0) {
        int h = lane >> 4;
        el[wid * 4 + h] = pl;
        er[wid * 4 + h] = pr;
    }
}

// bf16-feat variant
__global__ __launch_bounds__(256) void eler_b_k(const unsigned short* __restrict__ featb,
                                                const float* __restrict__ al,
                                                const float* __restrict__ ar,
                                                float* __restrict__ el,
                                                float* __restrict__ er) {
    int wid = blockIdx.x * 4 + (threadIdx.x >> 6);
    int lane = threadIdx.x & 63;
    if (wid >= NN) return;
    int f = lane * 4;
    ushort4 u = *(const ushort4*)&featb[(size_t)wid * 256 + f];
    float4 a4 = *(const float4*)&al[f];
    float4 r4 = *(const float4*)&ar[f];
    float vx = bf2f(u.x), vy = bf2f(u.y), vz = bf2f(u.z), vw = bf2f(u.w);
    float pl = vx * a4.x + vy * a4.y + vz * a4.z + vw * a4.w;
    float pr = vx * r4.x + vy * r4.y + vz * r4.z + vw * r4.w;
#pragma unroll
    for (int off = 1; off < 16; off <<= 1) {
        pl += __shfl_xor(pl, off);
        pr += __shfl_xor(pr, off);
    }
    if ((lane & 15) == 0) {
        int h = lane >> 4;
        el[wid * 4 + h] = pl;
        er[wid * 4 + h] = pr;
    }
}

// ---------------- aggregation: one wave per dst node ----------------
__global__ __launch_bounds__(256) void agg1_k(const float* __restrict__ pos,
                                              const float* __restrict__ W1,
                                              const float* __restrict__ resW1,
                                              const float* __restrict__ el,
                                              const float* __restrict__ er,
                                              const int* __restrict__ row_ptr,
                                              const int* __restrict__ csr_src,
                                              float* __restrict__ hout,
                                              unsigned short* __restrict__ hb16) {
    int wid = blockIdx.x * 4 + (threadIdx.x >> 6);
    int lane = threadIdx.x & 63;
    if (wid >= NN) return;
    int f = lane * 4;
    int start = row_ptr[wid], end = row_ptr[wid + 1];
    float4 er4 = *(const float4*)&er[wid * 4];

    float m0 = -1e30f, m1 = -1e30f, m2 = -1e30f, m3 = -1e30f;
    for (int s = start + lane; s < end; s += 64) {
        int sn = csr_src[s];
        float4 ev = *(const float4*)&el[sn * 4];
        m0 = fmaxf(m0, lrelu(ev.x + er4.x));
        m1 = fmaxf(m1, lrelu(ev.y + er4.y));
        m2 = fmaxf(m2, lrelu(ev.z + er4.z));
        m3 = fmaxf(m3, lrelu(ev.w + er4.w));
    }
#pragma unroll
    for (int off = 32; off; off >>= 1) {
        m0 = fmaxf(m0, __shfl_xor(m0, off));
        m1 = fmaxf(m1, __shfl_xor(m1, off));
        m2 = fmaxf(m2, __shfl_xor(m2, off));
        m3 = fmaxf(m3, __shfl_xor(m3, off));
    }
    float s0 = 0, s1 = 0, s2 = 0, s3 = 0;
    for (int s = start + lane; s < end; s += 64) {
        int sn = csr_src[s];
        float4 ev = *(const float4*)&el[sn * 4];
        s0 += __expf(lrelu(ev.x + er4.x) - m0);
        s1 += __expf(lrelu(ev.y + er4.y) - m1);
        s2 += __expf(lrelu(ev.z + er4.z) - m2);
        s3 += __expf(lrelu(ev.w + er4.w) - m3);
    }
#pragma unroll
    for (int off = 32; off; off >>= 1) {
        s0 += __shfl_xor(s0, off);
        s1 += __shfl_xor(s1, off);
        s2 += __shfl_xor(s2, off);
        s3 += __shfl_xor(s3, off);
    }
    float i0 = 1.f / fmaxf(s0, 1e-9f), i1 = 1.f / fmaxf(s1, 1e-9f);
    float i2 = 1.f / fmaxf(s2, 1e-9f), i3 = 1.f / fmaxf(s3, 1e-9f);

    int h = lane >> 4;
    float mh = (lane & 32) ? ((lane & 16) ? m3 : m2) : ((lane & 16) ? m1 : m0);
    float ih = (lane & 32) ? ((lane & 16) ? i3 : i2) : ((lane & 16) ? i1 : i0);
    float eh = (lane & 32) ? ((lane & 16) ? er4.w : er4.z) : ((lane & 16) ? er4.y : er4.x);

    float ap0 = 0.f, ap1 = 0.f;
    for (int s = start; s < end; ++s) {
        int sn = csr_src[s];
        float a = __expf(lrelu(el[sn * 4 + h] + eh) - mh) * ih;
        float2 p = *(const float2*)&pos[sn * 2];
        ap0 += a * p.x;
        ap1 += a * p.y;
    }
    float4 w0 = *(const float4*)&W1[f];
    float4 w1 = *(const float4*)&W1[256 + f];
    float4 rw0 = *(const float4*)&resW1[f];
    float4 rw1 = *(const float4*)&resW1[256 + f];
    float2 pd = *(const float2*)&pos[wid * 2];
    float4 o;
    o.x = fmaxf(ap0 * w0.x + ap1 * w1.x + pd.x * rw0.x + pd.y * rw1.x, 0.f);
    o.y = fmaxf(ap0 * w0.y + ap1 * w1.y + pd.x * rw0.y + pd.y * rw1.y, 0.f);
    o.z = fmaxf(ap0 * w0.z + ap1 * w1.z + pd.x * rw0.z + pd.y * rw1.z, 0.f);
    o.w = fmaxf(ap0 * w0.w + ap1 * w1.w + pd.x * rw0.w + pd.y * rw1.w, 0.f);
    *(float4*)&hout[(size_t)wid * 256 + f] = o;
    ushort4 ob;
    ob.x = f2bf(o.x); ob.y = f2bf(o.y); ob.z = f2bf(o.z); ob.w = f2bf(o.w);
    *(ushort4*)&hb16[(size_t)wid * 256 + f] = ob;
}

// bf16 feat gather, residual in f32 hio, relu; also emits bf16 copy for next GEMM
__global__ __launch_bounds__(256) void agg_k(const unsigned short* __restrict__ featb,
                                             const float* __restrict__ el,
                                             const float* __restrict__ er,
                                             const int* __restrict__ row_ptr,
                                             const int* __restrict__ csr_src,
                                             float* __restrict__ hio,
                                             unsigned short* __restrict__ hb16) {
    int wid = blockIdx.x * 4 + (threadIdx.x >> 6);
    int lane = threadIdx.x & 63;
    if (wid >= NN) return;
    int f = lane * 4;
    int start = row_ptr[wid], end = row_ptr[wid + 1];
    float4 er4 = *(const float4*)&er[wid * 4];

    float m0 = -1e30f, m1 = -1e30f, m2 = -1e30f, m3 = -1e30f;
    for (int s = start + lane; s < end; s += 64) {
        int sn = csr_src[s];
        float4 ev = *(const float4*)&el[sn * 4];
        m0 = fmaxf(m0, lrelu(ev.x + er4.x));
        m1 = fmaxf(m1, lrelu(ev.y + er4.y));
        m2 = fmaxf(m2, lrelu(ev.z + er4.z));
        m3 = fmaxf(m3, lrelu(ev.w + er4.w));
    }
#pragma unroll
    for (int off = 32; off; off >>= 1) {
        m0 = fmaxf(m0, __shfl_xor(m0, off));
        m1 = fmaxf(m1, __shfl_xor(m1, off));
        m2 = fmaxf(m2, __shfl_xor(m2, off));
        m3 = fmaxf(m3, __shfl_xor(m3, off));
    }
    float s0 = 0, s1 = 0, s2 = 0, s3 = 0;
    for (int s = start + lane; s < end; s += 64) {
        int sn = csr_src[s];
        float4 ev = *(const float4*)&el[sn * 4];
        s0 += __expf(lrelu(ev.x + er4.x) - m0);
        s1 += __expf(lrelu(ev.y + er4.y) - m1);
        s2 += __expf(lrelu(ev.z + er4.z) - m2);
        s3 += __expf(lrelu(ev.w + er4.w) - m3);
    }
#pragma unroll
    for (int off = 32; off; off >>= 1) {
        s0 += __shfl_xor(s0, off);
        s1 += __shfl_xor(s1, off);
        s2 += __shfl_xor(s2, off);
        s3 += __shfl_xor(s3, off);
    }
    float i0 = 1.f / fmaxf(s0, 1e-9f), i1 = 1.f / fmaxf(s1, 1e-9f);
    float i2 = 1.f / fmaxf(s2, 1e-9f), i3 = 1.f / fmaxf(s3, 1e-9f);

    int h = lane >> 4;
    float mh = (lane & 32) ? ((lane & 16) ? m3 : m2) : ((lane & 16) ? m1 : m0);
    float ih = (lane & 32) ? ((lane & 16) ? i3 : i2) : ((lane & 16) ? i1 : i0);
    float eh = (lane & 32) ? ((lane & 16) ? er4.w : er4.z) : ((lane & 16) ? er4.y : er4.x);

    float4 acc = {0.f, 0.f, 0.f, 0.f};
    for (int s = start; s < end; ++s) {
        int sn = csr_src[s];
        float a = __expf(lrelu(el[sn * 4 + h] + eh) - mh) * ih;
        ushort4 v = *(const ushort4*)&featb[(size_t)sn * 256 + f];
        acc.x += a * bf2f(v.x);
        acc.y += a * bf2f(v.y);
        acc.z += a * bf2f(v.z);
        acc.w += a * bf2f(v.w);
    }
    float4 r = *(const float4*)&hio[(size_t)wid * 256 + f];
    float4 o;
    o.x = fmaxf(acc.x + r.x, 0.f);
    o.y = fmaxf(acc.y + r.y, 0.f);
    o.z = fmaxf(acc.z + r.z, 0.f);
    o.w = fmaxf(acc.w + r.w, 0.f);
    *(float4*)&hio[(size_t)wid * 256 + f] = o;
    ushort4 ob;
    ob.x = f2bf(o.x); ob.y = f2bf(o.y); ob.z = f2bf(o.z); ob.w = f2bf(o.w);
    *(ushort4*)&hb16[(size_t)wid * 256 + f] = ob;
}

// layer 3: bf16 feat gather, f32 residual, mean over heads -> bf16 hsmall [N,64]
__global__ __launch_bounds__(256) void agg3_k(const unsigned short* __restrict__ featb,
                                              const float* __restrict__ el,
                                              const float* __restrict__ er,
                                              const int* __restrict__ row_ptr,
                                              const int* __restrict__ csr_src,
                                              const float* __restrict__ hres,
                                              unsigned short* __restrict__ hsmallb) {
    int wid = blockIdx.x * 4 + (threadIdx.x >> 6);
    int lane = threadIdx.x & 63;
    if (wid >= NN) return;
    int f = lane * 4;
    int start = row_ptr[wid], end = row_ptr[wid + 1];
    float4 er4 = *(const float4*)&er[wid * 4];

    float m0 = -1e30f, m1 = -1e30f, m2 = -1e30f, m3 = -1e30f;
    for (int s = start + lane; s < end; s += 64) {
        int sn = csr_src[s];
        float4 ev = *(const float4*)&el[sn * 4];
        m0 = fmaxf(m0, lrelu(ev.x + er4.x));
        m1 = fmaxf(m1, lrelu(ev.y + er4.y));
        m2 = fmaxf(m2, lrelu(ev.z + er4.z));
        m3 = fmaxf(m3, lrelu(ev.w + er4.w));
    }
#pragma unroll
    for (int off = 32; off; off >>= 1) {
        m0 = fmaxf(m0, __shfl_xor(m0, off));
        m1 = fmaxf(m1, __shfl_xor(m1, off));
        m2 = fmaxf(m2, __shfl_xor(m2, off));
        m3 = fmaxf(m3, __shfl_xor(m3, off));
    }
    float s0 = 0, s1 = 0, s2 = 0, s3 = 0;
    for (int s = start + lane; s < end; s += 64) {
        int sn = csr_src[s];
        float4 ev = *(const float4*)&el[sn * 4];
        s0 += __expf(lrelu(ev.x + er4.x) - m0);
        s1 += __expf(lrelu(ev.y + er4.y) - m1);
        s2 += __expf(lrelu(ev.z + er4.z) - m2);
        s3 += __expf(lrelu(ev.w + er4.w) - m3);
    }
#pragma unroll
    for (int off = 32; off; off >>= 1) {
        s0 += __shfl_xor(s0, off);
        s1 += __shfl_xor(s1, off);
        s2 += __shfl_xor(s2, off);
        s3 += __shfl_xor(s3, off);
    }
    float i0 = 1.f / fmaxf(s0, 1e-9f), i1 = 1.f / fmaxf(s1, 1e-9f);
    float i2 = 1.f / fmaxf(s2, 1e-9f), i3 = 1.f / fmaxf(s3, 1e-9f);

    int h = lane >> 4;
    float mh = (lane & 32) ? ((lane & 16) ? m3 : m2) : ((lane & 16) ? m1 : m0);
    float ih = (lane & 32) ? ((lane & 16) ? i3 : i2) : ((lane & 16) ? i1 : i0);
    float eh = (lane & 32) ? ((lane & 16) ? er4.w : er4.z) : ((lane & 16) ? er4.y : er4.x);

    float4 acc = {0.f, 0.f, 0.f, 0.f};
    for (int s = start; s < end; ++s) {
        int sn = csr_src[s];
        float a = __expf(lrelu(el[sn * 4 + h] + eh) - mh) * ih;
        ushort4 v = *(const ushort4*)&featb[(size_t)sn * 256 + f];
        acc.x += a * bf2f(v.x);
        acc.y += a * bf2f(v.y);
        acc.z += a * bf2f(v.z);
        acc.w += a * bf2f(v.w);
    }
    float4 r = *(const float4*)&hres[(size_t)wid * 256 + f];
    float4 o;
    o.x = acc.x + r.x;
    o.y = acc.y + r.y;
    o.z = acc.z + r.z;
    o.w = acc.w + r.w;
    o.x += __shfl_xor(o.x, 16); o.y += __shfl_xor(o.y, 16);
    o.z += __shfl_xor(o.z, 16); o.w += __shfl_xor(o.w, 16);
    o.x += __shfl_xor(o.x, 32); o.y += __shfl_xor(o.y, 32);
    o.z += __shfl_xor(o.z, 32); o.w += __shfl_xor(o.w, 32);
    if (lane < 16) {
        ushort4 m4;
        m4.x = f2bf(o.x * 0.25f);
        m4.y = f2bf(o.y * 0.25f);
        m4.z = f2bf(o.z * 0.25f);
        m4.w = f2bf(o.w * 0.25f);
        *(ushort4*)&hsmallb[(size_t)wid * 64 + lane * 4] = m4;
    }
}

// ---------------- MFMA GEMM: [N,256]bf16 @ BT[n][k]bf16 -> [N,256]bf16 ----------------
__global__ __launch_bounds__(256) void gemm_mfma_k(const unsigned short* __restrict__ Ab,
                                                   const unsigned short* __restrict__ BT,
                                                   unsigned short* __restrict__ C) {
    __shared__ __align__(16) short As[128 * 40];
    __shared__ __align__(16) short Bs[128 * 40];
    int tid = threadIdx.x;
    int lane = tid & 63, wave = tid >> 6;
    int wr = wave >> 1, wc = wave & 1;
    int tileM = blockIdx.x * 128;
    int tileN = blockIdx.y * 128;

    int srow = tid >> 1, sko = (tid & 1) * 16;
    int fm = lane & 15, kg = lane >> 4;

    f32x4 acc[4][4];
#pragma unroll
    for (int i = 0; i < 4; ++i)
#pragma unroll
        for (int j = 0; j < 4; ++j) acc[i][j] = (f32x4){0.f, 0.f, 0.f, 0.f};

    for (int k0 = 0; k0 < 256; k0 += 32) {
        int gr = tileM + srow;
        short8 a0 = (short8)0, a1 = (short8)0;
        if (gr < NN) {
            a0 = *(const short8*)&Ab[(size_t)gr * 256 + k0 + sko];
            a1 = *(const short8*)&Ab[(size_t)gr * 256 + k0 + sko + 8];
        }
        *(short8*)&As[srow * 40 + sko] = a0;
        *(short8*)&As[srow * 40 + sko + 8] = a1;
        short8 b0 = *(const short8*)&BT[(size_t)(tileN + srow) * 256 + k0 + sko];
        short8 b1 = *(const short8*)&BT[(size_t)(tileN + srow) * 256 + k0 + sko + 8];
        *(short8*)&Bs[srow * 40 + sko] = b0;
        *(short8*)&Bs[srow * 40 + sko + 8] = b1;
        __syncthreads();

        short8 afr[4], bfr[4];
#pragma unroll
        for (int mi = 0; mi < 4; ++mi)
            afr[mi] = *(const short8*)&As[(wr * 64 + mi * 16 + fm) * 40 + kg * 8];
#pragma unroll
        for (int ni = 0; ni < 4; ++ni)
            bfr[ni] = *(const short8*)&Bs[(wc * 64 + ni * 16 + fm) * 40 + kg * 8];
#pragma unroll
        for (int mi = 0; mi < 4; ++mi)
#pragma unroll
            for (int ni = 0; ni < 4; ++ni)
                acc[mi][ni] = __builtin_amdgcn_mfma_f32_16x16x32_bf16(
                    afr[mi], bfr[ni], acc[mi][ni], 0, 0, 0);
        __syncthreads();
    }

#pragma unroll
    for (int mi = 0; mi < 4; ++mi) {
#pragma unroll
        for (int ni = 0; ni < 4; ++ni) {
            int col = tileN + wc * 64 + ni * 16 + fm;
#pragma unroll
            for (int r = 0; r < 4; ++r) {
                int row = tileM + wr * 64 + mi * 16 + kg * 4 + r;
                if (row < NN) C[(size_t)row * 256 + col] = f2bf(acc[mi][ni][r]);
            }
        }
    }
}

// ---------------- edge scoring MLP: LDS-tiled micro-GEMM, 64 edges/block, bf16 hsmall ----------------
__global__ __launch_bounds__(256) void edge_score3_k(const unsigned short* __restrict__ hs,
                                                     const int* __restrict__ src,
                                                     const int* __restrict__ dst,
                                                     const float* __restrict__ mW1,
                                                     const float* __restrict__ mb1,
                                                     const float* __restrict__ mW2,
                                                     const float* __restrict__ mb2,
                                                     float* __restrict__ out) {
    __shared__ __align__(16) float Ws[64 * 64];
    __shared__ __align__(16) float xT[64][66];
    __shared__ __align__(16) float b1s[64];
    __shared__ __align__(16) float w2s[64];
    int tid = threadIdx.x;
    for (int i = tid * 4; i < 4096; i += 1024)
        *(float4*)&Ws[i] = *(const float4*)&mW1[i];
    if (tid < 64) { b1s[tid] = mb1[tid]; w2s[tid] = mW2[tid]; }

    int e_loc = tid >> 2, q = tid & 3;
    int e = blockIdx.x * 64 + e_loc;
    int s = src[e], d = dst[e];
    const unsigned short* rs = &hs[(size_t)s * 64 + q * 16];
    const unsigned short* rd = &hs[(size_t)d * 64 + q * 16];
#pragma unroll
    for (int i = 0; i < 4; ++i) {
        ushort4 a = *(const ushort4*)&rs[i * 4];
        ushort4 b = *(const ushort4*)&rd[i * 4];
        int k = q * 16 + i * 4;
        xT[k + 0][e_loc] = fabsf(bf2f(a.x) - bf2f(b.x));
        xT[k + 1][e_loc] = fabsf(bf2f(a.y) - bf2f(b.y));
        xT[k + 2][e_loc] = fabsf(bf2f(a.z) - bf2f(b.z));
        xT[k + 3][e_loc] = fabsf(bf2f(a.w) - bf2f(b.w));
    }
    __syncthreads();

    int eq = tid >> 4, jq = tid & 15;
    float4 bb = *(const float4*)&b1s[jq * 4];
    float4 acc0 = bb, acc1 = bb, acc2 = bb, acc3 = bb;
#pragma unroll
    for (int k = 0; k < 64; ++k) {
        float4 xv = *(const float4*)&xT[k][eq * 4];
        float4 wv = *(const float4*)&Ws[k * 64 + jq * 4];
        acc0.x += xv.x * wv.x; acc0.y += xv.x * wv.y; acc0.z += xv.x * wv.z; acc0.w += xv.x * wv.w;
        acc1.x += xv.y * wv.x; acc1.y += xv.y * wv.y; acc1.z += xv.y * wv.z; acc1.w += xv.y * wv.w;
        acc2.x += xv.z * wv.x; acc2.y += xv.z * wv.y; acc2.z += xv.z * wv.z; acc2.w += xv.z * wv.w;
        acc3.x += xv.w * wv.x; acc3.y += xv.w * wv.y; acc3.z += xv.w * wv.z; acc3.w += xv.w * wv.w;
    }
    float4 w2 = *(const float4*)&w2s[jq * 4];
    float t0 = fmaxf(acc0.x, 0.f) * w2.x + fmaxf(acc0.y, 0.f) * w2.y +
               fmaxf(acc0.z, 0.f) * w2.z + fmaxf(acc0.w, 0.f) * w2.w;
    float t1 = fmaxf(acc1.x, 0.f) * w2.x + fmaxf(acc1.y, 0.f) * w2.y +
               fmaxf(acc1.z, 0.f) * w2.z + fmaxf(acc1.w, 0.f) * w2.w;
    float t2 = fmaxf(acc2.x, 0.f) * w2.x + fmaxf(acc2.y, 0.f) * w2.y +
               fmaxf(acc2.z, 0.f) * w2.z + fmaxf(acc2.w, 0.f) * w2.w;
    float t3 = fmaxf(acc3.x, 0.f) * w2.x + fmaxf(acc3.y, 0.f) * w2.y +
               fmaxf(acc3.z, 0.f) * w2.z + fmaxf(acc3.w, 0.f) * w2.w;
#pragma unroll
    for (int off = 1; off < 16; off <<= 1) {
        t0 += __shfl_xor(t0, off);
        t1 += __shfl_xor(t1, off);
        t2 += __shfl_xor(t2, off);
        t3 += __shfl_xor(t3, off);
    }
    if (jq == 0) {
        float bias = mb2[0];
        int base = blockIdx.x * 64 + eq * 4;
        out[base + 0] = 1.f / (1.f + __expf(-(t0 + bias)));
        out[base + 1] = 1.f / (1.f + __expf(-(t1 + bias)));
        out[base + 2] = 1.f / (1.f + __expf(-(t2 + bias)));
        out[base + 3] = 1.f / (1.f + __expf(-(t3 + bias)));
    }
}

extern "C" void kernel_launch(void* const* d_in, const int* in_sizes, int n_in,
                              void* d_out, int out_size, void* d_ws, size_t ws_size,
                              hipStream_t stream) {
    (void)in_sizes; (void)n_in; (void)out_size; (void)ws_size;
    const float* pos   = (const float*)d_in[0];
    const int*   src   = (const int*)d_in[1];
    const int*   dst   = (const int*)d_in[2];
    const float* W1    = (const float*)d_in[3];
    const float* al1   = (const float*)d_in[4];
    const float* ar1   = (const float*)d_in[5];
    const float* resW1 = (const float*)d_in[6];
    const float* W2    = (const float*)d_in[7];
    const float* al2   = (const float*)d_in[8];
    const float* ar2   = (const float*)d_in[9];
    const float* W3    = (const float*)d_in[10];
    const float* al3   = (const float*)d_in[11];
    const float* ar3   = (const float*)d_in[12];
    const float* mW1   = (const float*)d_in[13];
    const float* mb1   = (const float*)d_in[14];
    const float* mW2   = (const float*)d_in[15];
    const float* mb2   = (const float*)d_in[16];
    float* out = (float*)d_out;

    char* ws = (char*)d_ws;
    size_t off = 0;
    auto alloc = [&](size_t bytes) {
        void* p = ws + off;
        off += (bytes + 255) & ~(size_t)255;
        return p;
    };
    float* Hbuf            = (float*)alloc((size_t)NN * 256 * 4);
    unsigned short* FEATb  = (unsigned short*)alloc((size_t)NN * 256 * 2);
    unsigned short* Hb16   = (unsigned short*)alloc((size_t)NN * 256 * 2);
    unsigned short* BT2    = (unsigned short*)alloc((size_t)256 * 256 * 2);
    unsigned short* BT3    = (unsigned short*)alloc((size_t)256 * 256 * 2);
    unsigned short* hsmallb = (unsigned short*)alloc((size_t)NN * 64 * 2);
    float* el     = (float*)alloc((size_t)NN * 4 * 4);
    float* er     = (float*)alloc((size_t)NN * 4 * 4);
    int* deg      = (int*)alloc((size_t)NN * 4);
    int* row_ptr  = (int*)alloc((size_t)(NN + 1) * 4);
    int* cursor   = (int*)alloc((size_t)NN * 4);
    int* csr      = (int*)alloc((size_t)EE * 4);

    hipMemsetAsync(deg, 0, (size_t)NN * 4, stream);
    hist_k<<<(EE + 255) / 256, 256, 0, stream>>>(dst, deg);
    scan_k<<<1, 1024, 0, stream>>>(deg, row_ptr, cursor);
    scatter_k<<<(EE + 255) / 256, 256, 0, stream>>>(src, dst, cursor, csr);
    bconv_k<<<256, 256, 0, stream>>>(W2, W3, BT2, BT3);

    // layer 1
    eler1_k<<<NN / 4 + 1, 256, 0, stream>>>(pos, W1, al1, ar1, el, er);
    agg1_k<<<NN / 4 + 1, 256, 0, stream>>>(pos, W1, resW1, el, er, row_ptr, csr, Hbuf, Hb16);

    dim3 ggrid((NN + 127) / 128, 2);
    // layer 2
    gemm_mfma_k<<<ggrid, 256, 0, stream>>>(Hb16, BT2, FEATb);
    eler_b_k<<<NN / 4 + 1, 256, 0, stream>>>(FEATb, al2, ar2, el, er);
    agg_k<<<NN / 4 + 1, 256, 0, stream>>>(FEATb, el, er, row_ptr, csr, Hbuf, Hb16);

    // layer 3
    gemm_mfma_k<<<ggrid, 256, 0, stream>>>(Hb16, BT3, FEATb);
    eler_b_k<<<NN / 4 + 1, 256, 0, stream>>>(FEATb, al3, ar3, el, er);
    agg3_k<<<NN / 4 + 1, 256, 0, stream>>>(FEATb, el, er, row_ptr, csr, Hbuf, hsmallb);

    // edge MLP
    edge_score3_k<<<EE / 64, 256, 0, stream>>>(hsmallb, src, dst, mW1, mb1, mW2, mb2, out);
}

// Round 7
// 573.934 us; speedup vs baseline: 2.0519x; 1.1947x over previous
//
#include <hip/hip_runtime.h>
#include <hip/hip_bf16.h>

#define NN 50000
#define EE 800000

typedef short short8 __attribute__((ext_vector_type(8)));
typedef float f32x4 __attribute__((ext_vector_type(4)));

__device__ __forceinline__ float lrelu(float x) { return x > 0.f ? x : 0.2f * x; }

__device__ __forceinline__ unsigned short f2bf(float x) {
    __hip_bfloat16 b = __float2bfloat16(x);
    return *(unsigned short*)&b;
}
__device__ __forceinline__ float bf2f(unsigned short u) {
    return __uint_as_float(((unsigned int)u) << 16);
}

// ---------------- CSR build ----------------
__global__ void hist_k(const int* __restrict__ dst, int* __restrict__ deg) {
    int i = blockIdx.x * 256 + threadIdx.x;
    if (i < EE) atomicAdd(&deg[dst[i]], 1);
}

__global__ __launch_bounds__(1024) void scan_k(const int* __restrict__ deg,
                                               int* __restrict__ row_ptr,
                                               int* __restrict__ cursor) {
    __shared__ int wsum[16];
    int tid = threadIdx.x, lane = tid & 63, w = tid >> 6;
    int carry = 0;
    for (int base = 0; base < NN; base += 1024) {
        int i = base + tid;
        int v = (i < NN) ? deg[i] : 0;
        int x = v;
#pragma unroll
        for (int off = 1; off < 64; off <<= 1) {
            int y = __shfl_up(x, off);
            if (lane >= off) x += y;
        }
        if (lane == 63) wsum[w] = x;
        __syncthreads();
        if (tid < 16) {
            int s = wsum[tid];
#pragma unroll
            for (int off = 1; off < 16; off <<= 1) {
                int y = __shfl_up(s, off);
                if (tid >= off) s += y;
            }
            wsum[tid] = s;
        }
        __syncthreads();
        int woff = w ? wsum[w - 1] : 0;
        int excl = carry + woff + x - v;
        if (i < NN) { row_ptr[i] = excl; cursor[i] = excl; }
        carry += wsum[15];
        __syncthreads();
    }
    if (tid == 0) row_ptr[NN] = carry;
}

__global__ void scatter_k(const int* __restrict__ src, const int* __restrict__ dst,
                          int* __restrict__ cursor, int* __restrict__ csr_src) {
    int i = blockIdx.x * 256 + threadIdx.x;
    if (i < EE) {
        int slot = atomicAdd(&cursor[dst[i]], 1);
        csr_src[slot] = src[i];
    }
}

// ---------------- W2/W3 -> bf16, transposed BT[n][k] ----------------
__global__ __launch_bounds__(256) void bconv_k(const float* __restrict__ W2,
                                               const float* __restrict__ W3,
                                               unsigned short* __restrict__ BT2,
                                               unsigned short* __restrict__ BT3) {
    int tid = blockIdx.x * 256 + threadIdx.x;   // 65536
    int k = tid & 255, n = tid >> 8;
    BT2[n * 256 + k] = f2bf(W2[k * 256 + n]);
    BT3[n * 256 + k] = f2bf(W3[k * 256 + n]);
}

// ---------------- attention logits el/er ----------------
__global__ __launch_bounds__(256) void eler1_k(const float* __restrict__ pos,
                                               const float* __restrict__ W1,
                                               const float* __restrict__ al,
                                               const float* __restrict__ ar,
                                               float* __restrict__ el,
                                               float* __restrict__ er) {
    int wid = blockIdx.x * 4 + (threadIdx.x >> 6);
    int lane = threadIdx.x & 63;
    if (wid >= NN) return;
    int f = lane * 4;
    float4 w0 = *(const float4*)&W1[f];
    float4 w1 = *(const float4*)&W1[256 + f];
    float4 a4 = *(const float4*)&al[f];
    float4 r4 = *(const float4*)&ar[f];
    float2 p = *(const float2*)&pos[wid * 2];
    float fx = p.x * w0.x + p.y * w1.x;
    float fy = p.x * w0.y + p.y * w1.y;
    float fz = p.x * w0.z + p.y * w1.z;
    float fw = p.x * w0.w + p.y * w1.w;
    float pl = fx * a4.x + fy * a4.y + fz * a4.z + fw * a4.w;
    float pr = fx * r4.x + fy * r4.y + fz * r4.z + fw * r4.w;
#pragma unroll
    for (int off = 1; off < 16; off <<= 1) {
        pl += __shfl_xor(pl, off);
        pr += __shfl_xor(pr, off);
    }
    if ((lane & 15) == 0) {
        int h = lane >> 4;
        el[wid * 4 + h] = pl;
        er[wid * 4 + h] = pr;
    }
}

// bf16-feat variant
__global__ __launch_bounds__(256) void eler_b_k(const unsigned short* __restrict__ featb,
                                                const float* __restrict__ al,
                                                const float* __restrict__ ar,
                                                float* __restrict__ el,
                                                float* __restrict__ er) {
    int wid = blockIdx.x * 4 + (threadIdx.x >> 6);
    int lane = threadIdx.x & 63;
    if (wid >= NN) return;
    int f = lane * 4;
    ushort4 u = *(const ushort4*)&featb[(size_t)wid * 256 + f];
    float4 a4 = *(const float4*)&al[f];
    float4 r4 = *(const float4*)&ar[f];
    float vx = bf2f(u.x), vy = bf2f(u.y), vz = bf2f(u.z), vw = bf2f(u.w);
    float pl = vx * a4.x + vy * a4.y + vz * a4.z + vw * a4.w;
    float pr = vx * r4.x + vy * r4.y + vz * r4.z + vw * r4.w;
#pragma unroll
    for (int off = 1; off < 16; off <<= 1) {
        pl += __shfl_xor(pl, off);
        pr += __shfl_xor(pr, off);
    }
    if ((lane & 15) == 0) {
        int h = lane >> 4;
        el[wid * 4 + h] = pl;
        er[wid * 4 + h] = pr;
    }
}

// ---------------- aggregation: one wave per dst node, ONE-PASS softmax ----------------
// Softmax is shift-invariant: sum(exp(e)*f)/sum(exp(e)) needs no max pass.
// e = lrelu(el+er) is O(1..10) for this data -> exp() safe in f32.
__global__ __launch_bounds__(256) void agg1_k(const float* __restrict__ pos,
                                              const float* __restrict__ W1,
                                              const float* __restrict__ resW1,
                                              const float* __restrict__ el,
                                              const float* __restrict__ er,
                                              const int* __restrict__ row_ptr,
                                              const int* __restrict__ csr_src,
                                              float* __restrict__ hout,
                                              unsigned short* __restrict__ hb16) {
    int wid = blockIdx.x * 4 + (threadIdx.x >> 6);
    int lane = threadIdx.x & 63;
    if (wid >= NN) return;
    int f = lane * 4;
    int start = row_ptr[wid], end = row_ptr[wid + 1];
    int h = lane >> 4;
    float eh = er[wid * 4 + h];

    float ap0 = 0.f, ap1 = 0.f, den = 0.f;
    int s = start;
    for (; s + 3 < end; s += 4) {
        int sn0 = csr_src[s], sn1 = csr_src[s + 1];
        int sn2 = csr_src[s + 2], sn3 = csr_src[s + 3];
        float e0 = el[sn0 * 4 + h], e1 = el[sn1 * 4 + h];
        float e2 = el[sn2 * 4 + h], e3 = el[sn3 * 4 + h];
        float2 p0 = *(const float2*)&pos[sn0 * 2];
        float2 p1 = *(const float2*)&pos[sn1 * 2];
        float2 p2 = *(const float2*)&pos[sn2 * 2];
        float2 p3 = *(const float2*)&pos[sn3 * 2];
        float w0 = __expf(lrelu(e0 + eh)), w1 = __expf(lrelu(e1 + eh));
        float w2 = __expf(lrelu(e2 + eh)), w3 = __expf(lrelu(e3 + eh));
        den += (w0 + w1) + (w2 + w3);
        ap0 += w0 * p0.x + w1 * p1.x + w2 * p2.x + w3 * p3.x;
        ap1 += w0 * p0.y + w1 * p1.y + w2 * p2.y + w3 * p3.y;
    }
    for (; s < end; ++s) {
        int sn = csr_src[s];
        float w = __expf(lrelu(el[sn * 4 + h] + eh));
        float2 p = *(const float2*)&pos[sn * 2];
        den += w;
        ap0 += w * p.x;
        ap1 += w * p.y;
    }
    float inv = 1.f / fmaxf(den, 1e-9f);
    ap0 *= inv;
    ap1 *= inv;

    float4 w0 = *(const float4*)&W1[f];
    float4 w1 = *(const float4*)&W1[256 + f];
    float4 rw0 = *(const float4*)&resW1[f];
    float4 rw1 = *(const float4*)&resW1[256 + f];
    float2 pd = *(const float2*)&pos[wid * 2];
    float4 o;
    o.x = fmaxf(ap0 * w0.x + ap1 * w1.x + pd.x * rw0.x + pd.y * rw1.x, 0.f);
    o.y = fmaxf(ap0 * w0.y + ap1 * w1.y + pd.x * rw0.y + pd.y * rw1.y, 0.f);
    o.z = fmaxf(ap0 * w0.z + ap1 * w1.z + pd.x * rw0.z + pd.y * rw1.z, 0.f);
    o.w = fmaxf(ap0 * w0.w + ap1 * w1.w + pd.x * rw0.w + pd.y * rw1.w, 0.f);
    *(float4*)&hout[(size_t)wid * 256 + f] = o;
    ushort4 ob;
    ob.x = f2bf(o.x); ob.y = f2bf(o.y); ob.z = f2bf(o.z); ob.w = f2bf(o.w);
    *(ushort4*)&hb16[(size_t)wid * 256 + f] = ob;
}

__global__ __launch_bounds__(256) void agg_k(const unsigned short* __restrict__ featb,
                                             const float* __restrict__ el,
                                             const float* __restrict__ er,
                                             const int* __restrict__ row_ptr,
                                             const int* __restrict__ csr_src,
                                             float* __restrict__ hio,
                                             unsigned short* __restrict__ hb16) {
    int wid = blockIdx.x * 4 + (threadIdx.x >> 6);
    int lane = threadIdx.x & 63;
    if (wid >= NN) return;
    int f = lane * 4;
    int start = row_ptr[wid], end = row_ptr[wid + 1];
    int h = lane >> 4;
    float eh = er[wid * 4 + h];

    float4 acc = {0.f, 0.f, 0.f, 0.f};
    float den = 0.f;
    int s = start;
    for (; s + 3 < end; s += 4) {
        int sn0 = csr_src[s], sn1 = csr_src[s + 1];
        int sn2 = csr_src[s + 2], sn3 = csr_src[s + 3];
        float e0 = el[sn0 * 4 + h], e1 = el[sn1 * 4 + h];
        float e2 = el[sn2 * 4 + h], e3 = el[sn3 * 4 + h];
        ushort4 v0 = *(const ushort4*)&featb[(size_t)sn0 * 256 + f];
        ushort4 v1 = *(const ushort4*)&featb[(size_t)sn1 * 256 + f];
        ushort4 v2 = *(const ushort4*)&featb[(size_t)sn2 * 256 + f];
        ushort4 v3 = *(const ushort4*)&featb[(size_t)sn3 * 256 + f];
        float w0 = __expf(lrelu(e0 + eh)), w1 = __expf(lrelu(e1 + eh));
        float w2 = __expf(lrelu(e2 + eh)), w3 = __expf(lrelu(e3 + eh));
        den += (w0 + w1) + (w2 + w3);
        acc.x += w0 * bf2f(v0.x) + w1 * bf2f(v1.x) + w2 * bf2f(v2.x) + w3 * bf2f(v3.x);
        acc.y += w0 * bf2f(v0.y) + w1 * bf2f(v1.y) + w2 * bf2f(v2.y) + w3 * bf2f(v3.y);
        acc.z += w0 * bf2f(v0.z) + w1 * bf2f(v1.z) + w2 * bf2f(v2.z) + w3 * bf2f(v3.z);
        acc.w += w0 * bf2f(v0.w) + w1 * bf2f(v1.w) + w2 * bf2f(v2.w) + w3 * bf2f(v3.w);
    }
    for (; s < end; ++s) {
        int sn = csr_src[s];
        float w = __expf(lrelu(el[sn * 4 + h] + eh));
        ushort4 v = *(const ushort4*)&featb[(size_t)sn * 256 + f];
        den += w;
        acc.x += w * bf2f(v.x);
        acc.y += w * bf2f(v.y);
        acc.z += w * bf2f(v.z);
        acc.w += w * bf2f(v.w);
    }
    float inv = 1.f / fmaxf(den, 1e-9f);
    float4 r = *(const float4*)&hio[(size_t)wid * 256 + f];
    float4 o;
    o.x = fmaxf(acc.x * inv + r.x, 0.f);
    o.y = fmaxf(acc.y * inv + r.y, 0.f);
    o.z = fmaxf(acc.z * inv + r.z, 0.f);
    o.w = fmaxf(acc.w * inv + r.w, 0.f);
    *(float4*)&hio[(size_t)wid * 256 + f] = o;
    ushort4 ob;
    ob.x = f2bf(o.x); ob.y = f2bf(o.y); ob.z = f2bf(o.z); ob.w = f2bf(o.w);
    *(ushort4*)&hb16[(size_t)wid * 256 + f] = ob;
}

__global__ __launch_bounds__(256) void agg3_k(const unsigned short* __restrict__ featb,
                                              const float* __restrict__ el,
                                              const float* __restrict__ er,
                                              const int* __restrict__ row_ptr,
                                              const int* __restrict__ csr_src,
                                              const float* __restrict__ hres,
                                              unsigned short* __restrict__ hsmallb) {
    int wid = blockIdx.x * 4 + (threadIdx.x >> 6);
    int lane = threadIdx.x & 63;
    if (wid >= NN) return;
    int f = lane * 4;
    int start = row_ptr[wid], end = row_ptr[wid + 1];
    int h = lane >> 4;
    float eh = er[wid * 4 + h];

    float4 acc = {0.f, 0.f, 0.f, 0.f};
    float den = 0.f;
    int s = start;
    for (; s + 3 < end; s += 4) {
        int sn0 = csr_src[s], sn1 = csr_src[s + 1];
        int sn2 = csr_src[s + 2], sn3 = csr_src[s + 3];
        float e0 = el[sn0 * 4 + h], e1 = el[sn1 * 4 + h];
        float e2 = el[sn2 * 4 + h], e3 = el[sn3 * 4 + h];
        ushort4 v0 = *(const ushort4*)&featb[(size_t)sn0 * 256 + f];
        ushort4 v1 = *(const ushort4*)&featb[(size_t)sn1 * 256 + f];
        ushort4 v2 = *(const ushort4*)&featb[(size_t)sn2 * 256 + f];
        ushort4 v3 = *(const ushort4*)&featb[(size_t)sn3 * 256 + f];
        float w0 = __expf(lrelu(e0 + eh)), w1 = __expf(lrelu(e1 + eh));
        float w2 = __expf(lrelu(e2 + eh)), w3 = __expf(lrelu(e3 + eh));
        den += (w0 + w1) + (w2 + w3);
        acc.x += w0 * bf2f(v0.x) + w1 * bf2f(v1.x) + w2 * bf2f(v2.x) + w3 * bf2f(v3.x);
        acc.y += w0 * bf2f(v0.y) + w1 * bf2f(v1.y) + w2 * bf2f(v2.y) + w3 * bf2f(v3.y);
        acc.z += w0 * bf2f(v0.z) + w1 * bf2f(v1.z) + w2 * bf2f(v2.z) + w3 * bf2f(v3.z);
        acc.w += w0 * bf2f(v0.w) + w1 * bf2f(v1.w) + w2 * bf2f(v2.w) + w3 * bf2f(v3.w);
    }
    for (; s < end; ++s) {
        int sn = csr_src[s];
        float w = __expf(lrelu(el[sn * 4 + h] + eh));
        ushort4 v = *(const ushort4*)&featb[(size_t)sn * 256 + f];
        den += w;
        acc.x += w * bf2f(v.x);
        acc.y += w * bf2f(v.y);
        acc.z += w * bf2f(v.z);
        acc.w += w * bf2f(v.w);
    }
    float inv = 1.f / fmaxf(den, 1e-9f);
    float4 r = *(const float4*)&hres[(size_t)wid * 256 + f];
    float4 o;
    o.x = acc.x * inv + r.x;
    o.y = acc.y * inv + r.y;
    o.z = acc.z * inv + r.z;
    o.w = acc.w * inv + r.w;
    o.x += __shfl_xor(o.x, 16); o.y += __shfl_xor(o.y, 16);
    o.z += __shfl_xor(o.z, 16); o.w += __shfl_xor(o.w, 16);
    o.x += __shfl_xor(o.x, 32); o.y += __shfl_xor(o.y, 32);
    o.z += __shfl_xor(o.z, 32); o.w += __shfl_xor(o.w, 32);
    if (lane < 16) {
        ushort4 m4;
        m4.x = f2bf(o.x * 0.25f);
        m4.y = f2bf(o.y * 0.25f);
        m4.z = f2bf(o.z * 0.25f);
        m4.w = f2bf(o.w * 0.25f);
        *(ushort4*)&hsmallb[(size_t)wid * 64 + lane * 4] = m4;
    }
}

// ---------------- MFMA GEMM: [N,256]bf16 @ BT[n][k]bf16 -> [N,256]bf16 ----------------
__global__ __launch_bounds__(256) void gemm_mfma_k(const unsigned short* __restrict__ Ab,
                                                   const unsigned short* __restrict__ BT,
                                                   unsigned short* __restrict__ C) {
    __shared__ __align__(16) short As[128 * 40];
    __shared__ __align__(16) short Bs[128 * 40];
    int tid = threadIdx.x;
    int lane = tid & 63, wave = tid >> 6;
    int wr = wave >> 1, wc = wave & 1;
    int tileM = blockIdx.x * 128;
    int tileN = blockIdx.y * 128;

    int srow = tid >> 1, sko = (tid & 1) * 16;
    int fm = lane & 15, kg = lane >> 4;

    f32x4 acc[4][4];
#pragma unroll
    for (int i = 0; i < 4; ++i)
#pragma unroll
        for (int j = 0; j < 4; ++j) acc[i][j] = (f32x4){0.f, 0.f, 0.f, 0.f};

    for (int k0 = 0; k0 < 256; k0 += 32) {
        int gr = tileM + srow;
        short8 a0 = (short8)0, a1 = (short8)0;
        if (gr < NN) {
            a0 = *(const short8*)&Ab[(size_t)gr * 256 + k0 + sko];
            a1 = *(const short8*)&Ab[(size_t)gr * 256 + k0 + sko + 8];
        }
        *(short8*)&As[srow * 40 + sko] = a0;
        *(short8*)&As[srow * 40 + sko + 8] = a1;
        short8 b0 = *(const short8*)&BT[(size_t)(tileN + srow) * 256 + k0 + sko];
        short8 b1 = *(const short8*)&BT[(size_t)(tileN + srow) * 256 + k0 + sko + 8];
        *(short8*)&Bs[srow * 40 + sko] = b0;
        *(short8*)&Bs[srow * 40 + sko + 8] = b1;
        __syncthreads();

        short8 afr[4], bfr[4];
#pragma unroll
        for (int mi = 0; mi < 4; ++mi)
            afr[mi] = *(const short8*)&As[(wr * 64 + mi * 16 + fm) * 40 + kg * 8];
#pragma unroll
        for (int ni = 0; ni < 4; ++ni)
            bfr[ni] = *(const short8*)&Bs[(wc * 64 + ni * 16 + fm) * 40 + kg * 8];
#pragma unroll
        for (int mi = 0; mi < 4; ++mi)
#pragma unroll
            for (int ni = 0; ni < 4; ++ni)
                acc[mi][ni] = __builtin_amdgcn_mfma_f32_16x16x32_bf16(
                    afr[mi], bfr[ni], acc[mi][ni], 0, 0, 0);
        __syncthreads();
    }

#pragma unroll
    for (int mi = 0; mi < 4; ++mi) {
#pragma unroll
        for (int ni = 0; ni < 4; ++ni) {
            int col = tileN + wc * 64 + ni * 16 + fm;
#pragma unroll
            for (int r = 0; r < 4; ++r) {
                int row = tileM + wr * 64 + mi * 16 + kg * 4 + r;
                if (row < NN) C[(size_t)row * 256 + col] = f2bf(acc[mi][ni][r]);
            }
        }
    }
}

// ---------------- edge scoring MLP: LDS-tiled micro-GEMM, 64 edges/block, bf16 hsmall ----------------
__global__ __launch_bounds__(256) void edge_score3_k(const unsigned short* __restrict__ hs,
                                                     const int* __restrict__ src,
                                                     const int* __restrict__ dst,
                                                     const float* __restrict__ mW1,
                                                     const float* __restrict__ mb1,
                                                     const float* __restrict__ mW2,
                                                     const float* __restrict__ mb2,
                                                     float* __restrict__ out) {
    __shared__ __align__(16) float Ws[64 * 64];
    __shared__ __align__(16) float xT[64][66];
    __shared__ __align__(16) float b1s[64];
    __shared__ __align__(16) float w2s[64];
    int tid = threadIdx.x;
    for (int i = tid * 4; i < 4096; i += 1024)
        *(float4*)&Ws[i] = *(const float4*)&mW1[i];
    if (tid < 64) { b1s[tid] = mb1[tid]; w2s[tid] = mW2[tid]; }

    int e_loc = tid >> 2, q = tid & 3;
    int e = blockIdx.x * 64 + e_loc;
    int s = src[e], d = dst[e];
    const unsigned short* rs = &hs[(size_t)s * 64 + q * 16];
    const unsigned short* rd = &hs[(size_t)d * 64 + q * 16];
#pragma unroll
    for (int i = 0; i < 4; ++i) {
        ushort4 a = *(const ushort4*)&rs[i * 4];
        ushort4 b = *(const ushort4*)&rd[i * 4];
        int k = q * 16 + i * 4;
        xT[k + 0][e_loc] = fabsf(bf2f(a.x) - bf2f(b.x));
        xT[k + 1][e_loc] = fabsf(bf2f(a.y) - bf2f(b.y));
        xT[k + 2][e_loc] = fabsf(bf2f(a.z) - bf2f(b.z));
        xT[k + 3][e_loc] = fabsf(bf2f(a.w) - bf2f(b.w));
    }
    __syncthreads();

    int eq = tid >> 4, jq = tid & 15;
    float4 bb = *(const float4*)&b1s[jq * 4];
    float4 acc0 = bb, acc1 = bb, acc2 = bb, acc3 = bb;
#pragma unroll
    for (int k = 0; k < 64; ++k) {
        float4 xv = *(const float4*)&xT[k][eq * 4];
        float4 wv = *(const float4*)&Ws[k * 64 + jq * 4];
        acc0.x += xv.x * wv.x; acc0.y += xv.x * wv.y; acc0.z += xv.x * wv.z; acc0.w += xv.x * wv.w;
        acc1.x += xv.y * wv.x; acc1.y += xv.y * wv.y; acc1.z += xv.y * wv.z; acc1.w += xv.y * wv.w;
        acc2.x += xv.z * wv.x; acc2.y += xv.z * wv.y; acc2.z += xv.z * wv.z; acc2.w += xv.z * wv.w;
        acc3.x += xv.w * wv.x; acc3.y += xv.w * wv.y; acc3.z += xv.w * wv.z; acc3.w += xv.w * wv.w;
    }
    float4 w2 = *(const float4*)&w2s[jq * 4];
    float t0 = fmaxf(acc0.x, 0.f) * w2.x + fmaxf(acc0.y, 0.f) * w2.y +
               fmaxf(acc0.z, 0.f) * w2.z + fmaxf(acc0.w, 0.f) * w2.w;
    float t1 = fmaxf(acc1.x, 0.f) * w2.x + fmaxf(acc1.y, 0.f) * w2.y +
               fmaxf(acc1.z, 0.f) * w2.z + fmaxf(acc1.w, 0.f) * w2.w;
    float t2 = fmaxf(acc2.x, 0.f) * w2.x + fmaxf(acc2.y, 0.f) * w2.y +
               fmaxf(acc2.z, 0.f) * w2.z + fmaxf(acc2.w, 0.f) * w2.w;
    float t3 = fmaxf(acc3.x, 0.f) * w2.x + fmaxf(acc3.y, 0.f) * w2.y +
               fmaxf(acc3.z, 0.f) * w2.z + fmaxf(acc3.w, 0.f) * w2.w;
#pragma unroll
    for (int off = 1; off < 16; off <<= 1) {
        t0 += __shfl_xor(t0, off);
        t1 += __shfl_xor(t1, off);
        t2 += __shfl_xor(t2, off);
        t3 += __shfl_xor(t3, off);
    }
    if (jq == 0) {
        float bias = mb2[0];
        int base = blockIdx.x * 64 + eq * 4;
        out[base + 0] = 1.f / (1.f + __expf(-(t0 + bias)));
        out[base + 1] = 1.f / (1.f + __expf(-(t1 + bias)));
        out[base + 2] = 1.f / (1.f + __expf(-(t2 + bias)));
        out[base + 3] = 1.f / (1.f + __expf(-(t3 + bias)));
    }
}

extern "C" void kernel_launch(void* const* d_in, const int* in_sizes, int n_in,
                              void* d_out, int out_size, void* d_ws, size_t ws_size,
                              hipStream_t stream) {
    (void)in_sizes; (void)n_in; (void)out_size; (void)ws_size;
    const float* pos   = (const float*)d_in[0];
    const int*   src   = (const int*)d_in[1];
    const int*   dst   = (const int*)d_in[2];
    const float* W1    = (const float*)d_in[3];
    const float* al1   = (const float*)d_in[4];
    const float* ar1   = (const float*)d_in[5];
    const float* resW1 = (const float*)d_in[6];
    const float* W2    = (const float*)d_in[7];
    const float* al2   = (const float*)d_in[8];
    const float* ar2   = (const float*)d_in[9];
    const float* W3    = (const float*)d_in[10];
    const float* al3   = (const float*)d_in[11];
    const float* ar3   = (const float*)d_in[12];
    const float* mW1   = (const float*)d_in[13];
    const float* mb1   = (const float*)d_in[14];
    const float* mW2   = (const float*)d_in[15];
    const float* mb2   = (const float*)d_in[16];
    float* out = (float*)d_out;

    char* ws = (char*)d_ws;
    size_t off = 0;
    auto alloc = [&](size_t bytes) {
        void* p = ws + off;
        off += (bytes + 255) & ~(size_t)255;
        return p;
    };
    float* Hbuf            = (float*)alloc((size_t)NN * 256 * 4);
    unsigned short* FEATb  = (unsigned short*)alloc((size_t)NN * 256 * 2);
    unsigned short* Hb16   = (unsigned short*)alloc((size_t)NN * 256 * 2);
    unsigned short* BT2    = (unsigned short*)alloc((size_t)256 * 256 * 2);
    unsigned short* BT3    = (unsigned short*)alloc((size_t)256 * 256 * 2);
    unsigned short* hsmallb = (unsigned short*)alloc((size_t)NN * 64 * 2);
    float* el     = (float*)alloc((size_t)NN * 4 * 4);
    float* er     = (float*)alloc((size_t)NN * 4 * 4);
    int* deg      = (int*)alloc((size_t)NN * 4);
    int* row_ptr  = (int*)alloc((size_t)(NN + 1) * 4);
    int* cursor   = (int*)alloc((size_t)NN * 4);
    int* csr      = (int*)alloc((size_t)EE * 4);

    hipMemsetAsync(deg, 0, (size_t)NN * 4, stream);
    hist_k<<<(EE + 255) / 256, 256, 0, stream>>>(dst, deg);
    scan_k<<<1, 1024, 0, stream>>>(deg, row_ptr, cursor);
    scatter_k<<<(EE + 255) / 256, 256, 0, stream>>>(src, dst, cursor, csr);
    bconv_k<<<256, 256, 0, stream>>>(W2, W3, BT2, BT3);

    // layer 1
    eler1_k<<<NN / 4 + 1, 256, 0, stream>>>(pos, W1, al1, ar1, el, er);
    agg1_k<<<NN / 4 + 1, 256, 0, stream>>>(pos, W1, resW1, el, er, row_ptr, csr, Hbuf, Hb16);

    dim3 ggrid((NN + 127) / 128, 2);
    // layer 2
    gemm_mfma_k<<<ggrid, 256, 0, stream>>>(Hb16, BT2, FEATb);
    eler_b_k<<<NN / 4 + 1, 256, 0, stream>>>(FEATb, al2, ar2, el, er);
    agg_k<<<NN / 4 + 1, 256, 0, stream>>>(FEATb, el, er, row_ptr, csr, Hbuf, Hb16);

    // layer 3
    gemm_mfma_k<<<ggrid, 256, 0, stream>>>(Hb16, BT3, FEATb);
    eler_b_k<<<NN / 4 + 1, 256, 0, stream>>>(FEATb, al3, ar3, el, er);
    agg3_k<<<NN / 4 + 1, 256, 0, stream>>>(FEATb, el, er, row_ptr, csr, Hbuf, hsmallb);

    // edge MLP
    edge_score3_k<<<EE / 64, 256, 0, stream>>>(hsmallb, src, dst, mW1, mb1, mW2, mb2, out);
}

// Round 8
// 505.962 us; speedup vs baseline: 2.3276x; 1.1343x over previous
//
#include <hip/hip_runtime.h>
#include <hip/hip_bf16.h>

#define NN 50000
#define EE 800000

typedef short short8 __attribute__((ext_vector_type(8)));
typedef float f32x4 __attribute__((ext_vector_type(4)));

__device__ __forceinline__ float lrelu(float x) { return x > 0.f ? x : 0.2f * x; }

__device__ __forceinline__ unsigned short f2bf(float x) {
    __hip_bfloat16 b = __float2bfloat16(x);
    return *(unsigned short*)&b;
}
__device__ __forceinline__ float bf2f(unsigned short u) {
    return __uint_as_float(((unsigned int)u) << 16);
}

// ---------------- CSR build ----------------
__global__ void hist_k(const int* __restrict__ dst, int* __restrict__ deg) {
    int i = blockIdx.x * 256 + threadIdx.x;
    if (i < EE) atomicAdd(&deg[dst[i]], 1);
}

__global__ __launch_bounds__(1024) void scan_k(const int* __restrict__ deg,
                                               int* __restrict__ row_ptr,
                                               int* __restrict__ cursor) {
    __shared__ int wsum[16];
    int tid = threadIdx.x, lane = tid & 63, w = tid >> 6;
    int carry = 0;
    for (int base = 0; base < NN; base += 1024) {
        int i = base + tid;
        int v = (i < NN) ? deg[i] : 0;
        int x = v;
#pragma unroll
        for (int off = 1; off < 64; off <<= 1) {
            int y = __shfl_up(x, off);
            if (lane >= off) x += y;
        }
        if (lane == 63) wsum[w] = x;
        __syncthreads();
        if (tid < 16) {
            int s = wsum[tid];
#pragma unroll
            for (int off = 1; off < 16; off <<= 1) {
                int y = __shfl_up(s, off);
                if (tid >= off) s += y;
            }
            wsum[tid] = s;
        }
        __syncthreads();
        int woff = w ? wsum[w - 1] : 0;
        int excl = carry + woff + x - v;
        if (i < NN) { row_ptr[i] = excl; cursor[i] = excl; }
        carry += wsum[15];
        __syncthreads();
    }
    if (tid == 0) row_ptr[NN] = carry;
}

__global__ void scatter_k(const int* __restrict__ src, const int* __restrict__ dst,
                          int* __restrict__ cursor, int* __restrict__ csr_src) {
    int i = blockIdx.x * 256 + threadIdx.x;
    if (i < EE) {
        int slot = atomicAdd(&cursor[dst[i]], 1);
        csr_src[slot] = src[i];
    }
}

// ---------------- weights -> bf16 (W2/W3 transposed; mW1 transposed) ----------------
__global__ __launch_bounds__(256) void bconv_k(const float* __restrict__ W2,
                                               const float* __restrict__ W3,
                                               const float* __restrict__ mW1,
                                               unsigned short* __restrict__ BT2,
                                               unsigned short* __restrict__ BT3,
                                               unsigned short* __restrict__ W1Tb) {
    int tid = blockIdx.x * 256 + threadIdx.x;   // 65536
    int k = tid & 255, n = tid >> 8;
    BT2[n * 256 + k] = f2bf(W2[k * 256 + n]);
    BT3[n * 256 + k] = f2bf(W3[k * 256 + n]);
    if (tid < 4096) {
        int kk = tid & 63, nn = tid >> 6;
        W1Tb[nn * 64 + kk] = f2bf(mW1[kk * 64 + nn]);
    }
}

// ---------------- attention logits el/er ----------------
__global__ __launch_bounds__(256) void eler1_k(const float* __restrict__ pos,
                                               const float* __restrict__ W1,
                                               const float* __restrict__ al,
                                               const float* __restrict__ ar,
                                               float* __restrict__ el,
                                               float* __restrict__ er) {
    int wid = blockIdx.x * 4 + (threadIdx.x >> 6);
    int lane = threadIdx.x & 63;
    if (wid >= NN) return;
    int f = lane * 4;
    float4 w0 = *(const float4*)&W1[f];
    float4 w1 = *(const float4*)&W1[256 + f];
    float4 a4 = *(const float4*)&al[f];
    float4 r4 = *(const float4*)&ar[f];
    float2 p = *(const float2*)&pos[wid * 2];
    float fx = p.x * w0.x + p.y * w1.x;
    float fy = p.x * w0.y + p.y * w1.y;
    float fz = p.x * w0.z + p.y * w1.z;
    float fw = p.x * w0.w + p.y * w1.w;
    float pl = fx * a4.x + fy * a4.y + fz * a4.z + fw * a4.w;
    float pr = fx * r4.x + fy * r4.y + fz * r4.z + fw * r4.w;
#pragma unroll
    for (int off = 1; off < 16; off <<= 1) {
        pl += __shfl_xor(pl, off);
        pr += __shfl_xor(pr, off);
    }
    if ((lane & 15) == 0) {
        int h = lane >> 4;
        el[wid * 4 + h] = pl;
        er[wid * 4 + h] = pr;
    }
}

// bf16-feat variant
__global__ __launch_bounds__(256) void eler_b_k(const unsigned short* __restrict__ featb,
                                                const float* __restrict__ al,
                                                const float* __restrict__ ar,
                                                float* __restrict__ el,
                                                float* __restrict__ er) {
    int wid = blockIdx.x * 4 + (threadIdx.x >> 6);
    int lane = threadIdx.x & 63;
    if (wid >= NN) return;
    int f = lane * 4;
    ushort4 u = *(const ushort4*)&featb[(size_t)wid * 256 + f];
    float4 a4 = *(const float4*)&al[f];
    float4 r4 = *(const float4*)&ar[f];
    float vx = bf2f(u.x), vy = bf2f(u.y), vz = bf2f(u.z), vw = bf2f(u.w);
    float pl = vx * a4.x + vy * a4.y + vz * a4.z + vw * a4.w;
    float pr = vx * r4.x + vy * r4.y + vz * r4.z + vw * r4.w;
#pragma unroll
    for (int off = 1; off < 16; off <<= 1) {
        pl += __shfl_xor(pl, off);
        pr += __shfl_xor(pr, off);
    }
    if ((lane & 15) == 0) {
        int h = lane >> 4;
        el[wid * 4 + h] = pl;
        er[wid * 4 + h] = pr;
    }
}

// ---------------- aggregation: one wave per dst node, ONE-PASS softmax ----------------
__global__ __launch_bounds__(256) void agg1_k(const float* __restrict__ pos,
                                              const float* __restrict__ W1,
                                              const float* __restrict__ resW1,
                                              const float* __restrict__ el,
                                              const float* __restrict__ er,
                                              const int* __restrict__ row_ptr,
                                              const int* __restrict__ csr_src,
                                              float* __restrict__ hout,
                                              unsigned short* __restrict__ hb16) {
    int wid = blockIdx.x * 4 + (threadIdx.x >> 6);
    int lane = threadIdx.x & 63;
    if (wid >= NN) return;
    int f = lane * 4;
    int start = row_ptr[wid], end = row_ptr[wid + 1];
    int h = lane >> 4;
    float eh = er[wid * 4 + h];

    float ap0 = 0.f, ap1 = 0.f, den = 0.f;
    int s = start;
    for (; s + 3 < end; s += 4) {
        int sn0 = csr_src[s], sn1 = csr_src[s + 1];
        int sn2 = csr_src[s + 2], sn3 = csr_src[s + 3];
        float e0 = el[sn0 * 4 + h], e1 = el[sn1 * 4 + h];
        float e2 = el[sn2 * 4 + h], e3 = el[sn3 * 4 + h];
        float2 p0 = *(const float2*)&pos[sn0 * 2];
        float2 p1 = *(const float2*)&pos[sn1 * 2];
        float2 p2 = *(const float2*)&pos[sn2 * 2];
        float2 p3 = *(const float2*)&pos[sn3 * 2];
        float w0 = __expf(lrelu(e0 + eh)), w1 = __expf(lrelu(e1 + eh));
        float w2 = __expf(lrelu(e2 + eh)), w3 = __expf(lrelu(e3 + eh));
        den += (w0 + w1) + (w2 + w3);
        ap0 += w0 * p0.x + w1 * p1.x + w2 * p2.x + w3 * p3.x;
        ap1 += w0 * p0.y + w1 * p1.y + w2 * p2.y + w3 * p3.y;
    }
    for (; s < end; ++s) {
        int sn = csr_src[s];
        float w = __expf(lrelu(el[sn * 4 + h] + eh));
        float2 p = *(const float2*)&pos[sn * 2];
        den += w;
        ap0 += w * p.x;
        ap1 += w * p.y;
    }
    float inv = 1.f / fmaxf(den, 1e-9f);
    ap0 *= inv;
    ap1 *= inv;

    float4 w0 = *(const float4*)&W1[f];
    float4 w1 = *(const float4*)&W1[256 + f];
    float4 rw0 = *(const float4*)&resW1[f];
    float4 rw1 = *(const float4*)&resW1[256 + f];
    float2 pd = *(const float2*)&pos[wid * 2];
    float4 o;
    o.x = fmaxf(ap0 * w0.x + ap1 * w1.x + pd.x * rw0.x + pd.y * rw1.x, 0.f);
    o.y = fmaxf(ap0 * w0.y + ap1 * w1.y + pd.x * rw0.y + pd.y * rw1.y, 0.f);
    o.z = fmaxf(ap0 * w0.z + ap1 * w1.z + pd.x * rw0.z + pd.y * rw1.z, 0.f);
    o.w = fmaxf(ap0 * w0.w + ap1 * w1.w + pd.x * rw0.w + pd.y * rw1.w, 0.f);
    *(float4*)&hout[(size_t)wid * 256 + f] = o;
    ushort4 ob;
    ob.x = f2bf(o.x); ob.y = f2bf(o.y); ob.z = f2bf(o.z); ob.w = f2bf(o.w);
    *(ushort4*)&hb16[(size_t)wid * 256 + f] = ob;
}

__global__ __launch_bounds__(256) void agg_k(const unsigned short* __restrict__ featb,
                                             const float* __restrict__ el,
                                             const float* __restrict__ er,
                                             const int* __restrict__ row_ptr,
                                             const int* __restrict__ csr_src,
                                             float* __restrict__ hio,
                                             unsigned short* __restrict__ hb16) {
    int wid = blockIdx.x * 4 + (threadIdx.x >> 6);
    int lane = threadIdx.x & 63;
    if (wid >= NN) return;
    int f = lane * 4;
    int start = row_ptr[wid], end = row_ptr[wid + 1];
    int h = lane >> 4;
    float eh = er[wid * 4 + h];

    float4 acc = {0.f, 0.f, 0.f, 0.f};
    float den = 0.f;
    int s = start;
    for (; s + 3 < end; s += 4) {
        int sn0 = csr_src[s], sn1 = csr_src[s + 1];
        int sn2 = csr_src[s + 2], sn3 = csr_src[s + 3];
        float e0 = el[sn0 * 4 + h], e1 = el[sn1 * 4 + h];
        float e2 = el[sn2 * 4 + h], e3 = el[sn3 * 4 + h];
        ushort4 v0 = *(const ushort4*)&featb[(size_t)sn0 * 256 + f];
        ushort4 v1 = *(const ushort4*)&featb[(size_t)sn1 * 256 + f];
        ushort4 v2 = *(const ushort4*)&featb[(size_t)sn2 * 256 + f];
        ushort4 v3 = *(const ushort4*)&featb[(size_t)sn3 * 256 + f];
        float w0 = __expf(lrelu(e0 + eh)), w1 = __expf(lrelu(e1 + eh));
        float w2 = __expf(lrelu(e2 + eh)), w3 = __expf(lrelu(e3 + eh));
        den += (w0 + w1) + (w2 + w3);
        acc.x += w0 * bf2f(v0.x) + w1 * bf2f(v1.x) + w2 * bf2f(v2.x) + w3 * bf2f(v3.x);
        acc.y += w0 * bf2f(v0.y) + w1 * bf2f(v1.y) + w2 * bf2f(v2.y) + w3 * bf2f(v3.y);
        acc.z += w0 * bf2f(v0.z) + w1 * bf2f(v1.z) + w2 * bf2f(v2.z) + w3 * bf2f(v3.z);
        acc.w += w0 * bf2f(v0.w) + w1 * bf2f(v1.w) + w2 * bf2f(v2.w) + w3 * bf2f(v3.w);
    }
    for (; s < end; ++s) {
        int sn = csr_src[s];
        float w = __expf(lrelu(el[sn * 4 + h] + eh));
        ushort4 v = *(const ushort4*)&featb[(size_t)sn * 256 + f];
        den += w;
        acc.x += w * bf2f(v.x);
        acc.y += w * bf2f(v.y);
        acc.z += w * bf2f(v.z);
        acc.w += w * bf2f(v.w);
    }
    float inv = 1.f / fmaxf(den, 1e-9f);
    float4 r = *(const float4*)&hio[(size_t)wid * 256 + f];
    float4 o;
    o.x = fmaxf(acc.x * inv + r.x, 0.f);
    o.y = fmaxf(acc.y * inv + r.y, 0.f);
    o.z = fmaxf(acc.z * inv + r.z, 0.f);
    o.w = fmaxf(acc.w * inv + r.w, 0.f);
    *(float4*)&hio[(size_t)wid * 256 + f] = o;
    ushort4 ob;
    ob.x = f2bf(o.x); ob.y = f2bf(o.y); ob.z = f2bf(o.z); ob.w = f2bf(o.w);
    *(ushort4*)&hb16[(size_t)wid * 256 + f] = ob;
}

__global__ __launch_bounds__(256) void agg3_k(const unsigned short* __restrict__ featb,
                                              const float* __restrict__ el,
                                              const float* __restrict__ er,
                                              const int* __restrict__ row_ptr,
                                              const int* __restrict__ csr_src,
                                              const float* __restrict__ hres,
                                              unsigned short* __restrict__ hsmallb) {
    int wid = blockIdx.x * 4 + (threadIdx.x >> 6);
    int lane = threadIdx.x & 63;
    if (wid >= NN) return;
    int f = lane * 4;
    int start = row_ptr[wid], end = row_ptr[wid + 1];
    int h = lane >> 4;
    float eh = er[wid * 4 + h];

    float4 acc = {0.f, 0.f, 0.f, 0.f};
    float den = 0.f;
    int s = start;
    for (; s + 3 < end; s += 4) {
        int sn0 = csr_src[s], sn1 = csr_src[s + 1];
        int sn2 = csr_src[s + 2], sn3 = csr_src[s + 3];
        float e0 = el[sn0 * 4 + h], e1 = el[sn1 * 4 + h];
        float e2 = el[sn2 * 4 + h], e3 = el[sn3 * 4 + h];
        ushort4 v0 = *(const ushort4*)&featb[(size_t)sn0 * 256 + f];
        ushort4 v1 = *(const ushort4*)&featb[(size_t)sn1 * 256 + f];
        ushort4 v2 = *(const ushort4*)&featb[(size_t)sn2 * 256 + f];
        ushort4 v3 = *(const ushort4*)&featb[(size_t)sn3 * 256 + f];
        float w0 = __expf(lrelu(e0 + eh)), w1 = __expf(lrelu(e1 + eh));
        float w2 = __expf(lrelu(e2 + eh)), w3 = __expf(lrelu(e3 + eh));
        den += (w0 + w1) + (w2 + w3);
        acc.x += w0 * bf2f(v0.x) + w1 * bf2f(v1.x) + w2 * bf2f(v2.x) + w3 * bf2f(v3.x);
        acc.y += w0 * bf2f(v0.y) + w1 * bf2f(v1.y) + w2 * bf2f(v2.y) + w3 * bf2f(v3.y);
        acc.z += w0 * bf2f(v0.z) + w1 * bf2f(v1.z) + w2 * bf2f(v2.z) + w3 * bf2f(v3.z);
        acc.w += w0 * bf2f(v0.w) + w1 * bf2f(v1.w) + w2 * bf2f(v2.w) + w3 * bf2f(v3.w);
    }
    for (; s < end; ++s) {
        int sn = csr_src[s];
        float w = __expf(lrelu(el[sn * 4 + h] + eh));
        ushort4 v = *(const ushort4*)&featb[(size_t)sn * 256 + f];
        den += w;
        acc.x += w * bf2f(v.x);
        acc.y += w * bf2f(v.y);
        acc.z += w * bf2f(v.z);
        acc.w += w * bf2f(v.w);
    }
    float inv = 1.f / fmaxf(den, 1e-9f);
    float4 r = *(const float4*)&hres[(size_t)wid * 256 + f];
    float4 o;
    o.x = acc.x * inv + r.x;
    o.y = acc.y * inv + r.y;
    o.z = acc.z * inv + r.z;
    o.w = acc.w * inv + r.w;
    o.x += __shfl_xor(o.x, 16); o.y += __shfl_xor(o.y, 16);
    o.z += __shfl_xor(o.z, 16); o.w += __shfl_xor(o.w, 16);
    o.x += __shfl_xor(o.x, 32); o.y += __shfl_xor(o.y, 32);
    o.z += __shfl_xor(o.z, 32); o.w += __shfl_xor(o.w, 32);
    if (lane < 16) {
        ushort4 m4;
        m4.x = f2bf(o.x * 0.25f);
        m4.y = f2bf(o.y * 0.25f);
        m4.z = f2bf(o.z * 0.25f);
        m4.w = f2bf(o.w * 0.25f);
        *(ushort4*)&hsmallb[(size_t)wid * 64 + lane * 4] = m4;
    }
}

// ---------------- MFMA GEMM: [N,256]bf16 @ BT[n][k]bf16 -> [N,256]bf16 ----------------
__global__ __launch_bounds__(256) void gemm_mfma_k(const unsigned short* __restrict__ Ab,
                                                   const unsigned short* __restrict__ BT,
                                                   unsigned short* __restrict__ C) {
    __shared__ __align__(16) short As[128 * 40];
    __shared__ __align__(16) short Bs[128 * 40];
    int tid = threadIdx.x;
    int lane = tid & 63, wave = tid >> 6;
    int wr = wave >> 1, wc = wave & 1;
    int tileM = blockIdx.x * 128;
    int tileN = blockIdx.y * 128;

    int srow = tid >> 1, sko = (tid & 1) * 16;
    int fm = lane & 15, kg = lane >> 4;

    f32x4 acc[4][4];
#pragma unroll
    for (int i = 0; i < 4; ++i)
#pragma unroll
        for (int j = 0; j < 4; ++j) acc[i][j] = (f32x4){0.f, 0.f, 0.f, 0.f};

    for (int k0 = 0; k0 < 256; k0 += 32) {
        int gr = tileM + srow;
        short8 a0 = (short8)0, a1 = (short8)0;
        if (gr < NN) {
            a0 = *(const short8*)&Ab[(size_t)gr * 256 + k0 + sko];
            a1 = *(const short8*)&Ab[(size_t)gr * 256 + k0 + sko + 8];
        }
        *(short8*)&As[srow * 40 + sko] = a0;
        *(short8*)&As[srow * 40 + sko + 8] = a1;
        short8 b0 = *(const short8*)&BT[(size_t)(tileN + srow) * 256 + k0 + sko];
        short8 b1 = *(const short8*)&BT[(size_t)(tileN + srow) * 256 + k0 + sko + 8];
        *(short8*)&Bs[srow * 40 + sko] = b0;
        *(short8*)&Bs[srow * 40 + sko + 8] = b1;
        __syncthreads();

        short8 afr[4], bfr[4];
#pragma unroll
        for (int mi = 0; mi < 4; ++mi)
            afr[mi] = *(const short8*)&As[(wr * 64 + mi * 16 + fm) * 40 + kg * 8];
#pragma unroll
        for (int ni = 0; ni < 4; ++ni)
            bfr[ni] = *(const short8*)&Bs[(wc * 64 + ni * 16 + fm) * 40 + kg * 8];
#pragma unroll
        for (int mi = 0; mi < 4; ++mi)
#pragma unroll
            for (int ni = 0; ni < 4; ++ni)
                acc[mi][ni] = __builtin_amdgcn_mfma_f32_16x16x32_bf16(
                    afr[mi], bfr[ni], acc[mi][ni], 0, 0, 0);
        __syncthreads();
    }

#pragma unroll
    for (int mi = 0; mi < 4; ++mi) {
#pragma unroll
        for (int ni = 0; ni < 4; ++ni) {
            int col = tileN + wc * 64 + ni * 16 + fm;
#pragma unroll
            for (int r = 0; r < 4; ++r) {
                int row = tileM + wr * 64 + mi * 16 + kg * 4 + r;
                if (row < NN) C[(size_t)row * 256 + col] = f2bf(acc[mi][ni][r]);
            }
        }
    }
}

// ---------------- edge scoring MLP v4: MFMA, 64 edges/block ----------------
// x[64 edges][64 k] bf16 in LDS (rows padded to 72 shorts, 16B-aligned),
// W1T[n][k] bf16 rows. Same fragment convention as gemm_mfma_k (verified).
__global__ __launch_bounds__(256) void edge_score4_k(const unsigned short* __restrict__ hs,
                                                     const int* __restrict__ src,
                                                     const int* __restrict__ dst,
                                                     const unsigned short* __restrict__ W1Tb,
                                                     const float* __restrict__ mb1,
                                                     const float* __restrict__ mW2,
                                                     const float* __restrict__ mb2,
                                                     float* __restrict__ out) {
    __shared__ __align__(16) unsigned short xs[64 * 72];
    __shared__ __align__(16) unsigned short wt[64 * 72];
    __shared__ float b1s[64], w2s[64];
    int tid = threadIdx.x;
    int e_loc = tid >> 2, q = tid & 3;

    // stage W1T (4 threads/row, 16 shorts each)
    *(short8*)&wt[e_loc * 72 + q * 16]     = *(const short8*)&W1Tb[e_loc * 64 + q * 16];
    *(short8*)&wt[e_loc * 72 + q * 16 + 8] = *(const short8*)&W1Tb[e_loc * 64 + q * 16 + 8];
    if (tid < 64) { b1s[tid] = mb1[tid]; w2s[tid] = mW2[tid]; }

    // stage x = |h_src - h_dst| (bf16)
    int e = blockIdx.x * 64 + e_loc;                 // EE % 64 == 0
    int s = src[e], d = dst[e];
    const unsigned short* rs = &hs[(size_t)s * 64 + q * 16];
    const unsigned short* rd = &hs[(size_t)d * 64 + q * 16];
    short8 a0 = *(const short8*)&rs[0];
    short8 a1 = *(const short8*)&rs[8];
    short8 b0 = *(const short8*)&rd[0];
    short8 b1 = *(const short8*)&rd[8];
    short8 x0, x1;
#pragma unroll
    for (int i = 0; i < 8; ++i) {
        x0[i] = (short)f2bf(fabsf(bf2f((unsigned short)a0[i]) - bf2f((unsigned short)b0[i])));
        x1[i] = (short)f2bf(fabsf(bf2f((unsigned short)a1[i]) - bf2f((unsigned short)b1[i])));
    }
    *(short8*)&xs[e_loc * 72 + q * 16]     = x0;
    *(short8*)&xs[e_loc * 72 + q * 16 + 8] = x1;
    __syncthreads();

    int lane = tid & 63, w = tid >> 6;
    int fm = lane & 15, kg = lane >> 4;

    // A fragments: row = w*16 + fm, two k-chunks of 32
    const unsigned short* arow = &xs[(w * 16 + fm) * 72];
    short8 af0 = *(const short8*)&arow[kg * 8];
    short8 af1 = *(const short8*)&arow[32 + kg * 8];

    f32x4 acc[4];
#pragma unroll
    for (int ni = 0; ni < 4; ++ni) acc[ni] = (f32x4){0.f, 0.f, 0.f, 0.f};
#pragma unroll
    for (int ni = 0; ni < 4; ++ni) {
        const unsigned short* brow = &wt[(ni * 16 + fm) * 72];
        short8 bf0 = *(const short8*)&brow[kg * 8];
        short8 bf1 = *(const short8*)&brow[32 + kg * 8];
        acc[ni] = __builtin_amdgcn_mfma_f32_16x16x32_bf16(af0, bf0, acc[ni], 0, 0, 0);
        acc[ni] = __builtin_amdgcn_mfma_f32_16x16x32_bf16(af1, bf1, acc[ni], 0, 0, 0);
    }

    // epilogue: relu(+b1) * w2, sum over n (4 ni in-register + 16 fm lanes via shfl)
    float t0 = 0.f, t1 = 0.f, t2 = 0.f, t3 = 0.f;
#pragma unroll
    for (int ni = 0; ni < 4; ++ni) {
        int n = ni * 16 + fm;
        float bb = b1s[n], ww = w2s[n];
        t0 += fmaxf(acc[ni][0] + bb, 0.f) * ww;
        t1 += fmaxf(acc[ni][1] + bb, 0.f) * ww;
        t2 += fmaxf(acc[ni][2] + bb, 0.f) * ww;
        t3 += fmaxf(acc[ni][3] + bb, 0.f) * ww;
    }
#pragma unroll
    for (int off = 1; off < 16; off <<= 1) {
        t0 += __shfl_xor(t0, off);
        t1 += __shfl_xor(t1, off);
        t2 += __shfl_xor(t2, off);
        t3 += __shfl_xor(t3, off);
    }
    if (fm == 0) {
        float bias = mb2[0];
        int base = blockIdx.x * 64 + w * 16 + kg * 4;   // D row = kg*4 + r
        out[base + 0] = 1.f / (1.f + __expf(-(t0 + bias)));
        out[base + 1] = 1.f / (1.f + __expf(-(t1 + bias)));
        out[base + 2] = 1.f / (1.f + __expf(-(t2 + bias)));
        out[base + 3] = 1.f / (1.f + __expf(-(t3 + bias)));
    }
}

extern "C" void kernel_launch(void* const* d_in, const int* in_sizes, int n_in,
                              void* d_out, int out_size, void* d_ws, size_t ws_size,
                              hipStream_t stream) {
    (void)in_sizes; (void)n_in; (void)out_size; (void)ws_size;
    const float* pos   = (const float*)d_in[0];
    const int*   src   = (const int*)d_in[1];
    const int*   dst   = (const int*)d_in[2];
    const float* W1    = (const float*)d_in[3];
    const float* al1   = (const float*)d_in[4];
    const float* ar1   = (const float*)d_in[5];
    const float* resW1 = (const float*)d_in[6];
    const float* W2    = (const float*)d_in[7];
    const float* al2   = (const float*)d_in[8];
    const float* ar2   = (const float*)d_in[9];
    const float* W3    = (const float*)d_in[10];
    const float* al3   = (const float*)d_in[11];
    const float* ar3   = (const float*)d_in[12];
    const float* mW1   = (const float*)d_in[13];
    const float* mb1   = (const float*)d_in[14];
    const float* mW2   = (const float*)d_in[15];
    const float* mb2   = (const float*)d_in[16];
    float* out = (float*)d_out;

    char* ws = (char*)d_ws;
    size_t off = 0;
    auto alloc = [&](size_t bytes) {
        void* p = ws + off;
        off += (bytes + 255) & ~(size_t)255;
        return p;
    };
    float* Hbuf            = (float*)alloc((size_t)NN * 256 * 4);
    unsigned short* FEATb  = (unsigned short*)alloc((size_t)NN * 256 * 2);
    unsigned short* Hb16   = (unsigned short*)alloc((size_t)NN * 256 * 2);
    unsigned short* BT2    = (unsigned short*)alloc((size_t)256 * 256 * 2);
    unsigned short* BT3    = (unsigned short*)alloc((size_t)256 * 256 * 2);
    unsigned short* W1Tb   = (unsigned short*)alloc((size_t)64 * 64 * 2);
    unsigned short* hsmallb = (unsigned short*)alloc((size_t)NN * 64 * 2);
    float* el     = (float*)alloc((size_t)NN * 4 * 4);
    float* er     = (float*)alloc((size_t)NN * 4 * 4);
    int* deg      = (int*)alloc((size_t)NN * 4);
    int* row_ptr  = (int*)alloc((size_t)(NN + 1) * 4);
    int* cursor   = (int*)alloc((size_t)NN * 4);
    int* csr      = (int*)alloc((size_t)EE * 4);

    hipMemsetAsync(deg, 0, (size_t)NN * 4, stream);
    hist_k<<<(EE + 255) / 256, 256, 0, stream>>>(dst, deg);
    scan_k<<<1, 1024, 0, stream>>>(deg, row_ptr, cursor);
    scatter_k<<<(EE + 255) / 256, 256, 0, stream>>>(src, dst, cursor, csr);
    bconv_k<<<256, 256, 0, stream>>>(W2, W3, mW1, BT2, BT3, W1Tb);

    // layer 1
    eler1_k<<<NN / 4 + 1, 256, 0, stream>>>(pos, W1, al1, ar1, el, er);
    agg1_k<<<NN / 4 + 1, 256, 0, stream>>>(pos, W1, resW1, el, er, row_ptr, csr, Hbuf, Hb16);

    dim3 ggrid((NN + 127) / 128, 2);
    // layer 2
    gemm_mfma_k<<<ggrid, 256, 0, stream>>>(Hb16, BT2, FEATb);
    eler_b_k<<<NN / 4 + 1, 256, 0, stream>>>(FEATb, al2, ar2, el, er);
    agg_k<<<NN / 4 + 1, 256, 0, stream>>>(FEATb, el, er, row_ptr, csr, Hbuf, Hb16);

    // layer 3
    gemm_mfma_k<<<ggrid, 256, 0, stream>>>(Hb16, BT3, FEATb);
    eler_b_k<<<NN / 4 + 1, 256, 0, stream>>>(FEATb, al3, ar3, el, er);
    agg3_k<<<NN / 4 + 1, 256, 0, stream>>>(FEATb, el, er, row_ptr, csr, Hbuf, hsmallb);

    // edge MLP (MFMA)
    edge_score4_k<<<EE / 64, 256, 0, stream>>>(hsmallb, src, dst, W1Tb, mb1, mW2, mb2, out);
}

// Round 9
// 494.036 us; speedup vs baseline: 2.3838x; 1.0241x over previous
//
#include <hip/hip_runtime.h>
#include <hip/hip_bf16.h>

#define NN 50000
#define EE 800000

typedef short short8 __attribute__((ext_vector_type(8)));
typedef float f32x4 __attribute__((ext_vector_type(4)));

__device__ __forceinline__ float lrelu(float x) { return x > 0.f ? x : 0.2f * x; }

__device__ __forceinline__ unsigned short f2bf(float x) {
    __hip_bfloat16 b = __float2bfloat16(x);
    return *(unsigned short*)&b;
}
__device__ __forceinline__ float bf2f(unsigned short u) {
    return __uint_as_float(((unsigned int)u) << 16);
}

// ---------------- CSR build ----------------
__global__ void hist_k(const int* __restrict__ dst, int* __restrict__ deg) {
    int i = blockIdx.x * 256 + threadIdx.x;
    if (i < EE) atomicAdd(&deg[dst[i]], 1);
}

__global__ __launch_bounds__(1024) void scan_k(const int* __restrict__ deg,
                                               int* __restrict__ row_ptr,
                                               int* __restrict__ cursor) {
    __shared__ int wsum[16];
    int tid = threadIdx.x, lane = tid & 63, w = tid >> 6;
    int carry = 0;
    for (int base = 0; base < NN; base += 1024) {
        int i = base + tid;
        int v = (i < NN) ? deg[i] : 0;
        int x = v;
#pragma unroll
        for (int off = 1; off < 64; off <<= 1) {
            int y = __shfl_up(x, off);
            if (lane >= off) x += y;
        }
        if (lane == 63) wsum[w] = x;
        __syncthreads();
        if (tid < 16) {
            int s = wsum[tid];
#pragma unroll
            for (int off = 1; off < 16; off <<= 1) {
                int y = __shfl_up(s, off);
                if (tid >= off) s += y;
            }
            wsum[tid] = s;
        }
        __syncthreads();
        int woff = w ? wsum[w - 1] : 0;
        int excl = carry + woff + x - v;
        if (i < NN) { row_ptr[i] = excl; cursor[i] = excl; }
        carry += wsum[15];
        __syncthreads();
    }
    if (tid == 0) row_ptr[NN] = carry;
}

__global__ void scatter_k(const int* __restrict__ src, const int* __restrict__ dst,
                          int* __restrict__ cursor, int* __restrict__ csr_src) {
    int i = blockIdx.x * 256 + threadIdx.x;
    if (i < EE) {
        int slot = atomicAdd(&cursor[dst[i]], 1);
        csr_src[slot] = src[i];
    }
}

// ---------------- weights -> bf16 (W2/W3 transposed; mW1 transposed) ----------------
__global__ __launch_bounds__(256) void bconv_k(const float* __restrict__ W2,
                                               const float* __restrict__ W3,
                                               const float* __restrict__ mW1,
                                               unsigned short* __restrict__ BT2,
                                               unsigned short* __restrict__ BT3,
                                               unsigned short* __restrict__ W1Tb) {
    int tid = blockIdx.x * 256 + threadIdx.x;   // 65536
    int k = tid & 255, n = tid >> 8;
    BT2[n * 256 + k] = f2bf(W2[k * 256 + n]);
    BT3[n * 256 + k] = f2bf(W3[k * 256 + n]);
    if (tid < 4096) {
        int kk = tid & 63, nn = tid >> 6;
        W1Tb[nn * 64 + kk] = f2bf(mW1[kk * 64 + nn]);
    }
}

// ---------------- layer-1 attention logits (pos-based) ----------------
__global__ __launch_bounds__(256) void eler1_k(const float* __restrict__ pos,
                                               const float* __restrict__ W1,
                                               const float* __restrict__ al,
                                               const float* __restrict__ ar,
                                               float* __restrict__ el,
                                               float* __restrict__ er) {
    int wid = blockIdx.x * 4 + (threadIdx.x >> 6);
    int lane = threadIdx.x & 63;
    if (wid >= NN) return;
    int f = lane * 4;
    float4 w0 = *(const float4*)&W1[f];
    float4 w1 = *(const float4*)&W1[256 + f];
    float4 a4 = *(const float4*)&al[f];
    float4 r4 = *(const float4*)&ar[f];
    float2 p = *(const float2*)&pos[wid * 2];
    float fx = p.x * w0.x + p.y * w1.x;
    float fy = p.x * w0.y + p.y * w1.y;
    float fz = p.x * w0.z + p.y * w1.z;
    float fw = p.x * w0.w + p.y * w1.w;
    float pl = fx * a4.x + fy * a4.y + fz * a4.z + fw * a4.w;
    float pr = fx * r4.x + fy * r4.y + fz * r4.z + fw * r4.w;
#pragma unroll
    for (int off = 1; off < 16; off <<= 1) {
        pl += __shfl_xor(pl, off);
        pr += __shfl_xor(pr, off);
    }
    if ((lane & 15) == 0) {
        int h = lane >> 4;
        el[wid * 4 + h] = pl;
        er[wid * 4 + h] = pr;
    }
}

// ---------------- aggregation: one wave per dst node, ONE-PASS softmax ----------------
// Layer 1: pos gather; emits bf16 h1 only.
__global__ __launch_bounds__(256) void agg1_k(const float* __restrict__ pos,
                                              const float* __restrict__ W1,
                                              const float* __restrict__ resW1,
                                              const float* __restrict__ el,
                                              const float* __restrict__ er,
                                              const int* __restrict__ row_ptr,
                                              const int* __restrict__ csr_src,
                                              unsigned short* __restrict__ hb16) {
    int wid = blockIdx.x * 4 + (threadIdx.x >> 6);
    int lane = threadIdx.x & 63;
    if (wid >= NN) return;
    int f = lane * 4;
    int start = row_ptr[wid], end = row_ptr[wid + 1];
    int h = lane >> 4;
    float eh = er[wid * 4 + h];

    float ap0 = 0.f, ap1 = 0.f, den = 0.f;
    int s = start;
    for (; s + 3 < end; s += 4) {
        int sn0 = csr_src[s], sn1 = csr_src[s + 1];
        int sn2 = csr_src[s + 2], sn3 = csr_src[s + 3];
        float e0 = el[sn0 * 4 + h], e1 = el[sn1 * 4 + h];
        float e2 = el[sn2 * 4 + h], e3 = el[sn3 * 4 + h];
        float2 p0 = *(const float2*)&pos[sn0 * 2];
        float2 p1 = *(const float2*)&pos[sn1 * 2];
        float2 p2 = *(const float2*)&pos[sn2 * 2];
        float2 p3 = *(const float2*)&pos[sn3 * 2];
        float w0 = __expf(lrelu(e0 + eh)), w1 = __expf(lrelu(e1 + eh));
        float w2 = __expf(lrelu(e2 + eh)), w3 = __expf(lrelu(e3 + eh));
        den += (w0 + w1) + (w2 + w3);
        ap0 += w0 * p0.x + w1 * p1.x + w2 * p2.x + w3 * p3.x;
        ap1 += w0 * p0.y + w1 * p1.y + w2 * p2.y + w3 * p3.y;
    }
    for (; s < end; ++s) {
        int sn = csr_src[s];
        float w = __expf(lrelu(el[sn * 4 + h] + eh));
        float2 p = *(const float2*)&pos[sn * 2];
        den += w;
        ap0 += w * p.x;
        ap1 += w * p.y;
    }
    float inv = 1.f / fmaxf(den, 1e-9f);
    ap0 *= inv;
    ap1 *= inv;

    float4 w0 = *(const float4*)&W1[f];
    float4 w1 = *(const float4*)&W1[256 + f];
    float4 rw0 = *(const float4*)&resW1[f];
    float4 rw1 = *(const float4*)&resW1[256 + f];
    float2 pd = *(const float2*)&pos[wid * 2];
    float4 o;
    o.x = fmaxf(ap0 * w0.x + ap1 * w1.x + pd.x * rw0.x + pd.y * rw1.x, 0.f);
    o.y = fmaxf(ap0 * w0.y + ap1 * w1.y + pd.x * rw0.y + pd.y * rw1.y, 0.f);
    o.z = fmaxf(ap0 * w0.z + ap1 * w1.z + pd.x * rw0.z + pd.y * rw1.z, 0.f);
    o.w = fmaxf(ap0 * w0.w + ap1 * w1.w + pd.x * rw0.w + pd.y * rw1.w, 0.f);
    ushort4 ob;
    ob.x = f2bf(o.x); ob.y = f2bf(o.y); ob.z = f2bf(o.z); ob.w = f2bf(o.w);
    *(ushort4*)&hb16[(size_t)wid * 256 + f] = ob;
}

// Layer 2: bf16 feat gather, bf16 in-place residual (wave owns its row), relu.
__global__ __launch_bounds__(256) void agg_k(const unsigned short* __restrict__ featb,
                                             const float* __restrict__ el,
                                             const float* __restrict__ er,
                                             const int* __restrict__ row_ptr,
                                             const int* __restrict__ csr_src,
                                             unsigned short* __restrict__ hb16) {
    int wid = blockIdx.x * 4 + (threadIdx.x >> 6);
    int lane = threadIdx.x & 63;
    if (wid >= NN) return;
    int f = lane * 4;
    int start = row_ptr[wid], end = row_ptr[wid + 1];
    int h = lane >> 4;
    float eh = er[wid * 4 + h];

    float4 acc = {0.f, 0.f, 0.f, 0.f};
    float den = 0.f;
    int s = start;
    for (; s + 3 < end; s += 4) {
        int sn0 = csr_src[s], sn1 = csr_src[s + 1];
        int sn2 = csr_src[s + 2], sn3 = csr_src[s + 3];
        float e0 = el[sn0 * 4 + h], e1 = el[sn1 * 4 + h];
        float e2 = el[sn2 * 4 + h], e3 = el[sn3 * 4 + h];
        ushort4 v0 = *(const ushort4*)&featb[(size_t)sn0 * 256 + f];
        ushort4 v1 = *(const ushort4*)&featb[(size_t)sn1 * 256 + f];
        ushort4 v2 = *(const ushort4*)&featb[(size_t)sn2 * 256 + f];
        ushort4 v3 = *(const ushort4*)&featb[(size_t)sn3 * 256 + f];
        float w0 = __expf(lrelu(e0 + eh)), w1 = __expf(lrelu(e1 + eh));
        float w2 = __expf(lrelu(e2 + eh)), w3 = __expf(lrelu(e3 + eh));
        den += (w0 + w1) + (w2 + w3);
        acc.x += w0 * bf2f(v0.x) + w1 * bf2f(v1.x) + w2 * bf2f(v2.x) + w3 * bf2f(v3.x);
        acc.y += w0 * bf2f(v0.y) + w1 * bf2f(v1.y) + w2 * bf2f(v2.y) + w3 * bf2f(v3.y);
        acc.z += w0 * bf2f(v0.z) + w1 * bf2f(v1.z) + w2 * bf2f(v2.z) + w3 * bf2f(v3.z);
        acc.w += w0 * bf2f(v0.w) + w1 * bf2f(v1.w) + w2 * bf2f(v2.w) + w3 * bf2f(v3.w);
    }
    for (; s < end; ++s) {
        int sn = csr_src[s];
        float w = __expf(lrelu(el[sn * 4 + h] + eh));
        ushort4 v = *(const ushort4*)&featb[(size_t)sn * 256 + f];
        den += w;
        acc.x += w * bf2f(v.x);
        acc.y += w * bf2f(v.y);
        acc.z += w * bf2f(v.z);
        acc.w += w * bf2f(v.w);
    }
    float inv = 1.f / fmaxf(den, 1e-9f);
    ushort4 rb = *(const ushort4*)&hb16[(size_t)wid * 256 + f];
    float4 o;
    o.x = fmaxf(acc.x * inv + bf2f(rb.x), 0.f);
    o.y = fmaxf(acc.y * inv + bf2f(rb.y), 0.f);
    o.z = fmaxf(acc.z * inv + bf2f(rb.z), 0.f);
    o.w = fmaxf(acc.w * inv + bf2f(rb.w), 0.f);
    ushort4 ob;
    ob.x = f2bf(o.x); ob.y = f2bf(o.y); ob.z = f2bf(o.z); ob.w = f2bf(o.w);
    *(ushort4*)&hb16[(size_t)wid * 256 + f] = ob;
}

// Layer 3: bf16 feat gather, bf16 residual, mean over heads -> bf16 hsmall [N,64]
__global__ __launch_bounds__(256) void agg3_k(const unsigned short* __restrict__ featb,
                                              const float* __restrict__ el,
                                              const float* __restrict__ er,
                                              const int* __restrict__ row_ptr,
                                              const int* __restrict__ csr_src,
                                              const unsigned short* __restrict__ hresb,
                                              unsigned short* __restrict__ hsmallb) {
    int wid = blockIdx.x * 4 + (threadIdx.x >> 6);
    int lane = threadIdx.x & 63;
    if (wid >= NN) return;
    int f = lane * 4;
    int start = row_ptr[wid], end = row_ptr[wid + 1];
    int h = lane >> 4;
    float eh = er[wid * 4 + h];

    float4 acc = {0.f, 0.f, 0.f, 0.f};
    float den = 0.f;
    int s = start;
    for (; s + 3 < end; s += 4) {
        int sn0 = csr_src[s], sn1 = csr_src[s + 1];
        int sn2 = csr_src[s + 2], sn3 = csr_src[s + 3];
        float e0 = el[sn0 * 4 + h], e1 = el[sn1 * 4 + h];
        float e2 = el[sn2 * 4 + h], e3 = el[sn3 * 4 + h];
        ushort4 v0 = *(const ushort4*)&featb[(size_t)sn0 * 256 + f];
        ushort4 v1 = *(const ushort4*)&featb[(size_t)sn1 * 256 + f];
        ushort4 v2 = *(const ushort4*)&featb[(size_t)sn2 * 256 + f];
        ushort4 v3 = *(const ushort4*)&featb[(size_t)sn3 * 256 + f];
        float w0 = __expf(lrelu(e0 + eh)), w1 = __expf(lrelu(e1 + eh));
        float w2 = __expf(lrelu(e2 + eh)), w3 = __expf(lrelu(e3 + eh));
        den += (w0 + w1) + (w2 + w3);
        acc.x += w0 * bf2f(v0.x) + w1 * bf2f(v1.x) + w2 * bf2f(v2.x) + w3 * bf2f(v3.x);
        acc.y += w0 * bf2f(v0.y) + w1 * bf2f(v1.y) + w2 * bf2f(v2.y) + w3 * bf2f(v3.y);
        acc.z += w0 * bf2f(v0.z) + w1 * bf2f(v1.z) + w2 * bf2f(v2.z) + w3 * bf2f(v3.z);
        acc.w += w0 * bf2f(v0.w) + w1 * bf2f(v1.w) + w2 * bf2f(v2.w) + w3 * bf2f(v3.w);
    }
    for (; s < end; ++s) {
        int sn = csr_src[s];
        float w = __expf(lrelu(el[sn * 4 + h] + eh));
        ushort4 v = *(const ushort4*)&featb[(size_t)sn * 256 + f];
        den += w;
        acc.x += w * bf2f(v.x);
        acc.y += w * bf2f(v.y);
        acc.z += w * bf2f(v.z);
        acc.w += w * bf2f(v.w);
    }
    float inv = 1.f / fmaxf(den, 1e-9f);
    ushort4 rb = *(const ushort4*)&hresb[(size_t)wid * 256 + f];
    float4 o;
    o.x = acc.x * inv + bf2f(rb.x);
    o.y = acc.y * inv + bf2f(rb.y);
    o.z = acc.z * inv + bf2f(rb.z);
    o.w = acc.w * inv + bf2f(rb.w);
    o.x += __shfl_xor(o.x, 16); o.y += __shfl_xor(o.y, 16);
    o.z += __shfl_xor(o.z, 16); o.w += __shfl_xor(o.w, 16);
    o.x += __shfl_xor(o.x, 32); o.y += __shfl_xor(o.y, 32);
    o.z += __shfl_xor(o.z, 32); o.w += __shfl_xor(o.w, 32);
    if (lane < 16) {
        ushort4 m4;
        m4.x = f2bf(o.x * 0.25f);
        m4.y = f2bf(o.y * 0.25f);
        m4.z = f2bf(o.z * 0.25f);
        m4.w = f2bf(o.w * 0.25f);
        *(ushort4*)&hsmallb[(size_t)wid * 64 + lane * 4] = m4;
    }
}

// ---------------- MFMA GEMM + fused el/er epilogue ----------------
// Wave (wr,wc) covers rows [tileM+wr*64, +64) x cols [tileN+wc*64, +64).
// Its 64 cols are exactly head h = blockIdx.y*2 + wc -> el/er computed in-register.
__global__ __launch_bounds__(256) void gemm_mfma_k(const unsigned short* __restrict__ Ab,
                                                   const unsigned short* __restrict__ BT,
                                                   const float* __restrict__ al,
                                                   const float* __restrict__ ar,
                                                   unsigned short* __restrict__ C,
                                                   float* __restrict__ el,
                                                   float* __restrict__ er) {
    __shared__ __align__(16) short As[128 * 40];
    __shared__ __align__(16) short Bs[128 * 40];
    int tid = threadIdx.x;
    int lane = tid & 63, wave = tid >> 6;
    int wr = wave >> 1, wc = wave & 1;
    int tileM = blockIdx.x * 128;
    int tileN = blockIdx.y * 128;

    int srow = tid >> 1, sko = (tid & 1) * 16;
    int fm = lane & 15, kg = lane >> 4;

    f32x4 acc[4][4];
#pragma unroll
    for (int i = 0; i < 4; ++i)
#pragma unroll
        for (int j = 0; j < 4; ++j) acc[i][j] = (f32x4){0.f, 0.f, 0.f, 0.f};

    for (int k0 = 0; k0 < 256; k0 += 32) {
        int gr = tileM + srow;
        short8 a0 = (short8)0, a1 = (short8)0;
        if (gr < NN) {
            a0 = *(const short8*)&Ab[(size_t)gr * 256 + k0 + sko];
            a1 = *(const short8*)&Ab[(size_t)gr * 256 + k0 + sko + 8];
        }
        *(short8*)&As[srow * 40 + sko] = a0;
        *(short8*)&As[srow * 40 + sko + 8] = a1;
        short8 b0 = *(const short8*)&BT[(size_t)(tileN + srow) * 256 + k0 + sko];
        short8 b1 = *(const short8*)&BT[(size_t)(tileN + srow) * 256 + k0 + sko + 8];
        *(short8*)&Bs[srow * 40 + sko] = b0;
        *(short8*)&Bs[srow * 40 + sko + 8] = b1;
        __syncthreads();

        short8 afr[4], bfr[4];
#pragma unroll
        for (int mi = 0; mi < 4; ++mi)
            afr[mi] = *(const short8*)&As[(wr * 64 + mi * 16 + fm) * 40 + kg * 8];
#pragma unroll
        for (int ni = 0; ni < 4; ++ni)
            bfr[ni] = *(const short8*)&Bs[(wc * 64 + ni * 16 + fm) * 40 + kg * 8];
#pragma unroll
        for (int mi = 0; mi < 4; ++mi)
#pragma unroll
            for (int ni = 0; ni < 4; ++ni)
                acc[mi][ni] = __builtin_amdgcn_mfma_f32_16x16x32_bf16(
                    afr[mi], bfr[ni], acc[mi][ni], 0, 0, 0);
        __syncthreads();
    }

    // C write (bf16)
#pragma unroll
    for (int mi = 0; mi < 4; ++mi) {
#pragma unroll
        for (int ni = 0; ni < 4; ++ni) {
            int col = tileN + wc * 64 + ni * 16 + fm;
#pragma unroll
            for (int r = 0; r < 4; ++r) {
                int row = tileM + wr * 64 + mi * 16 + kg * 4 + r;
                if (row < NN) C[(size_t)row * 256 + col] = f2bf(acc[mi][ni][r]);
            }
        }
    }

    // fused el/er for head h (wave covers all 64 of its cols)
    int h = blockIdx.y * 2 + wc;
    float al_r[4], ar_r[4];
#pragma unroll
    for (int ni = 0; ni < 4; ++ni) {
        al_r[ni] = al[h * 64 + ni * 16 + fm];
        ar_r[ni] = ar[h * 64 + ni * 16 + fm];
    }
#pragma unroll
    for (int mi = 0; mi < 4; ++mi) {
#pragma unroll
        for (int r = 0; r < 4; ++r) {
            float tl = acc[mi][0][r] * al_r[0] + acc[mi][1][r] * al_r[1] +
                       acc[mi][2][r] * al_r[2] + acc[mi][3][r] * al_r[3];
            float tr = acc[mi][0][r] * ar_r[0] + acc[mi][1][r] * ar_r[1] +
                       acc[mi][2][r] * ar_r[2] + acc[mi][3][r] * ar_r[3];
#pragma unroll
            for (int off = 1; off < 16; off <<= 1) {
                tl += __shfl_xor(tl, off);
                tr += __shfl_xor(tr, off);
            }
            if (fm == 0) {
                int row = tileM + wr * 64 + mi * 16 + kg * 4 + r;
                if (row < NN) {
                    el[row * 4 + h] = tl;
                    er[row * 4 + h] = tr;
                }
            }
        }
    }
}

// ---------------- edge scoring MLP v4: MFMA, 64 edges/block ----------------
__global__ __launch_bounds__(256) void edge_score4_k(const unsigned short* __restrict__ hs,
                                                     const int* __restrict__ src,
                                                     const int* __restrict__ dst,
                                                     const unsigned short* __restrict__ W1Tb,
                                                     const float* __restrict__ mb1,
                                                     const float* __restrict__ mW2,
                                                     const float* __restrict__ mb2,
                                                     float* __restrict__ out) {
    __shared__ __align__(16) unsigned short xs[64 * 72];
    __shared__ __align__(16) unsigned short wt[64 * 72];
    __shared__ float b1s[64], w2s[64];
    int tid = threadIdx.x;
    int e_loc = tid >> 2, q = tid & 3;

    *(short8*)&wt[e_loc * 72 + q * 16]     = *(const short8*)&W1Tb[e_loc * 64 + q * 16];
    *(short8*)&wt[e_loc * 72 + q * 16 + 8] = *(const short8*)&W1Tb[e_loc * 64 + q * 16 + 8];
    if (tid < 64) { b1s[tid] = mb1[tid]; w2s[tid] = mW2[tid]; }

    int e = blockIdx.x * 64 + e_loc;                 // EE % 64 == 0
    int s = src[e], d = dst[e];
    const unsigned short* rs = &hs[(size_t)s * 64 + q * 16];
    const unsigned short* rd = &hs[(size_t)d * 64 + q * 16];
    short8 a0 = *(const short8*)&rs[0];
    short8 a1 = *(const short8*)&rs[8];
    short8 b0 = *(const short8*)&rd[0];
    short8 b1 = *(const short8*)&rd[8];
    short8 x0, x1;
#pragma unroll
    for (int i = 0; i < 8; ++i) {
        x0[i] = (short)f2bf(fabsf(bf2f((unsigned short)a0[i]) - bf2f((unsigned short)b0[i])));
        x1[i] = (short)f2bf(fabsf(bf2f((unsigned short)a1[i]) - bf2f((unsigned short)b1[i])));
    }
    *(short8*)&xs[e_loc * 72 + q * 16]     = x0;
    *(short8*)&xs[e_loc * 72 + q * 16 + 8] = x1;
    __syncthreads();

    int lane = tid & 63, w = tid >> 6;
    int fm = lane & 15, kg = lane >> 4;

    const unsigned short* arow = &xs[(w * 16 + fm) * 72];
    short8 af0 = *(const short8*)&arow[kg * 8];
    short8 af1 = *(const short8*)&arow[32 + kg * 8];

    f32x4 acc[4];
#pragma unroll
    for (int ni = 0; ni < 4; ++ni) acc[ni] = (f32x4){0.f, 0.f, 0.f, 0.f};
#pragma unroll
    for (int ni = 0; ni < 4; ++ni) {
        const unsigned short* brow = &wt[(ni * 16 + fm) * 72];
        short8 bf0 = *(const short8*)&brow[kg * 8];
        short8 bf1 = *(const short8*)&brow[32 + kg * 8];
        acc[ni] = __builtin_amdgcn_mfma_f32_16x16x32_bf16(af0, bf0, acc[ni], 0, 0, 0);
        acc[ni] = __builtin_amdgcn_mfma_f32_16x16x32_bf16(af1, bf1, acc[ni], 0, 0, 0);
    }

    float t0 = 0.f, t1 = 0.f, t2 = 0.f, t3 = 0.f;
#pragma unroll
    for (int ni = 0; ni < 4; ++ni) {
        int n = ni * 16 + fm;
        float bb = b1s[n], ww = w2s[n];
        t0 += fmaxf(acc[ni][0] + bb, 0.f) * ww;
        t1 += fmaxf(acc[ni][1] + bb, 0.f) * ww;
        t2 += fmaxf(acc[ni][2] + bb, 0.f) * ww;
        t3 += fmaxf(acc[ni][3] + bb, 0.f) * ww;
    }
#pragma unroll
    for (int off = 1; off < 16; off <<= 1) {
        t0 += __shfl_xor(t0, off);
        t1 += __shfl_xor(t1, off);
        t2 += __shfl_xor(t2, off);
        t3 += __shfl_xor(t3, off);
    }
    if (fm == 0) {
        float bias = mb2[0];
        int base = blockIdx.x * 64 + w * 16 + kg * 4;
        out[base + 0] = 1.f / (1.f + __expf(-(t0 + bias)));
        out[base + 1] = 1.f / (1.f + __expf(-(t1 + bias)));
        out[base + 2] = 1.f / (1.f + __expf(-(t2 + bias)));
        out[base + 3] = 1.f / (1.f + __expf(-(t3 + bias)));
    }
}

extern "C" void kernel_launch(void* const* d_in, const int* in_sizes, int n_in,
                              void* d_out, int out_size, void* d_ws, size_t ws_size,
                              hipStream_t stream) {
    (void)in_sizes; (void)n_in; (void)out_size; (void)ws_size;
    const float* pos   = (const float*)d_in[0];
    const int*   src   = (const int*)d_in[1];
    const int*   dst   = (const int*)d_in[2];
    const float* W1    = (const float*)d_in[3];
    const float* al1   = (const float*)d_in[4];
    const float* ar1   = (const float*)d_in[5];
    const float* resW1 = (const float*)d_in[6];
    const float* W2    = (const float*)d_in[7];
    const float* al2   = (const float*)d_in[8];
    const float* ar2   = (const float*)d_in[9];
    const float* W3    = (const float*)d_in[10];
    const float* al3   = (const float*)d_in[11];
    const float* ar3   = (const float*)d_in[12];
    const float* mW1   = (const float*)d_in[13];
    const float* mb1   = (const float*)d_in[14];
    const float* mW2   = (const float*)d_in[15];
    const float* mb2   = (const float*)d_in[16];
    float* out = (float*)d_out;

    char* ws = (char*)d_ws;
    size_t off = 0;
    auto alloc = [&](size_t bytes) {
        void* p = ws + off;
        off += (bytes + 255) & ~(size_t)255;
        return p;
    };
    unsigned short* FEATb  = (unsigned short*)alloc((size_t)NN * 256 * 2);
    unsigned short* Hb16   = (unsigned short*)alloc((size_t)NN * 256 * 2);
    unsigned short* BT2    = (unsigned short*)alloc((size_t)256 * 256 * 2);
    unsigned short* BT3    = (unsigned short*)alloc((size_t)256 * 256 * 2);
    unsigned short* W1Tb   = (unsigned short*)alloc((size_t)64 * 64 * 2);
    unsigned short* hsmallb = (unsigned short*)alloc((size_t)NN * 64 * 2);
    float* el     = (float*)alloc((size_t)NN * 4 * 4);
    float* er     = (float*)alloc((size_t)NN * 4 * 4);
    int* deg      = (int*)alloc((size_t)NN * 4);
    int* row_ptr  = (int*)alloc((size_t)(NN + 1) * 4);
    int* cursor   = (int*)alloc((size_t)NN * 4);
    int* csr      = (int*)alloc((size_t)EE * 4);

    hipMemsetAsync(deg, 0, (size_t)NN * 4, stream);
    hist_k<<<(EE + 255) / 256, 256, 0, stream>>>(dst, deg);
    scan_k<<<1, 1024, 0, stream>>>(deg, row_ptr, cursor);
    scatter_k<<<(EE + 255) / 256, 256, 0, stream>>>(src, dst, cursor, csr);
    bconv_k<<<256, 256, 0, stream>>>(W2, W3, mW1, BT2, BT3, W1Tb);

    // layer 1
    eler1_k<<<NN / 4 + 1, 256, 0, stream>>>(pos, W1, al1, ar1, el, er);
    agg1_k<<<NN / 4 + 1, 256, 0, stream>>>(pos, W1, resW1, el, er, row_ptr, csr, Hb16);

    dim3 ggrid((NN + 127) / 128, 2);
    // layer 2 (gemm computes FEATb + el/er in one pass)
    gemm_mfma_k<<<ggrid, 256, 0, stream>>>(Hb16, BT2, al2, ar2, FEATb, el, er);
    agg_k<<<NN / 4 + 1, 256, 0, stream>>>(FEATb, el, er, row_ptr, csr, Hb16);

    // layer 3
    gemm_mfma_k<<<ggrid, 256, 0, stream>>>(Hb16, BT3, al3, ar3, FEATb, el, er);
    agg3_k<<<NN / 4 + 1, 256, 0, stream>>>(FEATb, el, er, row_ptr, csr, Hb16, hsmallb);

    // edge MLP (MFMA)
    edge_score4_k<<<EE / 64, 256, 0, stream>>>(hsmallb, src, dst, W1Tb, mb1, mW2, mb2, out);
}

// Round 10
// 458.253 us; speedup vs baseline: 2.5699x; 1.0781x over previous
//
#include <hip/hip_runtime.h>
#include <hip/hip_bf16.h>

#define NN 50000
#define EE 800000
#define NB 196   // ceil(NN/256)

typedef short short8 __attribute__((ext_vector_type(8)));
typedef float f32x4 __attribute__((ext_vector_type(4)));

__device__ __forceinline__ float lrelu(float x) { return x > 0.f ? x : 0.2f * x; }

__device__ __forceinline__ unsigned short f2bf(float x) {
    __hip_bfloat16 b = __float2bfloat16(x);
    return *(unsigned short*)&b;
}
__device__ __forceinline__ float bf2f(unsigned short u) {
    return __uint_as_float(((unsigned int)u) << 16);
}

// ---------------- CSR build ----------------
__global__ void hist_k(const int* __restrict__ dst, int* __restrict__ deg) {
    int i = blockIdx.x * 256 + threadIdx.x;
    if (i < EE) atomicAdd(&deg[dst[i]], 1);
}

// two-level scan: A) per-256-chunk inclusive scan + block totals
__global__ __launch_bounds__(256) void scanA_k(const int* __restrict__ deg,
                                               int* __restrict__ cscan,
                                               int* __restrict__ bsum) {
    __shared__ int wtot[4];
    int tid = threadIdx.x, lane = tid & 63, w = tid >> 6;
    int i = blockIdx.x * 256 + tid;
    int v = (i < NN) ? deg[i] : 0;
    int x = v;
#pragma unroll
    for (int off = 1; off < 64; off <<= 1) {
        int y = __shfl_up(x, off);
        if (lane >= off) x += y;
    }
    if (lane == 63) wtot[w] = x;
    __syncthreads();
    int prefix = 0;
#pragma unroll
    for (int j = 0; j < 4; ++j)
        if (j < w) prefix += wtot[j];
    x += prefix;
    if (i < NN) cscan[i] = x;
    if (tid == 255) bsum[blockIdx.x] = x;
}

// B) scan of block totals (1 block)
__global__ __launch_bounds__(256) void scanB_k(const int* __restrict__ bsum,
                                               int* __restrict__ boff) {
    __shared__ int wtot[4];
    int tid = threadIdx.x, lane = tid & 63, w = tid >> 6;
    int v = (tid < NB) ? bsum[tid] : 0;
    int x = v;
#pragma unroll
    for (int off = 1; off < 64; off <<= 1) {
        int y = __shfl_up(x, off);
        if (lane >= off) x += y;
    }
    if (lane == 63) wtot[w] = x;
    __syncthreads();
    int prefix = 0;
#pragma unroll
    for (int j = 0; j < 4; ++j)
        if (j < w) prefix += wtot[j];
    x += prefix;
    if (tid < NB) boff[tid] = x - v;        // exclusive
    if (tid == NB - 1) boff[NB] = x;        // grand total
}

// C) combine -> exclusive row_ptr + cursor
__global__ __launch_bounds__(256) void scanC_k(const int* __restrict__ deg,
                                               const int* __restrict__ cscan,
                                               const int* __restrict__ boff,
                                               int* __restrict__ row_ptr,
                                               int* __restrict__ cursor) {
    int i = blockIdx.x * 256 + threadIdx.x;
    if (i < NN) {
        int e = boff[i >> 8] + cscan[i] - deg[i];
        row_ptr[i] = e;
        cursor[i] = e;
    }
    if (i == 0) row_ptr[NN] = boff[NB];
}

__global__ void scatter_k(const int* __restrict__ src, const int* __restrict__ dst,
                          int* __restrict__ cursor, int* __restrict__ csr_src) {
    int i = blockIdx.x * 256 + threadIdx.x;
    if (i < EE) {
        int slot = atomicAdd(&cursor[dst[i]], 1);
        csr_src[slot] = src[i];
    }
}

// ---------------- weights -> bf16 (W2/W3 transposed; mW1 transposed) ----------------
__global__ __launch_bounds__(256) void bconv_k(const float* __restrict__ W2,
                                               const float* __restrict__ W3,
                                               const float* __restrict__ mW1,
                                               unsigned short* __restrict__ BT2,
                                               unsigned short* __restrict__ BT3,
                                               unsigned short* __restrict__ W1Tb) {
    int tid = blockIdx.x * 256 + threadIdx.x;   // 65536
    int k = tid & 255, n = tid >> 8;
    BT2[n * 256 + k] = f2bf(W2[k * 256 + n]);
    BT3[n * 256 + k] = f2bf(W3[k * 256 + n]);
    if (tid < 4096) {
        int kk = tid & 63, nn = tid >> 6;
        W1Tb[nn * 64 + kk] = f2bf(mW1[kk * 64 + nn]);
    }
}

// ---------------- layer-1 attention logits (pos-based) ----------------
__global__ __launch_bounds__(256) void eler1_k(const float* __restrict__ pos,
                                               const float* __restrict__ W1,
                                               const float* __restrict__ al,
                                               const float* __restrict__ ar,
                                               float* __restrict__ el,
                                               float* __restrict__ er) {
    int wid = blockIdx.x * 4 + (threadIdx.x >> 6);
    int lane = threadIdx.x & 63;
    if (wid >= NN) return;
    int f = lane * 4;
    float4 w0 = *(const float4*)&W1[f];
    float4 w1 = *(const float4*)&W1[256 + f];
    float4 a4 = *(const float4*)&al[f];
    float4 r4 = *(const float4*)&ar[f];
    float2 p = *(const float2*)&pos[wid * 2];
    float fx = p.x * w0.x + p.y * w1.x;
    float fy = p.x * w0.y + p.y * w1.y;
    float fz = p.x * w0.z + p.y * w1.z;
    float fw = p.x * w0.w + p.y * w1.w;
    float pl = fx * a4.x + fy * a4.y + fz * a4.z + fw * a4.w;
    float pr = fx * r4.x + fy * r4.y + fz * r4.z + fw * r4.w;
#pragma unroll
    for (int off = 1; off < 16; off <<= 1) {
        pl += __shfl_xor(pl, off);
        pr += __shfl_xor(pr, off);
    }
    if ((lane & 15) == 0) {
        int h = lane >> 4;
        el[wid * 4 + h] = pl;
        er[wid * 4 + h] = pr;
    }
}

// ---------------- aggregation: one wave per dst node, ONE-PASS softmax, unroll-8 ----------------
__global__ __launch_bounds__(256) void agg1_k(const float* __restrict__ pos,
                                              const float* __restrict__ W1,
                                              const float* __restrict__ resW1,
                                              const float* __restrict__ el,
                                              const float* __restrict__ er,
                                              const int* __restrict__ row_ptr,
                                              const int* __restrict__ csr_src,
                                              unsigned short* __restrict__ hb16) {
    int wid = blockIdx.x * 4 + (threadIdx.x >> 6);
    int lane = threadIdx.x & 63;
    if (wid >= NN) return;
    int f = lane * 4;
    int start = row_ptr[wid], end = row_ptr[wid + 1];
    int h = lane >> 4;
    float eh = er[wid * 4 + h];

    float ap0 = 0.f, ap1 = 0.f, den = 0.f;
    int s = start;
    for (; s + 7 < end; s += 8) {
        int sn[8];
#pragma unroll
        for (int j = 0; j < 8; ++j) sn[j] = csr_src[s + j];
        float e[8];
        float2 p[8];
#pragma unroll
        for (int j = 0; j < 8; ++j) {
            e[j] = el[sn[j] * 4 + h];
            p[j] = *(const float2*)&pos[sn[j] * 2];
        }
#pragma unroll
        for (int j = 0; j < 8; ++j) {
            float w = __expf(lrelu(e[j] + eh));
            den += w;
            ap0 += w * p[j].x;
            ap1 += w * p[j].y;
        }
    }
    for (; s < end; ++s) {
        int sn = csr_src[s];
        float w = __expf(lrelu(el[sn * 4 + h] + eh));
        float2 p = *(const float2*)&pos[sn * 2];
        den += w;
        ap0 += w * p.x;
        ap1 += w * p.y;
    }
    float inv = 1.f / fmaxf(den, 1e-9f);
    ap0 *= inv;
    ap1 *= inv;

    float4 w0 = *(const float4*)&W1[f];
    float4 w1 = *(const float4*)&W1[256 + f];
    float4 rw0 = *(const float4*)&resW1[f];
    float4 rw1 = *(const float4*)&resW1[256 + f];
    float2 pd = *(const float2*)&pos[wid * 2];
    float4 o;
    o.x = fmaxf(ap0 * w0.x + ap1 * w1.x + pd.x * rw0.x + pd.y * rw1.x, 0.f);
    o.y = fmaxf(ap0 * w0.y + ap1 * w1.y + pd.x * rw0.y + pd.y * rw1.y, 0.f);
    o.z = fmaxf(ap0 * w0.z + ap1 * w1.z + pd.x * rw0.z + pd.y * rw1.z, 0.f);
    o.w = fmaxf(ap0 * w0.w + ap1 * w1.w + pd.x * rw0.w + pd.y * rw1.w, 0.f);
    ushort4 ob;
    ob.x = f2bf(o.x); ob.y = f2bf(o.y); ob.z = f2bf(o.z); ob.w = f2bf(o.w);
    *(ushort4*)&hb16[(size_t)wid * 256 + f] = ob;
}

__global__ __launch_bounds__(256) void agg_k(const unsigned short* __restrict__ featb,
                                             const float* __restrict__ el,
                                             const float* __restrict__ er,
                                             const int* __restrict__ row_ptr,
                                             const int* __restrict__ csr_src,
                                             unsigned short* __restrict__ hb16) {
    int wid = blockIdx.x * 4 + (threadIdx.x >> 6);
    int lane = threadIdx.x & 63;
    if (wid >= NN) return;
    int f = lane * 4;
    int start = row_ptr[wid], end = row_ptr[wid + 1];
    int h = lane >> 4;
    float eh = er[wid * 4 + h];

    float4 acc = {0.f, 0.f, 0.f, 0.f};
    float den = 0.f;
    int s = start;
    for (; s + 7 < end; s += 8) {
        int sn[8];
#pragma unroll
        for (int j = 0; j < 8; ++j) sn[j] = csr_src[s + j];
        float e[8];
        ushort4 v[8];
#pragma unroll
        for (int j = 0; j < 8; ++j) {
            e[j] = el[sn[j] * 4 + h];
            v[j] = *(const ushort4*)&featb[(size_t)sn[j] * 256 + f];
        }
#pragma unroll
        for (int j = 0; j < 8; ++j) {
            float w = __expf(lrelu(e[j] + eh));
            den += w;
            acc.x += w * bf2f(v[j].x);
            acc.y += w * bf2f(v[j].y);
            acc.z += w * bf2f(v[j].z);
            acc.w += w * bf2f(v[j].w);
        }
    }
    for (; s < end; ++s) {
        int sn = csr_src[s];
        float w = __expf(lrelu(el[sn * 4 + h] + eh));
        ushort4 v = *(const ushort4*)&featb[(size_t)sn * 256 + f];
        den += w;
        acc.x += w * bf2f(v.x);
        acc.y += w * bf2f(v.y);
        acc.z += w * bf2f(v.z);
        acc.w += w * bf2f(v.w);
    }
    float inv = 1.f / fmaxf(den, 1e-9f);
    ushort4 rb = *(const ushort4*)&hb16[(size_t)wid * 256 + f];
    float4 o;
    o.x = fmaxf(acc.x * inv + bf2f(rb.x), 0.f);
    o.y = fmaxf(acc.y * inv + bf2f(rb.y), 0.f);
    o.z = fmaxf(acc.z * inv + bf2f(rb.z), 0.f);
    o.w = fmaxf(acc.w * inv + bf2f(rb.w), 0.f);
    ushort4 ob;
    ob.x = f2bf(o.x); ob.y = f2bf(o.y); ob.z = f2bf(o.z); ob.w = f2bf(o.w);
    *(ushort4*)&hb16[(size_t)wid * 256 + f] = ob;
}

__global__ __launch_bounds__(256) void agg3_k(const unsigned short* __restrict__ featb,
                                              const float* __restrict__ el,
                                              const float* __restrict__ er,
                                              const int* __restrict__ row_ptr,
                                              const int* __restrict__ csr_src,
                                              const unsigned short* __restrict__ hresb,
                                              unsigned short* __restrict__ hsmallb) {
    int wid = blockIdx.x * 4 + (threadIdx.x >> 6);
    int lane = threadIdx.x & 63;
    if (wid >= NN) return;
    int f = lane * 4;
    int start = row_ptr[wid], end = row_ptr[wid + 1];
    int h = lane >> 4;
    float eh = er[wid * 4 + h];

    float4 acc = {0.f, 0.f, 0.f, 0.f};
    float den = 0.f;
    int s = start;
    for (; s + 7 < end; s += 8) {
        int sn[8];
#pragma unroll
        for (int j = 0; j < 8; ++j) sn[j] = csr_src[s + j];
        float e[8];
        ushort4 v[8];
#pragma unroll
        for (int j = 0; j < 8; ++j) {
            e[j] = el[sn[j] * 4 + h];
            v[j] = *(const ushort4*)&featb[(size_t)sn[j] * 256 + f];
        }
#pragma unroll
        for (int j = 0; j < 8; ++j) {
            float w = __expf(lrelu(e[j] + eh));
            den += w;
            acc.x += w * bf2f(v[j].x);
            acc.y += w * bf2f(v[j].y);
            acc.z += w * bf2f(v[j].z);
            acc.w += w * bf2f(v[j].w);
        }
    }
    for (; s < end; ++s) {
        int sn = csr_src[s];
        float w = __expf(lrelu(el[sn * 4 + h] + eh));
        ushort4 v = *(const ushort4*)&featb[(size_t)sn * 256 + f];
        den += w;
        acc.x += w * bf2f(v.x);
        acc.y += w * bf2f(v.y);
        acc.z += w * bf2f(v.z);
        acc.w += w * bf2f(v.w);
    }
    float inv = 1.f / fmaxf(den, 1e-9f);
    ushort4 rb = *(const ushort4*)&hresb[(size_t)wid * 256 + f];
    float4 o;
    o.x = acc.x * inv + bf2f(rb.x);
    o.y = acc.y * inv + bf2f(rb.y);
    o.z = acc.z * inv + bf2f(rb.z);
    o.w = acc.w * inv + bf2f(rb.w);
    o.x += __shfl_xor(o.x, 16); o.y += __shfl_xor(o.y, 16);
    o.z += __shfl_xor(o.z, 16); o.w += __shfl_xor(o.w, 16);
    o.x += __shfl_xor(o.x, 32); o.y += __shfl_xor(o.y, 32);
    o.z += __shfl_xor(o.z, 32); o.w += __shfl_xor(o.w, 32);
    if (lane < 16) {
        ushort4 m4;
        m4.x = f2bf(o.x * 0.25f);
        m4.y = f2bf(o.y * 0.25f);
        m4.z = f2bf(o.z * 0.25f);
        m4.w = f2bf(o.w * 0.25f);
        *(ushort4*)&hsmallb[(size_t)wid * 64 + lane * 4] = m4;
    }
}

// ---------------- MFMA GEMM + fused el/er epilogue ----------------
__global__ __launch_bounds__(256) void gemm_mfma_k(const unsigned short* __restrict__ Ab,
                                                   const unsigned short* __restrict__ BT,
                                                   const float* __restrict__ al,
                                                   const float* __restrict__ ar,
                                                   unsigned short* __restrict__ C,
                                                   float* __restrict__ el,
                                                   float* __restrict__ er) {
    __shared__ __align__(16) short As[128 * 40];
    __shared__ __align__(16) short Bs[128 * 40];
    int tid = threadIdx.x;
    int lane = tid & 63, wave = tid >> 6;
    int wr = wave >> 1, wc = wave & 1;
    int tileM = blockIdx.x * 128;
    int tileN = blockIdx.y * 128;

    int srow = tid >> 1, sko = (tid & 1) * 16;
    int fm = lane & 15, kg = lane >> 4;

    f32x4 acc[4][4];
#pragma unroll
    for (int i = 0; i < 4; ++i)
#pragma unroll
        for (int j = 0; j < 4; ++j) acc[i][j] = (f32x4){0.f, 0.f, 0.f, 0.f};

    for (int k0 = 0; k0 < 256; k0 += 32) {
        int gr = tileM + srow;
        short8 a0 = (short8)0, a1 = (short8)0;
        if (gr < NN) {
            a0 = *(const short8*)&Ab[(size_t)gr * 256 + k0 + sko];
            a1 = *(const short8*)&Ab[(size_t)gr * 256 + k0 + sko + 8];
        }
        *(short8*)&As[srow * 40 + sko] = a0;
        *(short8*)&As[srow * 40 + sko + 8] = a1;
        short8 b0 = *(const short8*)&BT[(size_t)(tileN + srow) * 256 + k0 + sko];
        short8 b1 = *(const short8*)&BT[(size_t)(tileN + srow) * 256 + k0 + sko + 8];
        *(short8*)&Bs[srow * 40 + sko] = b0;
        *(short8*)&Bs[srow * 40 + sko + 8] = b1;
        __syncthreads();

        short8 afr[4], bfr[4];
#pragma unroll
        for (int mi = 0; mi < 4; ++mi)
            afr[mi] = *(const short8*)&As[(wr * 64 + mi * 16 + fm) * 40 + kg * 8];
#pragma unroll
        for (int ni = 0; ni < 4; ++ni)
            bfr[ni] = *(const short8*)&Bs[(wc * 64 + ni * 16 + fm) * 40 + kg * 8];
#pragma unroll
        for (int mi = 0; mi < 4; ++mi)
#pragma unroll
            for (int ni = 0; ni < 4; ++ni)
                acc[mi][ni] = __builtin_amdgcn_mfma_f32_16x16x32_bf16(
                    afr[mi], bfr[ni], acc[mi][ni], 0, 0, 0);
        __syncthreads();
    }

#pragma unroll
    for (int mi = 0; mi < 4; ++mi) {
#pragma unroll
        for (int ni = 0; ni < 4; ++ni) {
            int col = tileN + wc * 64 + ni * 16 + fm;
#pragma unroll
            for (int r = 0; r < 4; ++r) {
                int row = tileM + wr * 64 + mi * 16 + kg * 4 + r;
                if (row < NN) C[(size_t)row * 256 + col] = f2bf(acc[mi][ni][r]);
            }
        }
    }

    int h = blockIdx.y * 2 + wc;
    float al_r[4], ar_r[4];
#pragma unroll
    for (int ni = 0; ni < 4; ++ni) {
        al_r[ni] = al[h * 64 + ni * 16 + fm];
        ar_r[ni] = ar[h * 64 + ni * 16 + fm];
    }
#pragma unroll
    for (int mi = 0; mi < 4; ++mi) {
#pragma unroll
        for (int r = 0; r < 4; ++r) {
            float tl = acc[mi][0][r] * al_r[0] + acc[mi][1][r] * al_r[1] +
                       acc[mi][2][r] * al_r[2] + acc[mi][3][r] * al_r[3];
            float tr = acc[mi][0][r] * ar_r[0] + acc[mi][1][r] * ar_r[1] +
                       acc[mi][2][r] * ar_r[2] + acc[mi][3][r] * ar_r[3];
#pragma unroll
            for (int off = 1; off < 16; off <<= 1) {
                tl += __shfl_xor(tl, off);
                tr += __shfl_xor(tr, off);
            }
            if (fm == 0) {
                int row = tileM + wr * 64 + mi * 16 + kg * 4 + r;
                if (row < NN) {
                    el[row * 4 + h] = tl;
                    er[row * 4 + h] = tr;
                }
            }
        }
    }
}

// ---------------- edge scoring MLP v4: MFMA, 64 edges/block ----------------
__global__ __launch_bounds__(256) void edge_score4_k(const unsigned short* __restrict__ hs,
                                                     const int* __restrict__ src,
                                                     const int* __restrict__ dst,
                                                     const unsigned short* __restrict__ W1Tb,
                                                     const float* __restrict__ mb1,
                                                     const float* __restrict__ mW2,
                                                     const float* __restrict__ mb2,
                                                     float* __restrict__ out) {
    __shared__ __align__(16) unsigned short xs[64 * 72];
    __shared__ __align__(16) unsigned short wt[64 * 72];
    __shared__ float b1s[64], w2s[64];
    int tid = threadIdx.x;
    int e_loc = tid >> 2, q = tid & 3;

    *(short8*)&wt[e_loc * 72 + q * 16]     = *(const short8*)&W1Tb[e_loc * 64 + q * 16];
    *(short8*)&wt[e_loc * 72 + q * 16 + 8] = *(const short8*)&W1Tb[e_loc * 64 + q * 16 + 8];
    if (tid < 64) { b1s[tid] = mb1[tid]; w2s[tid] = mW2[tid]; }

    int e = blockIdx.x * 64 + e_loc;                 // EE % 64 == 0
    int s = src[e], d = dst[e];
    const unsigned short* rs = &hs[(size_t)s * 64 + q * 16];
    const unsigned short* rd = &hs[(size_t)d * 64 + q * 16];
    short8 a0 = *(const short8*)&rs[0];
    short8 a1 = *(const short8*)&rs[8];
    short8 b0 = *(const short8*)&rd[0];
    short8 b1 = *(const short8*)&rd[8];
    short8 x0, x1;
#pragma unroll
    for (int i = 0; i < 8; ++i) {
        x0[i] = (short)f2bf(fabsf(bf2f((unsigned short)a0[i]) - bf2f((unsigned short)b0[i])));
        x1[i] = (short)f2bf(fabsf(bf2f((unsigned short)a1[i]) - bf2f((unsigned short)b1[i])));
    }
    *(short8*)&xs[e_loc * 72 + q * 16]     = x0;
    *(short8*)&xs[e_loc * 72 + q * 16 + 8] = x1;
    __syncthreads();

    int lane = tid & 63, w = tid >> 6;
    int fm = lane & 15, kg = lane >> 4;

    const unsigned short* arow = &xs[(w * 16 + fm) * 72];
    short8 af0 = *(const short8*)&arow[kg * 8];
    short8 af1 = *(const short8*)&arow[32 + kg * 8];

    f32x4 acc[4];
#pragma unroll
    for (int ni = 0; ni < 4; ++ni) acc[ni] = (f32x4){0.f, 0.f, 0.f, 0.f};
#pragma unroll
    for (int ni = 0; ni < 4; ++ni) {
        const unsigned short* brow = &wt[(ni * 16 + fm) * 72];
        short8 bf0 = *(const short8*)&brow[kg * 8];
        short8 bf1 = *(const short8*)&brow[32 + kg * 8];
        acc[ni] = __builtin_amdgcn_mfma_f32_16x16x32_bf16(af0, bf0, acc[ni], 0, 0, 0);
        acc[ni] = __builtin_amdgcn_mfma_f32_16x16x32_bf16(af1, bf1, acc[ni], 0, 0, 0);
    }

    float t0 = 0.f, t1 = 0.f, t2 = 0.f, t3 = 0.f;
#pragma unroll
    for (int ni = 0; ni < 4; ++ni) {
        int n = ni * 16 + fm;
        float bb = b1s[n], ww = w2s[n];
        t0 += fmaxf(acc[ni][0] + bb, 0.f) * ww;
        t1 += fmaxf(acc[ni][1] + bb, 0.f) * ww;
        t2 += fmaxf(acc[ni][2] + bb, 0.f) * ww;
        t3 += fmaxf(acc[ni][3] + bb, 0.f) * ww;
    }
#pragma unroll
    for (int off = 1; off < 16; off <<= 1) {
        t0 += __shfl_xor(t0, off);
        t1 += __shfl_xor(t1, off);
        t2 += __shfl_xor(t2, off);
        t3 += __shfl_xor(t3, off);
    }
    if (fm == 0) {
        float bias = mb2[0];
        int base = blockIdx.x * 64 + w * 16 + kg * 4;
        out[base + 0] = 1.f / (1.f + __expf(-(t0 + bias)));
        out[base + 1] = 1.f / (1.f + __expf(-(t1 + bias)));
        out[base + 2] = 1.f / (1.f + __expf(-(t2 + bias)));
        out[base + 3] = 1.f / (1.f + __expf(-(t3 + bias)));
    }
}

extern "C" void kernel_launch(void* const* d_in, const int* in_sizes, int n_in,
                              void* d_out, int out_size, void* d_ws, size_t ws_size,
                              hipStream_t stream) {
    (void)in_sizes; (void)n_in; (void)out_size; (void)ws_size;
    const float* pos   = (const float*)d_in[0];
    const int*   src   = (const int*)d_in[1];
    const int*   dst   = (const int*)d_in[2];
    const float* W1    = (const float*)d_in[3];
    const float* al1   = (const float*)d_in[4];
    const float* ar1   = (const float*)d_in[5];
    const float* resW1 = (const float*)d_in[6];
    const float* W2    = (const float*)d_in[7];
    const float* al2   = (const float*)d_in[8];
    const float* ar2   = (const float*)d_in[9];
    const float* W3    = (const float*)d_in[10];
    const float* al3   = (const float*)d_in[11];
    const float* ar3   = (const float*)d_in[12];
    const float* mW1   = (const float*)d_in[13];
    const float* mb1   = (const float*)d_in[14];
    const float* mW2   = (const float*)d_in[15];
    const float* mb2   = (const float*)d_in[16];
    float* out = (float*)d_out;

    char* ws = (char*)d_ws;
    size_t off = 0;
    auto alloc = [&](size_t bytes) {
        void* p = ws + off;
        off += (bytes + 255) & ~(size_t)255;
        return p;
    };
    unsigned short* FEATb  = (unsigned short*)alloc((size_t)NN * 256 * 2);
    unsigned short* Hb16   = (unsigned short*)alloc((size_t)NN * 256 * 2);
    unsigned short* BT2    = (unsigned short*)alloc((size_t)256 * 256 * 2);
    unsigned short* BT3    = (unsigned short*)alloc((size_t)256 * 256 * 2);
    unsigned short* W1Tb   = (unsigned short*)alloc((size_t)64 * 64 * 2);
    unsigned short* hsmallb = (unsigned short*)alloc((size_t)NN * 64 * 2);
    float* el     = (float*)alloc((size_t)NN * 4 * 4);
    float* er     = (float*)alloc((size_t)NN * 4 * 4);
    int* deg      = (int*)alloc((size_t)NN * 4);
    int* cscan    = (int*)alloc((size_t)NN * 4);
    int* bsum     = (int*)alloc((size_t)NB * 4);
    int* boff     = (int*)alloc((size_t)(NB + 1) * 4);
    int* row_ptr  = (int*)alloc((size_t)(NN + 1) * 4);
    int* cursor   = (int*)alloc((size_t)NN * 4);
    int* csr      = (int*)alloc((size_t)EE * 4);

    hipMemsetAsync(deg, 0, (size_t)NN * 4, stream);
    hist_k<<<(EE + 255) / 256, 256, 0, stream>>>(dst, deg);
    scanA_k<<<NB, 256, 0, stream>>>(deg, cscan, bsum);
    scanB_k<<<1, 256, 0, stream>>>(bsum, boff);
    scanC_k<<<NB, 256, 0, stream>>>(deg, cscan, boff, row_ptr, cursor);
    scatter_k<<<(EE + 255) / 256, 256, 0, stream>>>(src, dst, cursor, csr);
    bconv_k<<<256, 256, 0, stream>>>(W2, W3, mW1, BT2, BT3, W1Tb);

    // layer 1
    eler1_k<<<NN / 4 + 1, 256, 0, stream>>>(pos, W1, al1, ar1, el, er);
    agg1_k<<<NN / 4 + 1, 256, 0, stream>>>(pos, W1, resW1, el, er, row_ptr, csr, Hb16);

    dim3 ggrid((NN + 127) / 128, 2);
    // layer 2 (gemm computes FEATb + el/er in one pass)
    gemm_mfma_k<<<ggrid, 256, 0, stream>>>(Hb16, BT2, al2, ar2, FEATb, el, er);
    agg_k<<<NN / 4 + 1, 256, 0, stream>>>(FEATb, el, er, row_ptr, csr, Hb16);

    // layer 3
    gemm_mfma_k<<<ggrid, 256, 0, stream>>>(Hb16, BT3, al3, ar3, FEATb, el, er);
    agg3_k<<<NN / 4 + 1, 256, 0, stream>>>(FEATb, el, er, row_ptr, csr, Hb16, hsmallb);

    // edge MLP (MFMA)
    edge_score4_k<<<EE / 64, 256, 0, stream>>>(hsmallb, src, dst, W1Tb, mb1, mW2, mb2, out);
}